// Round 3
// baseline (1520.090 us; speedup 1.0000x reference)
//
#include <hip/hip_runtime.h>
#include <cstddef>
#include <cstdint>

#define N_NODES 100000
#define IN_CH 256
#define OUT_CH 64
#define N_EDGES 3200000

// bucketing: 128 nodes per bucket
#define BKT_SHIFT 7
#define BKT_R     128
#define K_BKT     782                 // ceil(100000/128)
#define T_PART    8192                // edges per partition block
#define NBLK_PART ((N_EDGES + T_PART - 1) / T_PART)   // 391

// ---- ws layout (bytes) ----
#define WS_FLAG_OFF   0
#define WS_BCNT_OFF   4096
#define WS_BBASE_OFF  8192            // 783 u32
#define WS_GCUR_OFF   12288
#define WS_DINV_OFF   16384           // 400000 B
#define WS_PAIRS_OFF  416384          // 12.8 MB
#define WS_H_OFF      13216384        // 25.6 MB
#define WS_NEED       38816384

// ---------------------------------------------------------------------------
__global__ void probe_kernel(const unsigned* __restrict__ ei, int* __restrict__ flag) {
    if (blockIdx.x == 0 && threadIdx.x == 0) {
        int all0 = 1;
        for (int i = 0; i < 16; ++i) all0 &= (ei[2 * i + 1] == 0u);
        *flag = all0;  // 1 => int64 layout, 0 => int32 layout
    }
}

__device__ __forceinline__ int load_idx(const int* ei32, const long long* ei64,
                                        bool is64, long long pos) {
    return is64 ? (int)ei64[pos] : ei32[pos];
}

// ---------------------------------------------------------------------------
// Per-bucket edge counts (782 bins) via per-block LDS histogram.
__global__ __launch_bounds__(256) void bcount_kernel(const int* __restrict__ ei32,
                                                     const long long* __restrict__ ei64,
                                                     const int* __restrict__ flag,
                                                     unsigned* __restrict__ bcount) {
    __shared__ unsigned hist[K_BKT];
    const bool is64 = (*flag != 0);
    for (int k = threadIdx.x; k < K_BKT; k += 256) hist[k] = 0u;
    __syncthreads();
    int i = blockIdx.x * 256 + threadIdx.x;
    const int stride = gridDim.x * 256;
    for (; i < N_EDGES; i += stride) {
        int d = load_idx(ei32, ei64, is64, (long long)N_EDGES + i);
        atomicAdd(&hist[d >> BKT_SHIFT], 1u);
    }
    __syncthreads();
    for (int k = threadIdx.x; k < K_BKT; k += 256) {
        unsigned c = hist[k];
        if (c) atomicAdd(&bcount[k], c);
    }
}

// Exclusive scan of the 782 bucket counts; writes bbase[0..K] and inits gcur.
__global__ __launch_bounds__(1024) void bscan_kernel(const unsigned* __restrict__ bcount,
                                                     unsigned* __restrict__ bbase,
                                                     unsigned* __restrict__ gcur) {
    __shared__ unsigned s[1024];
    const int t = threadIdx.x;
    unsigned v = (t < K_BKT) ? bcount[t] : 0u;
    s[t] = v; __syncthreads();
    #pragma unroll
    for (int d = 1; d < 1024; d <<= 1) {
        unsigned x = (t >= d) ? s[t - d] : 0u; __syncthreads();
        s[t] += x; __syncthreads();
    }
    if (t < K_BKT) {
        unsigned excl = s[t] - v;
        bbase[t] = excl;
        gcur[t]  = excl;
        if (t == K_BKT - 1) bbase[K_BKT] = s[t];
    }
}

// ---------------------------------------------------------------------------
// Partition edges into dst-range buckets. Per-block LDS hist -> one global
// reservation atomic per (block,bucket) -> scattered 4B writes that are
// block-clustered per bucket run (L2 merges them into near-full lines).
// pair = src | (dLocal<<17)
__global__ __launch_bounds__(512) void partition_kernel(const int* __restrict__ ei32,
                                                        const long long* __restrict__ ei64,
                                                        const int* __restrict__ flag,
                                                        unsigned* __restrict__ gcur,
                                                        unsigned* __restrict__ pairs) {
    __shared__ unsigned hist[K_BKT];
    __shared__ unsigned cur[K_BKT];
    const bool is64 = (*flag != 0);
    const int start = blockIdx.x * T_PART;
    const int end   = min(start + T_PART, N_EDGES);

    for (int k = threadIdx.x; k < K_BKT; k += 512) hist[k] = 0u;
    __syncthreads();
    for (int i = start + threadIdx.x; i < end; i += 512) {
        int d = load_idx(ei32, ei64, is64, (long long)N_EDGES + i);
        atomicAdd(&hist[d >> BKT_SHIFT], 1u);
    }
    __syncthreads();
    for (int k = threadIdx.x; k < K_BKT; k += 512) {
        unsigned c = hist[k];
        cur[k] = c ? atomicAdd(&gcur[k], c) : 0u;
    }
    __syncthreads();
    for (int i = start + threadIdx.x; i < end; i += 512) {
        int s = load_idx(ei32, ei64, is64, i);
        int d = load_idx(ei32, ei64, is64, (long long)N_EDGES + i);
        unsigned p = atomicAdd(&cur[d >> BKT_SHIFT], 1u);
        pairs[p] = (unsigned)s | ((unsigned)(d & (BKT_R - 1)) << 17);
    }
}

// ---------------------------------------------------------------------------
// Per-node degree from partitioned pairs (LDS counters), fused dinv write.
__global__ __launch_bounds__(256) void degdinv_kernel(const unsigned* __restrict__ pairs,
                                                      const unsigned* __restrict__ bbase,
                                                      float* __restrict__ dinv) {
    __shared__ unsigned cnt[BKT_R];
    const int k = blockIdx.x;
    if (threadIdx.x < BKT_R) cnt[threadIdx.x] = 0u;
    __syncthreads();
    const unsigned segS = bbase[k], segE = bbase[k + 1];
    for (unsigned j = segS + threadIdx.x; j < segE; j += 256)
        atomicAdd(&cnt[pairs[j] >> 17], 1u);
    __syncthreads();
    if (threadIdx.x < BKT_R) {
        int n = k * BKT_R + threadIdx.x;
        if (n < N_NODES) dinv[n] = rsqrtf((float)(cnt[threadIdx.x] + 1u));
    }
}

// ---------------------------------------------------------------------------
// h = x @ W   [N_NODES,256] @ [256,64] fp32 (vector ALU; no fp32 MFMA on CDNA4)
__global__ __launch_bounds__(256) void gemm_kernel(const float* __restrict__ x,
                                                   const float* __restrict__ W,
                                                   float* __restrict__ h) {
    __shared__ float xl[16][IN_CH + 1];
    __shared__ float wl[64 * OUT_CH];
    const int tid = threadIdx.x;
    const int cg = tid & 15;
    const int rl = tid >> 4;

    for (int g = blockIdx.x; g < N_NODES / 16; g += gridDim.x) {
        const int row0 = g * 16;
        __syncthreads();
        #pragma unroll
        for (int i = 0; i < 4; ++i) {
            int f4 = tid + i * 256;
            int r  = f4 >> 6;
            int kk = (f4 & 63) * 4;
            float4 v = *(const float4*)&x[(size_t)(row0 + r) * IN_CH + kk];
            xl[r][kk] = v.x; xl[r][kk + 1] = v.y; xl[r][kk + 2] = v.z; xl[r][kk + 3] = v.w;
        }
        float4 acc = {0.f, 0.f, 0.f, 0.f};
        for (int c4 = 0; c4 < IN_CH / 64; ++c4) {
            __syncthreads();
            #pragma unroll
            for (int i = 0; i < 4; ++i) {
                int f4 = tid + i * 256;
                int kk = f4 >> 4;
                int cc = (f4 & 15) * 4;
                *(float4*)&wl[kk * OUT_CH + cc] =
                    *(const float4*)&W[(size_t)(c4 * 64 + kk) * OUT_CH + cc];
            }
            __syncthreads();
            #pragma unroll 8
            for (int kk = 0; kk < 64; ++kk) {
                float xv = xl[rl][c4 * 64 + kk];
                float4 w4 = *(const float4*)&wl[kk * OUT_CH + cg * 4];
                acc.x = fmaf(xv, w4.x, acc.x);
                acc.y = fmaf(xv, w4.y, acc.y);
                acc.z = fmaf(xv, w4.z, acc.z);
                acc.w = fmaf(xv, w4.w, acc.w);
            }
        }
        *(float4*)&h[(size_t)(row0 + rl) * OUT_CH + cg * 4] = acc;
    }
}

// ---------------------------------------------------------------------------
// One block per bucket: LDS [128][64] fp32 accumulator, ds_add_f32 per edge,
// fused self-loop + bias + relu + log_softmax epilogue, coalesced out write.
__global__ __launch_bounds__(512) void reduce2_kernel(const float* __restrict__ h,
                                                      const float* __restrict__ dinv,
                                                      const unsigned* __restrict__ bbase,
                                                      const unsigned* __restrict__ pairs,
                                                      const float* __restrict__ b,
                                                      float* __restrict__ out) {
    __shared__ float acc[BKT_R * OUT_CH];   // 32 KB
    const int k = blockIdx.x;
    const int tid = threadIdx.x;
    const int lane = tid & 63;
    const int w = tid >> 6;                 // 8 waves

    for (int i = tid; i < BKT_R * OUT_CH / 4; i += 512)
        *(float4*)&acc[i * 4] = make_float4(0.f, 0.f, 0.f, 0.f);
    __syncthreads();

    const unsigned segS = bbase[k], segE = bbase[k + 1];
    for (unsigned j0 = segS + (unsigned)w * 4; j0 < segE; j0 += 32) {
        if (j0 + 4 <= segE) {
            unsigned p0 = pairs[j0], p1 = pairs[j0 + 1], p2 = pairs[j0 + 2], p3 = pairs[j0 + 3];
            int s0 = p0 & 0x1FFFF, s1 = p1 & 0x1FFFF, s2 = p2 & 0x1FFFF, s3 = p3 & 0x1FFFF;
            float f0 = dinv[s0], f1 = dinv[s1], f2 = dinv[s2], f3 = dinv[s3];
            float h0 = h[(size_t)s0 * OUT_CH + lane];
            float h1 = h[(size_t)s1 * OUT_CH + lane];
            float h2 = h[(size_t)s2 * OUT_CH + lane];
            float h3 = h[(size_t)s3 * OUT_CH + lane];
            atomicAdd(&acc[(p0 >> 17) * OUT_CH + lane], h0 * f0);
            atomicAdd(&acc[(p1 >> 17) * OUT_CH + lane], h1 * f1);
            atomicAdd(&acc[(p2 >> 17) * OUT_CH + lane], h2 * f2);
            atomicAdd(&acc[(p3 >> 17) * OUT_CH + lane], h3 * f3);
        } else {
            for (unsigned j = j0; j < segE; ++j) {
                unsigned p = pairs[j];
                int s = p & 0x1FFFF;
                atomicAdd(&acc[(p >> 17) * OUT_CH + lane],
                          h[(size_t)s * OUT_CH + lane] * dinv[s]);
            }
        }
    }
    __syncthreads();

    const float bias = b[lane];
    for (int r = w; r < BKT_R; r += 8) {
        int n = k * BKT_R + r;
        if (n >= N_NODES) break;
        float dn = dinv[n];
        float v = fmaf(acc[r * OUT_CH + lane] + h[(size_t)n * OUT_CH + lane] * dn, dn, bias);
        v = fmaxf(v, 0.f);
        float m = v;
        #pragma unroll
        for (int o = 32; o; o >>= 1) m = fmaxf(m, __shfl_xor(m, o));
        float ex = expf(v - m);
        float sum = ex;
        #pragma unroll
        for (int o = 32; o; o >>= 1) sum += __shfl_xor(sum, o);
        out[(size_t)n * OUT_CH + lane] = (v - m) - logf(sum);
    }
}

// ---------------------------------------------------------------------------
// Fallback (atomic scatter) path, only if ws is too small for the bucket path.
__global__ __launch_bounds__(256) void deg_kernel(const int* __restrict__ ei32,
                                                  const long long* __restrict__ ei64,
                                                  const int* __restrict__ flag,
                                                  unsigned* __restrict__ deg) {
    const bool is64 = (*flag != 0);
    int i = blockIdx.x * blockDim.x + threadIdx.x;
    const int stride = gridDim.x * blockDim.x;
    for (; i < N_EDGES; i += stride) {
        int d = load_idx(ei32, ei64, is64, (long long)N_EDGES + i);
        atomicAdd(&deg[d], 1u);
    }
}

__global__ __launch_bounds__(256) void dinv_kernel(const unsigned* __restrict__ deg,
                                                   float* __restrict__ dinv) {
    int i = blockIdx.x * blockDim.x + threadIdx.x;
    if (i < N_NODES) dinv[i] = rsqrtf((float)(deg[i] + 1u));
}

__global__ __launch_bounds__(256) void scatter_kernel(const int* __restrict__ ei32,
                                                      const long long* __restrict__ ei64,
                                                      const int* __restrict__ flag,
                                                      const float* __restrict__ h,
                                                      const float* __restrict__ dinv,
                                                      float* __restrict__ out) {
    const bool is64 = (*flag != 0);
    const int lane = threadIdx.x & 63;
    int w = blockIdx.x * (blockDim.x >> 6) + (threadIdx.x >> 6);
    const int nw = gridDim.x * (blockDim.x >> 6);
    for (int e = w; e < N_EDGES; e += nw) {
        int s = load_idx(ei32, ei64, is64, e);
        int d = load_idx(ei32, ei64, is64, (long long)N_EDGES + e);
        float nrm = dinv[s] * dinv[d];
        atomicAdd(&out[(size_t)d * OUT_CH + lane], h[(size_t)s * OUT_CH + lane] * nrm);
    }
}

__global__ __launch_bounds__(256) void final_kernel(const float* __restrict__ h,
                                                    const float* __restrict__ dinv,
                                                    const float* __restrict__ b,
                                                    float* __restrict__ out) {
    const int lane = threadIdx.x & 63;
    int w = blockIdx.x * (blockDim.x >> 6) + (threadIdx.x >> 6);
    const int nw = gridDim.x * (blockDim.x >> 6);
    const float bias = b[lane];
    for (int n = w; n < N_NODES; n += nw) {
        float di = dinv[n];
        float v = out[(size_t)n * OUT_CH + lane]
                + h[(size_t)n * OUT_CH + lane] * di * di + bias;
        v = fmaxf(v, 0.f);
        float m = v;
        #pragma unroll
        for (int o = 32; o; o >>= 1) m = fmaxf(m, __shfl_xor(m, o));
        float ex = expf(v - m);
        float sum = ex;
        #pragma unroll
        for (int o = 32; o; o >>= 1) sum += __shfl_xor(sum, o);
        out[(size_t)n * OUT_CH + lane] = (v - m) - logf(sum);
    }
}

// ---------------------------------------------------------------------------
extern "C" void kernel_launch(void* const* d_in, const int* in_sizes, int n_in,
                              void* d_out, int out_size, void* d_ws, size_t ws_size,
                              hipStream_t stream) {
    const float* x  = (const float*)d_in[0];
    const void*  ei = d_in[1];
    const float* W  = (const float*)d_in[2];
    const float* b  = (const float*)d_in[3];
    float* out = (float*)d_out;

    char* ws = (char*)d_ws;
    int*      flag  = (int*)(ws + WS_FLAG_OFF);
    unsigned* bcnt  = (unsigned*)(ws + WS_BCNT_OFF);
    unsigned* bbase = (unsigned*)(ws + WS_BBASE_OFF);
    unsigned* gcur  = (unsigned*)(ws + WS_GCUR_OFF);
    float*    dinv  = (float*)(ws + WS_DINV_OFF);
    unsigned* pairs = (unsigned*)(ws + WS_PAIRS_OFF);
    float*    h     = (float*)(ws + WS_H_OFF);

    const int* ei32       = (const int*)ei;
    const long long* ei64 = (const long long*)ei;

    probe_kernel<<<1, 64, 0, stream>>>((const unsigned*)ei, flag);

    if (ws_size >= (size_t)WS_NEED) {
        hipMemsetAsync(bcnt, 0, 4096, stream);
        bcount_kernel<<<1024, 256, 0, stream>>>(ei32, ei64, flag, bcnt);
        bscan_kernel<<<1, 1024, 0, stream>>>(bcnt, bbase, gcur);
        gemm_kernel<<<2048, 256, 0, stream>>>(x, W, h);
        partition_kernel<<<NBLK_PART, 512, 0, stream>>>(ei32, ei64, flag, gcur, pairs);
        degdinv_kernel<<<K_BKT, 256, 0, stream>>>(pairs, bbase, dinv);
        reduce2_kernel<<<K_BKT, 512, 0, stream>>>(h, dinv, bbase, pairs, b, out);
    } else {
        // fallback: atomic scatter (needs flag + dinv + pairs-region-as-deg + h)
        unsigned* deg = (unsigned*)(ws + WS_PAIRS_OFF);
        hipMemsetAsync(deg, 0, (size_t)N_NODES * sizeof(unsigned), stream);
        hipMemsetAsync(d_out, 0, (size_t)out_size * sizeof(float), stream);
        deg_kernel<<<2048, 256, 0, stream>>>(ei32, ei64, flag, deg);
        dinv_kernel<<<(N_NODES + 255) / 256, 256, 0, stream>>>(deg, dinv);
        gemm_kernel<<<2048, 256, 0, stream>>>(x, W, h);
        scatter_kernel<<<2048, 256, 0, stream>>>(ei32, ei64, flag, h, dinv, out);
        final_kernel<<<1024, 256, 0, stream>>>(h, dinv, b, out);
    }
}

// Round 4
// 303.760 us; speedup vs baseline: 5.0043x; 5.0043x over previous
//
#include <hip/hip_runtime.h>
#include <cstddef>
#include <cstdint>

#define N_NODES 100000
#define IN_CH 256
#define OUT_CH 64
#define N_EDGES 3200000

// bucketing: 128 nodes per bucket
#define BKT_SHIFT 7
#define BKT_R     128
#define K_BKT     782                 // ceil(100000/128)
#define T_PART    8192                // edges per partition block
#define NBLK_PART ((N_EDGES + T_PART - 1) / T_PART)   // 391

// ---- ws layout (bytes), packed to stay under observed-available ~39.6MB ----
#define WS_FLAG_OFF   0
#define WS_BCNT_OFF   64
#define WS_BBASE_OFF  3264
#define WS_GCUR_OFF   6400
#define WS_DINV_OFF   9600
#define WS_NOFF_OFF   409600
#define WS_PAIRS_OFF  809728
#define WS_SSRC_OFF   13609728
#define WS_H_OFF      26409728        // bf16 h: 100000*64*2 = 12.8MB
#define WS_NEED       39209728

// ---- fallback (atomic) layout ----
#define WSF_DEG_OFF   4096
#define WSF_DINV_OFF  404096
#define WSF_H_OFF     804096
#define WSF_NEED      13604096

// ---------------------------------------------------------------------------
static __device__ __forceinline__ unsigned short f2bf(float f) {
    unsigned u = __builtin_bit_cast(unsigned, f);
    u += 0x7FFFu + ((u >> 16) & 1u);     // round-to-nearest-even (finite inputs)
    return (unsigned short)(u >> 16);
}
static __device__ __forceinline__ float bf2f(unsigned short s) {
    unsigned u = (unsigned)s << 16;
    return __builtin_bit_cast(float, u);
}

// ---------------------------------------------------------------------------
__global__ void probe_kernel(const unsigned* __restrict__ ei, int* __restrict__ flag) {
    if (blockIdx.x == 0 && threadIdx.x == 0) {
        int all0 = 1;
        for (int i = 0; i < 16; ++i) all0 &= (ei[2 * i + 1] == 0u);
        *flag = all0;  // 1 => int64 layout, 0 => int32 layout
    }
}

__device__ __forceinline__ int load_idx(const int* ei32, const long long* ei64,
                                        bool is64, long long pos) {
    return is64 ? (int)ei64[pos] : ei32[pos];
}

// ---------------------------------------------------------------------------
// Per-bucket edge counts (782 bins) via per-block LDS histogram.
__global__ __launch_bounds__(256) void bcount_kernel(const int* __restrict__ ei32,
                                                     const long long* __restrict__ ei64,
                                                     const int* __restrict__ flag,
                                                     unsigned* __restrict__ bcount) {
    __shared__ unsigned hist[K_BKT];
    const bool is64 = (*flag != 0);
    for (int k = threadIdx.x; k < K_BKT; k += 256) hist[k] = 0u;
    __syncthreads();
    int i = blockIdx.x * 256 + threadIdx.x;
    const int stride = gridDim.x * 256;
    for (; i < N_EDGES; i += stride) {
        int d = load_idx(ei32, ei64, is64, (long long)N_EDGES + i);
        atomicAdd(&hist[d >> BKT_SHIFT], 1u);
    }
    __syncthreads();
    for (int k = threadIdx.x; k < K_BKT; k += 256) {
        unsigned c = hist[k];
        if (c) atomicAdd(&bcount[k], c);
    }
}

// Exclusive scan of the 782 bucket counts; writes bbase[0..K], inits gcur,
// and seeds noff[N_NODES] = N_EDGES (global CSR terminator).
__global__ __launch_bounds__(1024) void bscan_kernel(const unsigned* __restrict__ bcount,
                                                     unsigned* __restrict__ bbase,
                                                     unsigned* __restrict__ gcur,
                                                     unsigned* __restrict__ noff) {
    __shared__ unsigned s[1024];
    const int t = threadIdx.x;
    unsigned v = (t < K_BKT) ? bcount[t] : 0u;
    s[t] = v; __syncthreads();
    #pragma unroll
    for (int d = 1; d < 1024; d <<= 1) {
        unsigned x = (t >= d) ? s[t - d] : 0u; __syncthreads();
        s[t] += x; __syncthreads();
    }
    if (t < K_BKT) {
        unsigned excl = s[t] - v;
        bbase[t] = excl;
        gcur[t]  = excl;
        if (t == K_BKT - 1) bbase[K_BKT] = s[t];
    }
    if (t == 0) noff[N_NODES] = N_EDGES;
}

// ---------------------------------------------------------------------------
// Partition edges into dst-range buckets; writes are block-clustered per
// bucket run so L2 merges them into near-full lines. pair = src | dLocal<<17
__global__ __launch_bounds__(512) void partition_kernel(const int* __restrict__ ei32,
                                                        const long long* __restrict__ ei64,
                                                        const int* __restrict__ flag,
                                                        unsigned* __restrict__ gcur,
                                                        unsigned* __restrict__ pairs) {
    __shared__ unsigned hist[K_BKT];
    __shared__ unsigned cur[K_BKT];
    const bool is64 = (*flag != 0);
    const int start = blockIdx.x * T_PART;
    const int end   = min(start + T_PART, N_EDGES);

    for (int k = threadIdx.x; k < K_BKT; k += 512) hist[k] = 0u;
    __syncthreads();
    for (int i = start + threadIdx.x; i < end; i += 512) {
        int d = load_idx(ei32, ei64, is64, (long long)N_EDGES + i);
        atomicAdd(&hist[d >> BKT_SHIFT], 1u);
    }
    __syncthreads();
    for (int k = threadIdx.x; k < K_BKT; k += 512) {
        unsigned c = hist[k];
        cur[k] = c ? atomicAdd(&gcur[k], c) : 0u;
    }
    __syncthreads();
    for (int i = start + threadIdx.x; i < end; i += 512) {
        int s = load_idx(ei32, ei64, is64, i);
        int d = load_idx(ei32, ei64, is64, (long long)N_EDGES + i);
        unsigned p = atomicAdd(&cur[d >> BKT_SHIFT], 1u);
        pairs[p] = (unsigned)s | ((unsigned)(d & (BKT_R - 1)) << 17);
    }
}

// ---------------------------------------------------------------------------
// Within-bucket counting sort to exact per-node CSR. One block per bucket;
// reads/writes are contiguous in [segS,segE). Emits noff (CSR starts) + dinv.
__global__ __launch_bounds__(256) void sort2_kernel(const unsigned* __restrict__ pairs,
                                                    const unsigned* __restrict__ bbase,
                                                    int* __restrict__ ssrc,
                                                    unsigned* __restrict__ noff,
                                                    float* __restrict__ dinv) {
    __shared__ unsigned hist[BKT_R];
    __shared__ unsigned cur[BKT_R];
    const int k = blockIdx.x;
    const int t = threadIdx.x;
    const unsigned segS = bbase[k], segE = bbase[k + 1];

    if (t < BKT_R) hist[t] = 0u;
    __syncthreads();
    for (unsigned j = segS + t; j < segE; j += 256)
        atomicAdd(&hist[pairs[j] >> 17], 1u);
    __syncthreads();
    // Hillis-Steele inclusive scan of hist into cur
    if (t < BKT_R) cur[t] = hist[t];
    __syncthreads();
    #pragma unroll
    for (int d = 1; d < BKT_R; d <<= 1) {
        unsigned x = (t < BKT_R && t >= d) ? cur[t - d] : 0u;
        __syncthreads();
        if (t < BKT_R) cur[t] += x;
        __syncthreads();
    }
    if (t < BKT_R) {
        unsigned mydeg = hist[t];
        unsigned start = segS + cur[t] - mydeg;   // exclusive
        int n = k * BKT_R + t;
        if (n < N_NODES) {
            noff[n] = start;
            dinv[n] = rsqrtf((float)(mydeg + 1u));
        }
        cur[t] = start;  // running cursor
    }
    __syncthreads();
    for (unsigned j = segS + t; j < segE; j += 256) {
        unsigned p = pairs[j];
        unsigned pos = atomicAdd(&cur[p >> 17], 1u);
        ssrc[pos] = (int)(p & 0x1FFFF);
    }
}

// ---------------------------------------------------------------------------
// h = x @ W   [N_NODES,256]@[256,64] fp32 compute, bf16 store.
__global__ __launch_bounds__(256) void gemm_kernel(const float* __restrict__ x,
                                                   const float* __restrict__ W,
                                                   unsigned short* __restrict__ h) {
    __shared__ float xl[16][IN_CH + 1];
    __shared__ float wl[64 * OUT_CH];
    const int tid = threadIdx.x;
    const int cg = tid & 15;
    const int rl = tid >> 4;

    for (int g = blockIdx.x; g < N_NODES / 16; g += gridDim.x) {
        const int row0 = g * 16;
        __syncthreads();
        #pragma unroll
        for (int i = 0; i < 4; ++i) {
            int f4 = tid + i * 256;
            int r  = f4 >> 6;
            int kk = (f4 & 63) * 4;
            float4 v = *(const float4*)&x[(size_t)(row0 + r) * IN_CH + kk];
            xl[r][kk] = v.x; xl[r][kk + 1] = v.y; xl[r][kk + 2] = v.z; xl[r][kk + 3] = v.w;
        }
        float4 acc = {0.f, 0.f, 0.f, 0.f};
        for (int c4 = 0; c4 < IN_CH / 64; ++c4) {
            __syncthreads();
            #pragma unroll
            for (int i = 0; i < 4; ++i) {
                int f4 = tid + i * 256;
                int kk = f4 >> 4;
                int cc = (f4 & 15) * 4;
                *(float4*)&wl[kk * OUT_CH + cc] =
                    *(const float4*)&W[(size_t)(c4 * 64 + kk) * OUT_CH + cc];
            }
            __syncthreads();
            #pragma unroll 8
            for (int kk = 0; kk < 64; ++kk) {
                float xv = xl[rl][c4 * 64 + kk];
                float4 w4 = *(const float4*)&wl[kk * OUT_CH + cg * 4];
                acc.x = fmaf(xv, w4.x, acc.x);
                acc.y = fmaf(xv, w4.y, acc.y);
                acc.z = fmaf(xv, w4.z, acc.z);
                acc.w = fmaf(xv, w4.w, acc.w);
            }
        }
        ushort4 pk;
        pk.x = f2bf(acc.x); pk.y = f2bf(acc.y); pk.z = f2bf(acc.z); pk.w = f2bf(acc.w);
        *(ushort4*)&h[(size_t)(row0 + rl) * OUT_CH + cg * 4] = pk;
    }
}

// ---------------------------------------------------------------------------
// Wave per node: CSR segmented reduction + fused bias/relu/log_softmax.
__global__ __launch_bounds__(256) void reduce_kernel(const unsigned short* __restrict__ h,
                                                     const float* __restrict__ dinv,
                                                     const unsigned* __restrict__ noff,
                                                     const int* __restrict__ ssrc,
                                                     const float* __restrict__ b,
                                                     float* __restrict__ out) {
    const int n = blockIdx.x * 4 + (threadIdx.x >> 6);
    const int lane = threadIdx.x & 63;
    if (n >= N_NODES) return;
    const float dn = dinv[n];
    float acc = bf2f(h[(size_t)n * OUT_CH + lane]) * dn;   // self-loop
    unsigned j = noff[n];
    const unsigned end = noff[n + 1];
    for (; j + 4 <= end; j += 4) {
        int s0 = ssrc[j], s1 = ssrc[j + 1], s2 = ssrc[j + 2], s3 = ssrc[j + 3];
        float f0 = dinv[s0], f1 = dinv[s1], f2 = dinv[s2], f3 = dinv[s3];
        float h0 = bf2f(h[(size_t)s0 * OUT_CH + lane]);
        float h1 = bf2f(h[(size_t)s1 * OUT_CH + lane]);
        float h2 = bf2f(h[(size_t)s2 * OUT_CH + lane]);
        float h3 = bf2f(h[(size_t)s3 * OUT_CH + lane]);
        acc = fmaf(h0, f0, acc);
        acc = fmaf(h1, f1, acc);
        acc = fmaf(h2, f2, acc);
        acc = fmaf(h3, f3, acc);
    }
    for (; j < end; ++j) {
        int s = ssrc[j];
        acc = fmaf(bf2f(h[(size_t)s * OUT_CH + lane]), dinv[s], acc);
    }
    float v = fmaf(acc, dn, b[lane]);
    v = fmaxf(v, 0.f);
    float m = v;
    #pragma unroll
    for (int o = 32; o; o >>= 1) m = fmaxf(m, __shfl_xor(m, o));
    float ex = expf(v - m);
    float sum = ex;
    #pragma unroll
    for (int o = 32; o; o >>= 1) sum += __shfl_xor(sum, o);
    out[(size_t)n * OUT_CH + lane] = (v - m) - logf(sum);
}

// ---------------------------------------------------------------------------
// Fallback (atomic scatter) path, only if ws is too small for the CSR path.
__global__ __launch_bounds__(256) void deg_kernel(const int* __restrict__ ei32,
                                                  const long long* __restrict__ ei64,
                                                  const int* __restrict__ flag,
                                                  unsigned* __restrict__ deg) {
    const bool is64 = (*flag != 0);
    int i = blockIdx.x * blockDim.x + threadIdx.x;
    const int stride = gridDim.x * blockDim.x;
    for (; i < N_EDGES; i += stride) {
        int d = load_idx(ei32, ei64, is64, (long long)N_EDGES + i);
        atomicAdd(&deg[d], 1u);
    }
}

__global__ __launch_bounds__(256) void dinv_kernel(const unsigned* __restrict__ deg,
                                                   float* __restrict__ dinv) {
    int i = blockIdx.x * blockDim.x + threadIdx.x;
    if (i < N_NODES) dinv[i] = rsqrtf((float)(deg[i] + 1u));
}

__global__ __launch_bounds__(256) void scatter_kernel(const int* __restrict__ ei32,
                                                      const long long* __restrict__ ei64,
                                                      const int* __restrict__ flag,
                                                      const unsigned short* __restrict__ h,
                                                      const float* __restrict__ dinv,
                                                      float* __restrict__ out) {
    const bool is64 = (*flag != 0);
    const int lane = threadIdx.x & 63;
    int w = blockIdx.x * (blockDim.x >> 6) + (threadIdx.x >> 6);
    const int nw = gridDim.x * (blockDim.x >> 6);
    for (int e = w; e < N_EDGES; e += nw) {
        int s = load_idx(ei32, ei64, is64, e);
        int d = load_idx(ei32, ei64, is64, (long long)N_EDGES + e);
        float nrm = dinv[s] * dinv[d];
        atomicAdd(&out[(size_t)d * OUT_CH + lane], bf2f(h[(size_t)s * OUT_CH + lane]) * nrm);
    }
}

__global__ __launch_bounds__(256) void final_kernel(const unsigned short* __restrict__ h,
                                                    const float* __restrict__ dinv,
                                                    const float* __restrict__ b,
                                                    float* __restrict__ out) {
    const int lane = threadIdx.x & 63;
    int w = blockIdx.x * (blockDim.x >> 6) + (threadIdx.x >> 6);
    const int nw = gridDim.x * (blockDim.x >> 6);
    const float bias = b[lane];
    for (int n = w; n < N_NODES; n += nw) {
        float di = dinv[n];
        float v = out[(size_t)n * OUT_CH + lane]
                + bf2f(h[(size_t)n * OUT_CH + lane]) * di * di + bias;
        v = fmaxf(v, 0.f);
        float m = v;
        #pragma unroll
        for (int o = 32; o; o >>= 1) m = fmaxf(m, __shfl_xor(m, o));
        float ex = expf(v - m);
        float sum = ex;
        #pragma unroll
        for (int o = 32; o; o >>= 1) sum += __shfl_xor(sum, o);
        out[(size_t)n * OUT_CH + lane] = (v - m) - logf(sum);
    }
}

// ---------------------------------------------------------------------------
extern "C" void kernel_launch(void* const* d_in, const int* in_sizes, int n_in,
                              void* d_out, int out_size, void* d_ws, size_t ws_size,
                              hipStream_t stream) {
    const float* x  = (const float*)d_in[0];
    const void*  ei = d_in[1];
    const float* W  = (const float*)d_in[2];
    const float* b  = (const float*)d_in[3];
    float* out = (float*)d_out;

    char* ws = (char*)d_ws;
    int* flag = (int*)(ws + WS_FLAG_OFF);

    const int* ei32       = (const int*)ei;
    const long long* ei64 = (const long long*)ei;

    probe_kernel<<<1, 64, 0, stream>>>((const unsigned*)ei, flag);

    if (ws_size >= (size_t)WS_NEED) {
        unsigned* bcnt  = (unsigned*)(ws + WS_BCNT_OFF);
        unsigned* bbase = (unsigned*)(ws + WS_BBASE_OFF);
        unsigned* gcur  = (unsigned*)(ws + WS_GCUR_OFF);
        float*    dinv  = (float*)(ws + WS_DINV_OFF);
        unsigned* noff  = (unsigned*)(ws + WS_NOFF_OFF);
        unsigned* pairs = (unsigned*)(ws + WS_PAIRS_OFF);
        int*      ssrc  = (int*)(ws + WS_SSRC_OFF);
        unsigned short* h = (unsigned short*)(ws + WS_H_OFF);

        hipMemsetAsync(bcnt, 0, 3200, stream);
        bcount_kernel<<<1024, 256, 0, stream>>>(ei32, ei64, flag, bcnt);
        bscan_kernel<<<1, 1024, 0, stream>>>(bcnt, bbase, gcur, noff);
        gemm_kernel<<<2048, 256, 0, stream>>>(x, W, h);
        partition_kernel<<<NBLK_PART, 512, 0, stream>>>(ei32, ei64, flag, gcur, pairs);
        sort2_kernel<<<K_BKT, 256, 0, stream>>>(pairs, bbase, ssrc, noff, dinv);
        reduce_kernel<<<(N_NODES + 3) / 4, 256, 0, stream>>>(h, dinv, noff, ssrc, b, out);
    } else {
        unsigned* deg  = (unsigned*)(ws + WSF_DEG_OFF);
        float*    dinv = (float*)(ws + WSF_DINV_OFF);
        unsigned short* h = (unsigned short*)(ws + WSF_H_OFF);
        hipMemsetAsync(deg, 0, (size_t)N_NODES * sizeof(unsigned), stream);
        hipMemsetAsync(d_out, 0, (size_t)out_size * sizeof(float), stream);
        deg_kernel<<<2048, 256, 0, stream>>>(ei32, ei64, flag, deg);
        dinv_kernel<<<(N_NODES + 255) / 256, 256, 0, stream>>>(deg, dinv);
        gemm_kernel<<<2048, 256, 0, stream>>>(x, W, h);
        scatter_kernel<<<2048, 256, 0, stream>>>(ei32, ei64, flag, h, dinv, out);
        final_kernel<<<1024, 256, 0, stream>>>(h, dinv, b, out);
    }
}

// Round 5
// 267.432 us; speedup vs baseline: 5.6840x; 1.1358x over previous
//
#include <hip/hip_runtime.h>
#include <cstddef>
#include <cstdint>

#define N_NODES 100000
#define IN_CH 256
#define OUT_CH 64
#define N_EDGES 3200000

// bucketing: 128 nodes per bucket
#define BKT_SHIFT 7
#define BKT_R     128
#define K_BKT     782                 // ceil(100000/128)
#define T_PART    8192                // edges per partition block
#define NBLK_PART ((N_EDGES + T_PART - 1) / T_PART)   // 391

// ---- ws layout (bytes) ----
#define WS_FLAG_OFF   0
#define WS_BBASE_OFF  3264
#define WS_DINV_OFF   9600
#define WS_NOFF_OFF   409600
#define WS_PAIRS_OFF  809728
#define WS_SSRC_OFF   13609728        // aliased: hist2d (1.23MB) lives here until sort2
#define WS_H_OFF      26409728        // bf16 h: 100000*64*2 = 12.8MB
#define WS_NEED       39209728

// ---- fallback (atomic) layout ----
#define WSF_DEG_OFF   4096
#define WSF_DINV_OFF  404096
#define WSF_H_OFF     804096

// ---------------------------------------------------------------------------
static __device__ __forceinline__ unsigned short f2bf(float f) {
    unsigned u = __builtin_bit_cast(unsigned, f);
    u += 0x7FFFu + ((u >> 16) & 1u);     // round-to-nearest-even (finite inputs)
    return (unsigned short)(u >> 16);
}
static __device__ __forceinline__ float bflo(unsigned u) {
    return __builtin_bit_cast(float, u << 16);
}
static __device__ __forceinline__ float bfhi(unsigned u) {
    return __builtin_bit_cast(float, u & 0xFFFF0000u);
}

// ---------------------------------------------------------------------------
__global__ void probe_kernel(const unsigned* __restrict__ ei, int* __restrict__ flag) {
    if (blockIdx.x == 0 && threadIdx.x == 0) {
        int all0 = 1;
        for (int i = 0; i < 16; ++i) all0 &= (ei[2 * i + 1] == 0u);
        *flag = all0;  // 1 => int64 layout, 0 => int32 layout
    }
}

__device__ __forceinline__ int load_idx(const int* ei32, const long long* ei64,
                                        bool is64, long long pos) {
    return is64 ? (int)ei64[pos] : ei32[pos];
}

// ---------------------------------------------------------------------------
// Per-(block,bucket) histogram rows; NO global atomics.
__global__ __launch_bounds__(256) void bcount_kernel(const int* __restrict__ ei32,
                                                     const long long* __restrict__ ei64,
                                                     const int* __restrict__ flag,
                                                     unsigned* __restrict__ hist2d) {
    __shared__ unsigned hist[K_BKT];
    const bool is64 = (*flag != 0);
    const int start = blockIdx.x * T_PART;
    const int end   = min(start + T_PART, N_EDGES);
    for (int k = threadIdx.x; k < K_BKT; k += 256) hist[k] = 0u;
    __syncthreads();
    for (int i = start + threadIdx.x; i < end; i += 256) {
        int d = load_idx(ei32, ei64, is64, (long long)N_EDGES + i);
        atomicAdd(&hist[d >> BKT_SHIFT], 1u);
    }
    __syncthreads();
    for (int k = threadIdx.x; k < K_BKT; k += 256)
        hist2d[(size_t)blockIdx.x * K_BKT + k] = hist[k];
}

// Single block: bucket totals -> exclusive scan -> rewrite hist2d rows to
// per-(block,bucket) running bases. Also emits bbase[] and noff terminator.
__global__ __launch_bounds__(1024) void bscan2_kernel(unsigned* __restrict__ hist2d,
                                                      unsigned* __restrict__ bbase,
                                                      unsigned* __restrict__ noff) {
    __shared__ unsigned s[1024];
    const int t = threadIdx.x;
    unsigned tot = 0u;
    if (t < K_BKT) {
        #pragma unroll 4
        for (int blk = 0; blk < NBLK_PART; ++blk)
            tot += hist2d[(size_t)blk * K_BKT + t];
    }
    s[t] = (t < K_BKT) ? tot : 0u; __syncthreads();
    #pragma unroll
    for (int d = 1; d < 1024; d <<= 1) {
        unsigned x = (t >= d) ? s[t - d] : 0u; __syncthreads();
        s[t] += x; __syncthreads();
    }
    if (t < K_BKT) {
        unsigned excl = s[t] - tot;
        bbase[t] = excl;
        if (t == K_BKT - 1) bbase[K_BKT] = s[t];
        unsigned run = excl;
        for (int blk = 0; blk < NBLK_PART; ++blk) {
            unsigned c = hist2d[(size_t)blk * K_BKT + t];
            hist2d[(size_t)blk * K_BKT + t] = run;
            run += c;
        }
    }
    if (t == 0) noff[N_NODES] = N_EDGES;
}

// ---------------------------------------------------------------------------
// Partition edges into dst-range buckets using precomputed per-block bases.
// pair = src | dLocal<<17. Writes are block-clustered (L2-merged).
__global__ __launch_bounds__(512) void partition_kernel(const int* __restrict__ ei32,
                                                        const long long* __restrict__ ei64,
                                                        const int* __restrict__ flag,
                                                        const unsigned* __restrict__ hist2d,
                                                        unsigned* __restrict__ pairs) {
    __shared__ unsigned cur[K_BKT];
    const bool is64 = (*flag != 0);
    const int start = blockIdx.x * T_PART;
    const int end   = min(start + T_PART, N_EDGES);
    for (int k = threadIdx.x; k < K_BKT; k += 512)
        cur[k] = hist2d[(size_t)blockIdx.x * K_BKT + k];
    __syncthreads();
    for (int i = start + threadIdx.x; i < end; i += 512) {
        int s = load_idx(ei32, ei64, is64, i);
        int d = load_idx(ei32, ei64, is64, (long long)N_EDGES + i);
        unsigned p = atomicAdd(&cur[d >> BKT_SHIFT], 1u);
        pairs[p] = (unsigned)s | ((unsigned)(d & (BKT_R - 1)) << 17);
    }
}

// ---------------------------------------------------------------------------
// Within-bucket counting sort to exact per-node CSR + noff + dinv.
__global__ __launch_bounds__(256) void sort2_kernel(const unsigned* __restrict__ pairs,
                                                    const unsigned* __restrict__ bbase,
                                                    int* __restrict__ ssrc,
                                                    unsigned* __restrict__ noff,
                                                    float* __restrict__ dinv) {
    __shared__ unsigned hist[BKT_R];
    __shared__ unsigned cur[BKT_R];
    const int k = blockIdx.x;
    const int t = threadIdx.x;
    const unsigned segS = bbase[k], segE = bbase[k + 1];

    if (t < BKT_R) hist[t] = 0u;
    __syncthreads();
    for (unsigned j = segS + t; j < segE; j += 256)
        atomicAdd(&hist[pairs[j] >> 17], 1u);
    __syncthreads();
    if (t < BKT_R) cur[t] = hist[t];
    __syncthreads();
    #pragma unroll
    for (int d = 1; d < BKT_R; d <<= 1) {
        unsigned x = (t < BKT_R && t >= d) ? cur[t - d] : 0u;
        __syncthreads();
        if (t < BKT_R) cur[t] += x;
        __syncthreads();
    }
    if (t < BKT_R) {
        unsigned mydeg = hist[t];
        unsigned start = segS + cur[t] - mydeg;   // exclusive
        int n = k * BKT_R + t;
        if (n < N_NODES) {
            noff[n] = start;
            dinv[n] = rsqrtf((float)(mydeg + 1u));
        }
        cur[t] = start;
    }
    __syncthreads();
    for (unsigned j = segS + t; j < segE; j += 256) {
        unsigned p = pairs[j];
        unsigned pos = atomicAdd(&cur[p >> 17], 1u);
        ssrc[pos] = (int)(p & 0x1FFFF);
    }
}

// ---------------------------------------------------------------------------
// h = x @ W: 64 rows x 64 ch per block, 4x4 register blocking per thread.
// LDS: xT[k][row] (transposed, padded) + wl[k][ch]; 2 b128 reads per 16 FMA.
__global__ __launch_bounds__(256) void gemm_kernel(const float* __restrict__ x,
                                                   const float* __restrict__ W,
                                                   unsigned short* __restrict__ h) {
    __shared__ float xT[64][68];   // 17.4 KB, stride 272B keeps float4 alignment
    __shared__ float wl[64][64];   // 16 KB
    const int tid = threadIdx.x;
    const int ri = tid & 15;       // rows 4ri..4ri+3
    const int cj = tid >> 4;       // ch 4cj..4cj+3
    const int nblk = (N_NODES + 63) / 64;

    for (int g = blockIdx.x; g < nblk; g += gridDim.x) {
        const int row0 = g * 64;
        float acc[4][4] = {{0.f}};
        for (int c4 = 0; c4 < IN_CH / 64; ++c4) {
            __syncthreads();
            #pragma unroll
            for (int it = 0; it < 4; ++it) {
                int f4 = tid + it * 256;
                int kk = f4 >> 4;
                int cc = (f4 & 15) * 4;
                *(float4*)&wl[kk][cc] =
                    *(const float4*)&W[(size_t)(c4 * 64 + kk) * OUT_CH + cc];
            }
            #pragma unroll
            for (int it = 0; it < 4; ++it) {
                int f4 = tid + it * 256;
                int r  = f4 >> 4;
                int k4 = (f4 & 15) * 4;
                int row = row0 + r; if (row >= N_NODES) row = N_NODES - 1;
                float4 v = *(const float4*)&x[(size_t)row * IN_CH + c4 * 64 + k4];
                xT[k4 + 0][r] = v.x; xT[k4 + 1][r] = v.y;
                xT[k4 + 2][r] = v.z; xT[k4 + 3][r] = v.w;
            }
            __syncthreads();
            #pragma unroll 4
            for (int k = 0; k < 64; ++k) {
                float4 a = *(const float4*)&xT[k][ri * 4];
                float4 w = *(const float4*)&wl[k][cj * 4];
                acc[0][0] = fmaf(a.x, w.x, acc[0][0]);
                acc[0][1] = fmaf(a.x, w.y, acc[0][1]);
                acc[0][2] = fmaf(a.x, w.z, acc[0][2]);
                acc[0][3] = fmaf(a.x, w.w, acc[0][3]);
                acc[1][0] = fmaf(a.y, w.x, acc[1][0]);
                acc[1][1] = fmaf(a.y, w.y, acc[1][1]);
                acc[1][2] = fmaf(a.y, w.z, acc[1][2]);
                acc[1][3] = fmaf(a.y, w.w, acc[1][3]);
                acc[2][0] = fmaf(a.z, w.x, acc[2][0]);
                acc[2][1] = fmaf(a.z, w.y, acc[2][1]);
                acc[2][2] = fmaf(a.z, w.z, acc[2][2]);
                acc[2][3] = fmaf(a.z, w.w, acc[2][3]);
                acc[3][0] = fmaf(a.w, w.x, acc[3][0]);
                acc[3][1] = fmaf(a.w, w.y, acc[3][1]);
                acc[3][2] = fmaf(a.w, w.z, acc[3][2]);
                acc[3][3] = fmaf(a.w, w.w, acc[3][3]);
            }
        }
        #pragma unroll
        for (int rr = 0; rr < 4; ++rr) {
            int row = row0 + ri * 4 + rr;
            if (row < N_NODES) {
                ushort4 pk;
                pk.x = f2bf(acc[rr][0]); pk.y = f2bf(acc[rr][1]);
                pk.z = f2bf(acc[rr][2]); pk.w = f2bf(acc[rr][3]);
                *(ushort4*)&h[(size_t)row * OUT_CH + cj * 4] = pk;
            }
        }
    }
}

// ---------------------------------------------------------------------------
// Wave per node, half-wave per edge: each 32-lane half gathers a packed-u32
// (2 bf16 ch) h row slice; one gather serves 2 edges per wave instruction.
__global__ __launch_bounds__(256) void reduce_kernel(const unsigned short* __restrict__ h,
                                                     const float* __restrict__ dinv,
                                                     const unsigned* __restrict__ noff,
                                                     const int* __restrict__ ssrc,
                                                     const float* __restrict__ b,
                                                     float* __restrict__ out) {
    const int n = blockIdx.x * 4 + (threadIdx.x >> 6);
    const int lane = threadIdx.x & 63;
    const int half = lane >> 5;
    const int l32 = lane & 31;
    if (n >= N_NODES) return;
    const unsigned* h32 = (const unsigned*)h;   // one row = 32 u32
    const float dn = dinv[n];
    float acc0 = 0.f, acc1 = 0.f;
    {   // self-loop counted once (half 0 only)
        unsigned sv = h32[(size_t)n * 32 + l32];
        if (half == 0) { acc0 = bflo(sv) * dn; acc1 = bfhi(sv) * dn; }
    }
    unsigned j = noff[n];
    const unsigned end = noff[n + 1];
    for (; j + 8 <= end; j += 8) {
        int s0 = ssrc[j + half],     s1 = ssrc[j + 2 + half];
        int s2 = ssrc[j + 4 + half], s3 = ssrc[j + 6 + half];
        float f0 = dinv[s0], f1 = dinv[s1], f2 = dinv[s2], f3 = dinv[s3];
        unsigned v0 = h32[(size_t)s0 * 32 + l32];
        unsigned v1 = h32[(size_t)s1 * 32 + l32];
        unsigned v2 = h32[(size_t)s2 * 32 + l32];
        unsigned v3 = h32[(size_t)s3 * 32 + l32];
        acc0 = fmaf(bflo(v0), f0, acc0); acc1 = fmaf(bfhi(v0), f0, acc1);
        acc0 = fmaf(bflo(v1), f1, acc0); acc1 = fmaf(bfhi(v1), f1, acc1);
        acc0 = fmaf(bflo(v2), f2, acc0); acc1 = fmaf(bfhi(v2), f2, acc1);
        acc0 = fmaf(bflo(v3), f3, acc0); acc1 = fmaf(bfhi(v3), f3, acc1);
    }
    for (; j + 2 <= end; j += 2) {
        int s = ssrc[j + half];
        float f = dinv[s];
        unsigned v = h32[(size_t)s * 32 + l32];
        acc0 = fmaf(bflo(v), f, acc0); acc1 = fmaf(bfhi(v), f, acc1);
    }
    if (j < end && half == 0) {
        int s = ssrc[j];
        float f = dinv[s];
        unsigned v = h32[(size_t)s * 32 + l32];
        acc0 = fmaf(bflo(v), f, acc0); acc1 = fmaf(bfhi(v), f, acc1);
    }
    acc0 += __shfl_xor(acc0, 32);
    acc1 += __shfl_xor(acc1, 32);
    // epilogue: bias + relu + log_softmax (2 ch per lane, duplicated halves)
    float2 bb = ((const float2*)b)[l32];
    float v0 = fmaf(acc0, dn, bb.x);
    float v1 = fmaf(acc1, dn, bb.y);
    v0 = fmaxf(v0, 0.f); v1 = fmaxf(v1, 0.f);
    float m = fmaxf(v0, v1);
    #pragma unroll
    for (int o = 16; o; o >>= 1) m = fmaxf(m, __shfl_xor(m, o));
    float sum = expf(v0 - m) + expf(v1 - m);
    #pragma unroll
    for (int o = 16; o; o >>= 1) sum += __shfl_xor(sum, o);
    float ls = logf(sum);
    if (half == 0) {
        float2 r; r.x = (v0 - m) - ls; r.y = (v1 - m) - ls;
        *(float2*)&out[(size_t)n * OUT_CH + 2 * l32] = r;
    }
}

// ---------------------------------------------------------------------------
// Fallback (atomic scatter) path, only if ws is too small for the CSR path.
__global__ __launch_bounds__(256) void deg_kernel(const int* __restrict__ ei32,
                                                  const long long* __restrict__ ei64,
                                                  const int* __restrict__ flag,
                                                  unsigned* __restrict__ deg) {
    const bool is64 = (*flag != 0);
    int i = blockIdx.x * blockDim.x + threadIdx.x;
    const int stride = gridDim.x * blockDim.x;
    for (; i < N_EDGES; i += stride) {
        int d = load_idx(ei32, ei64, is64, (long long)N_EDGES + i);
        atomicAdd(&deg[d], 1u);
    }
}

__global__ __launch_bounds__(256) void dinv_kernel(const unsigned* __restrict__ deg,
                                                   float* __restrict__ dinv) {
    int i = blockIdx.x * blockDim.x + threadIdx.x;
    if (i < N_NODES) dinv[i] = rsqrtf((float)(deg[i] + 1u));
}

__global__ __launch_bounds__(256) void scatter_kernel(const int* __restrict__ ei32,
                                                      const long long* __restrict__ ei64,
                                                      const int* __restrict__ flag,
                                                      const unsigned short* __restrict__ h,
                                                      const float* __restrict__ dinv,
                                                      float* __restrict__ out) {
    const bool is64 = (*flag != 0);
    const int lane = threadIdx.x & 63;
    int w = blockIdx.x * (blockDim.x >> 6) + (threadIdx.x >> 6);
    const int nw = gridDim.x * (blockDim.x >> 6);
    for (int e = w; e < N_EDGES; e += nw) {
        int s = load_idx(ei32, ei64, is64, e);
        int d = load_idx(ei32, ei64, is64, (long long)N_EDGES + e);
        float nrm = dinv[s] * dinv[d];
        float hv = bflo(((const unsigned short*)h)[(size_t)s * OUT_CH + lane] ? 0u : 0u);
        // (scalar path) load bf16 and widen:
        unsigned short us = h[(size_t)s * OUT_CH + lane];
        hv = __builtin_bit_cast(float, (unsigned)us << 16);
        atomicAdd(&out[(size_t)d * OUT_CH + lane], hv * nrm);
    }
}

__global__ __launch_bounds__(256) void final_kernel(const unsigned short* __restrict__ h,
                                                    const float* __restrict__ dinv,
                                                    const float* __restrict__ b,
                                                    float* __restrict__ out) {
    const int lane = threadIdx.x & 63;
    int w = blockIdx.x * (blockDim.x >> 6) + (threadIdx.x >> 6);
    const int nw = gridDim.x * (blockDim.x >> 6);
    const float bias = b[lane];
    for (int n = w; n < N_NODES; n += nw) {
        float di = dinv[n];
        unsigned short us = h[(size_t)n * OUT_CH + lane];
        float hv = __builtin_bit_cast(float, (unsigned)us << 16);
        float v = out[(size_t)n * OUT_CH + lane] + hv * di * di + bias;
        v = fmaxf(v, 0.f);
        float m = v;
        #pragma unroll
        for (int o = 32; o; o >>= 1) m = fmaxf(m, __shfl_xor(m, o));
        float ex = expf(v - m);
        float sum = ex;
        #pragma unroll
        for (int o = 32; o; o >>= 1) sum += __shfl_xor(sum, o);
        out[(size_t)n * OUT_CH + lane] = (v - m) - logf(sum);
    }
}

// ---------------------------------------------------------------------------
extern "C" void kernel_launch(void* const* d_in, const int* in_sizes, int n_in,
                              void* d_out, int out_size, void* d_ws, size_t ws_size,
                              hipStream_t stream) {
    const float* x  = (const float*)d_in[0];
    const void*  ei = d_in[1];
    const float* W  = (const float*)d_in[2];
    const float* b  = (const float*)d_in[3];
    float* out = (float*)d_out;

    char* ws = (char*)d_ws;
    int* flag = (int*)(ws + WS_FLAG_OFF);

    const int* ei32       = (const int*)ei;
    const long long* ei64 = (const long long*)ei;

    probe_kernel<<<1, 64, 0, stream>>>((const unsigned*)ei, flag);

    if (ws_size >= (size_t)WS_NEED) {
        unsigned* bbase  = (unsigned*)(ws + WS_BBASE_OFF);
        float*    dinv   = (float*)(ws + WS_DINV_OFF);
        unsigned* noff   = (unsigned*)(ws + WS_NOFF_OFF);
        unsigned* pairs  = (unsigned*)(ws + WS_PAIRS_OFF);
        unsigned* hist2d = (unsigned*)(ws + WS_SSRC_OFF);   // aliased with ssrc
        int*      ssrc   = (int*)(ws + WS_SSRC_OFF);
        unsigned short* h = (unsigned short*)(ws + WS_H_OFF);

        bcount_kernel<<<NBLK_PART, 256, 0, stream>>>(ei32, ei64, flag, hist2d);
        bscan2_kernel<<<1, 1024, 0, stream>>>(hist2d, bbase, noff);
        partition_kernel<<<NBLK_PART, 512, 0, stream>>>(ei32, ei64, flag, hist2d, pairs);
        sort2_kernel<<<K_BKT, 256, 0, stream>>>(pairs, bbase, ssrc, noff, dinv);
        gemm_kernel<<<1563, 256, 0, stream>>>(x, W, h);
        reduce_kernel<<<(N_NODES + 3) / 4, 256, 0, stream>>>(h, dinv, noff, ssrc, b, out);
    } else {
        unsigned* deg  = (unsigned*)(ws + WSF_DEG_OFF);
        float*    dinv = (float*)(ws + WSF_DINV_OFF);
        unsigned short* h = (unsigned short*)(ws + WSF_H_OFF);
        hipMemsetAsync(deg, 0, (size_t)N_NODES * sizeof(unsigned), stream);
        hipMemsetAsync(d_out, 0, (size_t)out_size * sizeof(float), stream);
        deg_kernel<<<2048, 256, 0, stream>>>(ei32, ei64, flag, deg);
        dinv_kernel<<<(N_NODES + 255) / 256, 256, 0, stream>>>(deg, dinv);
        gemm_kernel<<<1563, 256, 0, stream>>>(x, W, h);
        scatter_kernel<<<2048, 256, 0, stream>>>(ei32, ei64, flag, h, dinv, out);
        final_kernel<<<1024, 256, 0, stream>>>(h, dinv, b, out);
    }
}

// Round 6
// 218.163 us; speedup vs baseline: 6.9677x; 1.2258x over previous
//
#include <hip/hip_runtime.h>
#include <cstddef>
#include <cstdint>

#define N_NODES 100000
#define IN_CH 256
#define OUT_CH 64
#define N_EDGES 3200000

// bucketing: 128 nodes per bucket
#define BKT_SHIFT 7
#define BKT_R     128
#define K_BKT     782                 // ceil(100000/128)
#define T_PART    8192                // edges per partition block
#define NBLK_PART ((N_EDGES + T_PART - 1) / T_PART)   // 391

// ---- ws layout (bytes) ----
#define WS_FLAG_OFF   0
#define WS_BBASE_OFF  3264            // 783 u32
#define WS_BTOT_OFF   6400            // 782 u32
#define WS_DINV_OFF   9600
#define WS_NOFF_OFF   409600
#define WS_PAIRS_OFF  809728
#define WS_SSRC_OFF   13609728        // aliased: hist2d (1.23MB) lives here until sort2
#define WS_H_OFF      26409728        // bf16 hs: 100000*64*2 = 12.8MB
#define WS_NEED       39209728

// ---- fallback (atomic) layout ----
#define WSF_DEG_OFF   4096
#define WSF_DINV_OFF  404096
#define WSF_H_OFF     804096

typedef __attribute__((ext_vector_type(8))) short bshort8;
typedef __attribute__((ext_vector_type(4))) float f32x4;
typedef __attribute__((ext_vector_type(4))) unsigned u32x4;

// ---------------------------------------------------------------------------
static __device__ __forceinline__ unsigned short f2bf(float f) {
    unsigned u = __builtin_bit_cast(unsigned, f);
    u += 0x7FFFu + ((u >> 16) & 1u);     // RNE (finite inputs)
    return (unsigned short)(u >> 16);
}
static __device__ __forceinline__ float bflo(unsigned u) {
    return __builtin_bit_cast(float, u << 16);
}
static __device__ __forceinline__ float bfhi(unsigned u) {
    return __builtin_bit_cast(float, u & 0xFFFF0000u);
}

// ---------------------------------------------------------------------------
__global__ void probe_kernel(const unsigned* __restrict__ ei, int* __restrict__ flag) {
    if (blockIdx.x == 0 && threadIdx.x == 0) {
        int all0 = 1;
        for (int i = 0; i < 16; ++i) all0 &= (ei[2 * i + 1] == 0u);
        *flag = all0;  // 1 => int64 layout, 0 => int32 layout
    }
}

__device__ __forceinline__ int load_idx(const int* ei32, const long long* ei64,
                                        bool is64, long long pos) {
    return is64 ? (int)ei64[pos] : ei32[pos];
}

// ---------------------------------------------------------------------------
// Per-(block,bucket) histogram rows; NO global atomics.
__global__ __launch_bounds__(256) void bcount_kernel(const int* __restrict__ ei32,
                                                     const long long* __restrict__ ei64,
                                                     const int* __restrict__ flag,
                                                     unsigned* __restrict__ hist2d) {
    __shared__ unsigned hist[K_BKT];
    const bool is64 = (*flag != 0);
    const int start = blockIdx.x * T_PART;
    const int end   = min(start + T_PART, N_EDGES);
    for (int k = threadIdx.x; k < K_BKT; k += 256) hist[k] = 0u;
    __syncthreads();
    for (int i = start + threadIdx.x; i < end; i += 256) {
        int d = load_idx(ei32, ei64, is64, (long long)N_EDGES + i);
        atomicAdd(&hist[d >> BKT_SHIFT], 1u);
    }
    __syncthreads();
    for (int k = threadIdx.x; k < K_BKT; k += 256)
        hist2d[(size_t)blockIdx.x * K_BKT + k] = hist[k];
}

// wave-per-bucket totals
__global__ __launch_bounds__(256) void bscanA_kernel(const unsigned* __restrict__ hist2d,
                                                     unsigned* __restrict__ btot) {
    const int k = blockIdx.x * 4 + (threadIdx.x >> 6);
    const int lane = threadIdx.x & 63;
    if (k >= K_BKT) return;
    unsigned tot = 0u;
    for (int c = lane; c < NBLK_PART; c += 64)
        tot += hist2d[(size_t)c * K_BKT + k];
    #pragma unroll
    for (int o = 32; o; o >>= 1) tot += __shfl_xor(tot, o);
    if (lane == 0) btot[k] = tot;
}

// single block: exclusive scan of bucket totals -> bbase; seeds noff terminator
__global__ __launch_bounds__(1024) void bscanB_kernel(const unsigned* __restrict__ btot,
                                                      unsigned* __restrict__ bbase,
                                                      unsigned* __restrict__ noff) {
    __shared__ unsigned s[1024];
    const int t = threadIdx.x;
    unsigned v = (t < K_BKT) ? btot[t] : 0u;
    s[t] = v; __syncthreads();
    #pragma unroll
    for (int d = 1; d < 1024; d <<= 1) {
        unsigned x = (t >= d) ? s[t - d] : 0u; __syncthreads();
        s[t] += x; __syncthreads();
    }
    if (t < K_BKT) {
        bbase[t] = s[t] - v;
        if (t == K_BKT - 1) bbase[K_BKT] = s[t];
    }
    if (t == 0) noff[N_NODES] = N_EDGES;
}

// wave-per-bucket: rewrite hist2d rows to per-(block,bucket) running bases
__global__ __launch_bounds__(256) void bscanC_kernel(unsigned* __restrict__ hist2d,
                                                     const unsigned* __restrict__ bbase) {
    const int k = blockIdx.x * 4 + (threadIdx.x >> 6);
    const int lane = threadIdx.x & 63;
    if (k >= K_BKT) return;
    unsigned run = bbase[k];
    for (int c0 = 0; c0 < NBLK_PART; c0 += 64) {
        int blk = c0 + lane;
        unsigned v = (blk < NBLK_PART) ? hist2d[(size_t)blk * K_BKT + k] : 0u;
        unsigned incl = v;
        #pragma unroll
        for (int d = 1; d < 64; d <<= 1) {
            unsigned tq = __shfl_up(incl, d);
            if (lane >= d) incl += tq;
        }
        if (blk < NBLK_PART) hist2d[(size_t)blk * K_BKT + k] = run + incl - v;
        run += __shfl(incl, 63);
    }
}

// ---------------------------------------------------------------------------
// Partition edges into dst-range buckets using precomputed per-block bases.
__global__ __launch_bounds__(512) void partition_kernel(const int* __restrict__ ei32,
                                                        const long long* __restrict__ ei64,
                                                        const int* __restrict__ flag,
                                                        const unsigned* __restrict__ hist2d,
                                                        unsigned* __restrict__ pairs) {
    __shared__ unsigned cur[K_BKT];
    const bool is64 = (*flag != 0);
    const int start = blockIdx.x * T_PART;
    const int end   = min(start + T_PART, N_EDGES);
    for (int k = threadIdx.x; k < K_BKT; k += 512)
        cur[k] = hist2d[(size_t)blockIdx.x * K_BKT + k];
    __syncthreads();
    for (int i = start + threadIdx.x; i < end; i += 512) {
        int s = load_idx(ei32, ei64, is64, i);
        int d = load_idx(ei32, ei64, is64, (long long)N_EDGES + i);
        unsigned p = atomicAdd(&cur[d >> BKT_SHIFT], 1u);
        pairs[p] = (unsigned)s | ((unsigned)(d & (BKT_R - 1)) << 17);
    }
}

// ---------------------------------------------------------------------------
// Within-bucket counting sort to exact per-node CSR + noff + dinv.
__global__ __launch_bounds__(256) void sort2_kernel(const unsigned* __restrict__ pairs,
                                                    const unsigned* __restrict__ bbase,
                                                    int* __restrict__ ssrc,
                                                    unsigned* __restrict__ noff,
                                                    float* __restrict__ dinv) {
    __shared__ unsigned hist[BKT_R];
    __shared__ unsigned cur[BKT_R];
    const int k = blockIdx.x;
    const int t = threadIdx.x;
    const unsigned segS = bbase[k], segE = bbase[k + 1];

    if (t < BKT_R) hist[t] = 0u;
    __syncthreads();
    for (unsigned j = segS + t; j < segE; j += 256)
        atomicAdd(&hist[pairs[j] >> 17], 1u);
    __syncthreads();
    if (t < BKT_R) cur[t] = hist[t];
    __syncthreads();
    #pragma unroll
    for (int d = 1; d < BKT_R; d <<= 1) {
        unsigned x = (t < BKT_R && t >= d) ? cur[t - d] : 0u;
        __syncthreads();
        if (t < BKT_R) cur[t] += x;
        __syncthreads();
    }
    if (t < BKT_R) {
        unsigned mydeg = hist[t];
        unsigned start = segS + cur[t] - mydeg;   // exclusive
        int n = k * BKT_R + t;
        if (n < N_NODES) {
            noff[n] = start;
            dinv[n] = rsqrtf((float)(mydeg + 1u));
        }
        cur[t] = start;
    }
    __syncthreads();
    for (unsigned j = segS + t; j < segE; j += 256) {
        unsigned p = pairs[j];
        unsigned pos = atomicAdd(&cur[p >> 17], 1u);
        ssrc[pos] = (int)(p & 0x1FFFF);
    }
}

// ---------------------------------------------------------------------------
// hs = (x @ W) * dinv[row], bf16 store. MFMA 16x16x32 bf16.
// Per wave: 16-row tile; A frags from x (cvt_pk to bf16); B frags from
// fragment-order W in LDS (one ds_read_b128 each); 4 col-tiles x 8 k-tiles.
__global__ __launch_bounds__(256) void gemm_kernel(const float* __restrict__ x,
                                                   const float* __restrict__ W,
                                                   const float* __restrict__ dinv,
                                                   unsigned short* __restrict__ hs) {
    __shared__ unsigned short Wf[8][4][64][8];   // 32 KB, fragment order
    const int tid = threadIdx.x;
    const int lane = tid & 63;
    const int wv = tid >> 6;

    // pack W into fragment-order LDS (bf16): B[k][c], lane l elem j ->
    // k = kt*32 + (l>>4)*8 + j, c = ct*16 + (l&15)
    for (int i = tid; i < 8 * 4 * 64 * 8; i += 256) {
        int kt = i >> 11;
        int rem = i & 2047;
        int ct = rem >> 9;
        int rem2 = rem & 511;
        int l = rem2 >> 3;
        int j = rem2 & 7;
        int kk = kt * 32 + (l >> 4) * 8 + j;
        int cc = ct * 16 + (l & 15);
        ((unsigned short*)Wf)[i] = f2bf(W[(size_t)kk * OUT_CH + cc]);
    }
    __syncthreads();

    const int r16 = lane & 15;   // A row within tile
    const int q = lane >> 4;     // k-quarter (A), row-quarter (C)

    for (int t = blockIdx.x * 4 + wv; t < N_NODES / 16; t += gridDim.x * 4) {
        const int row0 = t * 16;
        const float* xrow = &x[(size_t)(row0 + r16) * IN_CH + q * 8];
        f32x4 acc[4] = {{0.f,0.f,0.f,0.f},{0.f,0.f,0.f,0.f},
                        {0.f,0.f,0.f,0.f},{0.f,0.f,0.f,0.f}};
        #pragma unroll
        for (int kt = 0; kt < 8; ++kt) {
            float4 x0 = *(const float4*)&xrow[kt * 32];
            float4 x1 = *(const float4*)&xrow[kt * 32 + 4];
            unsigned p0, p1, p2, p3;
            asm("v_cvt_pk_bf16_f32 %0, %1, %2" : "=v"(p0) : "v"(x0.x), "v"(x0.y));
            asm("v_cvt_pk_bf16_f32 %0, %1, %2" : "=v"(p1) : "v"(x0.z), "v"(x0.w));
            asm("v_cvt_pk_bf16_f32 %0, %1, %2" : "=v"(p2) : "v"(x1.x), "v"(x1.y));
            asm("v_cvt_pk_bf16_f32 %0, %1, %2" : "=v"(p3) : "v"(x1.z), "v"(x1.w));
            u32x4 au = {p0, p1, p2, p3};
            bshort8 af = __builtin_bit_cast(bshort8, au);
            #pragma unroll
            for (int ct = 0; ct < 4; ++ct) {
                bshort8 bf = *(const bshort8*)&Wf[kt][ct][lane][0];
                acc[ct] = __builtin_amdgcn_mfma_f32_16x16x32_bf16(af, bf, acc[ct], 0, 0, 0);
            }
        }
        // C layout: col = ct*16 + (lane&15), row = row0 + q*4 + r
        float dv[4];
        #pragma unroll
        for (int r = 0; r < 4; ++r) dv[r] = dinv[row0 + q * 4 + r];
        #pragma unroll
        for (int ct = 0; ct < 4; ++ct) {
            #pragma unroll
            for (int r = 0; r < 4; ++r) {
                int row = row0 + q * 4 + r;
                hs[(size_t)row * OUT_CH + ct * 16 + r16] = f2bf(acc[ct][r] * dv[r]);
            }
        }
    }
}

// ---------------------------------------------------------------------------
// Wave per node, quarter-wave per edge: 16 lanes x uint2 (4ch) cover a row;
// 4 edges per gather instruction. hs already carries dinv[src].
__global__ __launch_bounds__(256) void reduce_kernel(const unsigned short* __restrict__ hs,
                                                     const float* __restrict__ dinv,
                                                     const unsigned* __restrict__ noff,
                                                     const int* __restrict__ ssrc,
                                                     const float* __restrict__ b,
                                                     float* __restrict__ out) {
    const int n = blockIdx.x * 4 + (threadIdx.x >> 6);
    const int lane = threadIdx.x & 63;
    const int q = lane >> 4;
    const int l16 = lane & 15;
    if (n >= N_NODES) return;
    const uint2* h8 = (const uint2*)hs;   // one row = 16 uint2
    float a0 = 0.f, a1 = 0.f, a2 = 0.f, a3 = 0.f;
    {   // self-loop: hs[n]*dn with acc*dn at the end -> just add hs[n] once
        uint2 sv = h8[(size_t)n * 16 + l16];
        if (q == 0) { a0 = bflo(sv.x); a1 = bfhi(sv.x); a2 = bflo(sv.y); a3 = bfhi(sv.y); }
    }
    unsigned j = noff[n];
    const unsigned end = noff[n + 1];
    for (; j + 4 <= end; j += 4) {
        int s = ssrc[j + q];
        uint2 v = h8[(size_t)s * 16 + l16];
        a0 += bflo(v.x); a1 += bfhi(v.x); a2 += bflo(v.y); a3 += bfhi(v.y);
    }
    unsigned rem = end - j;
    if ((unsigned)q < rem) {
        int s = ssrc[j + q];
        uint2 v = h8[(size_t)s * 16 + l16];
        a0 += bflo(v.x); a1 += bfhi(v.x); a2 += bflo(v.y); a3 += bfhi(v.y);
    }
    a0 += __shfl_xor(a0, 16); a0 += __shfl_xor(a0, 32);
    a1 += __shfl_xor(a1, 16); a1 += __shfl_xor(a1, 32);
    a2 += __shfl_xor(a2, 16); a2 += __shfl_xor(a2, 32);
    a3 += __shfl_xor(a3, 16); a3 += __shfl_xor(a3, 32);
    const float dn = dinv[n];
    float4 bb = ((const float4*)b)[l16];
    float v0 = fmaxf(fmaf(a0, dn, bb.x), 0.f);
    float v1 = fmaxf(fmaf(a1, dn, bb.y), 0.f);
    float v2 = fmaxf(fmaf(a2, dn, bb.z), 0.f);
    float v3 = fmaxf(fmaf(a3, dn, bb.w), 0.f);
    float m = fmaxf(fmaxf(v0, v1), fmaxf(v2, v3));
    #pragma unroll
    for (int o = 8; o; o >>= 1) m = fmaxf(m, __shfl_xor(m, o));
    float sum = expf(v0 - m) + expf(v1 - m) + expf(v2 - m) + expf(v3 - m);
    #pragma unroll
    for (int o = 8; o; o >>= 1) sum += __shfl_xor(sum, o);
    float ls = logf(sum);
    if (q == 0) {
        float4 r;
        r.x = (v0 - m) - ls; r.y = (v1 - m) - ls;
        r.z = (v2 - m) - ls; r.w = (v3 - m) - ls;
        *(float4*)&out[(size_t)n * OUT_CH + l16 * 4] = r;
    }
}

// ---------------------------------------------------------------------------
// Fallback (atomic scatter) path, only if ws is too small for the CSR path.
__global__ __launch_bounds__(256) void deg_kernel(const int* __restrict__ ei32,
                                                  const long long* __restrict__ ei64,
                                                  const int* __restrict__ flag,
                                                  unsigned* __restrict__ deg) {
    const bool is64 = (*flag != 0);
    int i = blockIdx.x * blockDim.x + threadIdx.x;
    const int stride = gridDim.x * blockDim.x;
    for (; i < N_EDGES; i += stride) {
        int d = load_idx(ei32, ei64, is64, (long long)N_EDGES + i);
        atomicAdd(&deg[d], 1u);
    }
}

__global__ __launch_bounds__(256) void dinv_kernel(const unsigned* __restrict__ deg,
                                                   float* __restrict__ dinv) {
    int i = blockIdx.x * blockDim.x + threadIdx.x;
    if (i < N_NODES) dinv[i] = rsqrtf((float)(deg[i] + 1u));
}

__global__ __launch_bounds__(256) void scatter_kernel(const int* __restrict__ ei32,
                                                      const long long* __restrict__ ei64,
                                                      const int* __restrict__ flag,
                                                      const unsigned short* __restrict__ hs,
                                                      const float* __restrict__ dinv,
                                                      float* __restrict__ out) {
    const bool is64 = (*flag != 0);
    const int lane = threadIdx.x & 63;
    int w = blockIdx.x * (blockDim.x >> 6) + (threadIdx.x >> 6);
    const int nw = gridDim.x * (blockDim.x >> 6);
    for (int e = w; e < N_EDGES; e += nw) {
        int s = load_idx(ei32, ei64, is64, e);
        int d = load_idx(ei32, ei64, is64, (long long)N_EDGES + e);
        unsigned short us = hs[(size_t)s * OUT_CH + lane];
        float hv = __builtin_bit_cast(float, (unsigned)us << 16);
        atomicAdd(&out[(size_t)d * OUT_CH + lane], hv * dinv[d]);
    }
}

__global__ __launch_bounds__(256) void final_kernel(const unsigned short* __restrict__ hs,
                                                    const float* __restrict__ dinv,
                                                    const float* __restrict__ b,
                                                    float* __restrict__ out) {
    const int lane = threadIdx.x & 63;
    int w = blockIdx.x * (blockDim.x >> 6) + (threadIdx.x >> 6);
    const int nw = gridDim.x * (blockDim.x >> 6);
    const float bias = b[lane];
    for (int n = w; n < N_NODES; n += nw) {
        float di = dinv[n];
        unsigned short us = hs[(size_t)n * OUT_CH + lane];
        float hv = __builtin_bit_cast(float, (unsigned)us << 16);
        float v = out[(size_t)n * OUT_CH + lane] + hv * di + bias;
        v = fmaxf(v, 0.f);
        float m = v;
        #pragma unroll
        for (int o = 32; o; o >>= 1) m = fmaxf(m, __shfl_xor(m, o));
        float ex = expf(v - m);
        float sum = ex;
        #pragma unroll
        for (int o = 32; o; o >>= 1) sum += __shfl_xor(sum, o);
        out[(size_t)n * OUT_CH + lane] = (v - m) - logf(sum);
    }
}

// ---------------------------------------------------------------------------
extern "C" void kernel_launch(void* const* d_in, const int* in_sizes, int n_in,
                              void* d_out, int out_size, void* d_ws, size_t ws_size,
                              hipStream_t stream) {
    const float* x  = (const float*)d_in[0];
    const void*  ei = d_in[1];
    const float* W  = (const float*)d_in[2];
    const float* b  = (const float*)d_in[3];
    float* out = (float*)d_out;

    char* ws = (char*)d_ws;
    int* flag = (int*)(ws + WS_FLAG_OFF);

    const int* ei32       = (const int*)ei;
    const long long* ei64 = (const long long*)ei;

    probe_kernel<<<1, 64, 0, stream>>>((const unsigned*)ei, flag);

    if (ws_size >= (size_t)WS_NEED) {
        unsigned* bbase  = (unsigned*)(ws + WS_BBASE_OFF);
        unsigned* btot   = (unsigned*)(ws + WS_BTOT_OFF);
        float*    dinv   = (float*)(ws + WS_DINV_OFF);
        unsigned* noff   = (unsigned*)(ws + WS_NOFF_OFF);
        unsigned* pairs  = (unsigned*)(ws + WS_PAIRS_OFF);
        unsigned* hist2d = (unsigned*)(ws + WS_SSRC_OFF);   // aliased with ssrc
        int*      ssrc   = (int*)(ws + WS_SSRC_OFF);
        unsigned short* hs = (unsigned short*)(ws + WS_H_OFF);

        bcount_kernel<<<NBLK_PART, 256, 0, stream>>>(ei32, ei64, flag, hist2d);
        bscanA_kernel<<<(K_BKT + 3) / 4, 256, 0, stream>>>(hist2d, btot);
        bscanB_kernel<<<1, 1024, 0, stream>>>(btot, bbase, noff);
        bscanC_kernel<<<(K_BKT + 3) / 4, 256, 0, stream>>>(hist2d, bbase);
        partition_kernel<<<NBLK_PART, 512, 0, stream>>>(ei32, ei64, flag, hist2d, pairs);
        sort2_kernel<<<K_BKT, 256, 0, stream>>>(pairs, bbase, ssrc, noff, dinv);
        gemm_kernel<<<512, 256, 0, stream>>>(x, W, dinv, hs);
        reduce_kernel<<<(N_NODES + 3) / 4, 256, 0, stream>>>(hs, dinv, noff, ssrc, b, out);
    } else {
        unsigned* deg  = (unsigned*)(ws + WSF_DEG_OFF);
        float*    dinv = (float*)(ws + WSF_DINV_OFF);
        unsigned short* hs = (unsigned short*)(ws + WSF_H_OFF);
        hipMemsetAsync(deg, 0, (size_t)N_NODES * sizeof(unsigned), stream);
        hipMemsetAsync(d_out, 0, (size_t)out_size * sizeof(float), stream);
        deg_kernel<<<2048, 256, 0, stream>>>(ei32, ei64, flag, deg);
        dinv_kernel<<<(N_NODES + 255) / 256, 256, 0, stream>>>(deg, dinv);
        gemm_kernel<<<512, 256, 0, stream>>>(x, W, dinv, hs);
        scatter_kernel<<<2048, 256, 0, stream>>>(ei32, ei64, flag, hs, dinv, out);
        final_kernel<<<1024, 256, 0, stream>>>(hs, dinv, b, out);
    }
}

// Round 7
// 180.319 us; speedup vs baseline: 8.4300x; 1.2099x over previous
//
#include <hip/hip_runtime.h>
#include <cstddef>
#include <cstdint>

#define N_NODES 100000
#define IN_CH 256
#define OUT_CH 64
#define N_EDGES 3200000

// bucketing: 128 nodes per bucket
#define BKT_SHIFT 7
#define BKT_R     128
#define K_BKT     782                 // ceil(100000/128)
#define T_PART    8192                // edges per partition block
#define NBLK_PART ((N_EDGES + T_PART - 1) / T_PART)   // 391

// ---- ws layout (bytes) ----
#define WS_FLAG_OFF   0
#define WS_BBASE_OFF  3264            // 783 u32
#define WS_BTOT_OFF   6400            // 782 u32
#define WS_DINV_OFF   9600
#define WS_NOFF_OFF   409600
#define WS_PAIRS_OFF  809728
#define WS_SSRC_OFF   13609728        // aliased: hist2d (1.23MB) lives here until sort2
#define WS_H_OFF      26409728        // bf16 hs: 100000*64*2 = 12.8MB
#define WS_NEED       39209728

// ---- fallback (atomic) layout ----
#define WSF_DEG_OFF   4096
#define WSF_DINV_OFF  404096
#define WSF_H_OFF     804096

typedef __attribute__((ext_vector_type(8))) short bshort8;
typedef __attribute__((ext_vector_type(4))) float f32x4;
typedef __attribute__((ext_vector_type(4))) unsigned u32x4;

// ---------------------------------------------------------------------------
static __device__ __forceinline__ unsigned short f2bf(float f) {
    unsigned u = __builtin_bit_cast(unsigned, f);
    u += 0x7FFFu + ((u >> 16) & 1u);     // RNE (finite inputs)
    return (unsigned short)(u >> 16);
}
static __device__ __forceinline__ float bflo(unsigned u) {
    return __builtin_bit_cast(float, u << 16);
}
static __device__ __forceinline__ float bfhi(unsigned u) {
    return __builtin_bit_cast(float, u & 0xFFFF0000u);
}

// ---------------------------------------------------------------------------
__global__ void probe_kernel(const unsigned* __restrict__ ei, int* __restrict__ flag) {
    if (blockIdx.x == 0 && threadIdx.x == 0) {
        int all0 = 1;
        for (int i = 0; i < 16; ++i) all0 &= (ei[2 * i + 1] == 0u);
        *flag = all0;  // 1 => int64 layout, 0 => int32 layout
    }
}

__device__ __forceinline__ int load_idx(const int* ei32, const long long* ei64,
                                        bool is64, long long pos) {
    return is64 ? (int)ei64[pos] : ei32[pos];
}

// ---------------------------------------------------------------------------
// Per-(block,bucket) histogram rows; NO global atomics. 2-edge vector loads.
__global__ __launch_bounds__(256) void bcount_kernel(const int* __restrict__ ei32,
                                                     const long long* __restrict__ ei64,
                                                     const int* __restrict__ flag,
                                                     unsigned* __restrict__ hist2d) {
    __shared__ unsigned hist[K_BKT];
    const bool is64 = (*flag != 0);
    const int start = blockIdx.x * T_PART;
    const int end   = min(start + T_PART, N_EDGES);
    for (int k = threadIdx.x; k < K_BKT; k += 256) hist[k] = 0u;
    __syncthreads();
    if (is64) {
        const longlong2* d2 = (const longlong2*)&ei64[N_EDGES];
        for (int i = (start >> 1) + threadIdx.x; i < (end >> 1); i += 256) {
            longlong2 d = d2[i];
            atomicAdd(&hist[(int)d.x >> BKT_SHIFT], 1u);
            atomicAdd(&hist[(int)d.y >> BKT_SHIFT], 1u);
        }
    } else {
        const int2* d2 = (const int2*)&ei32[N_EDGES];
        for (int i = (start >> 1) + threadIdx.x; i < (end >> 1); i += 256) {
            int2 d = d2[i];
            atomicAdd(&hist[d.x >> BKT_SHIFT], 1u);
            atomicAdd(&hist[d.y >> BKT_SHIFT], 1u);
        }
    }
    __syncthreads();
    for (int k = threadIdx.x; k < K_BKT; k += 256)
        hist2d[(size_t)blockIdx.x * K_BKT + k] = hist[k];
}

// wave-per-bucket totals
__global__ __launch_bounds__(256) void bscanA_kernel(const unsigned* __restrict__ hist2d,
                                                     unsigned* __restrict__ btot) {
    const int k = blockIdx.x * 4 + (threadIdx.x >> 6);
    const int lane = threadIdx.x & 63;
    if (k >= K_BKT) return;
    unsigned tot = 0u;
    for (int c = lane; c < NBLK_PART; c += 64)
        tot += hist2d[(size_t)c * K_BKT + k];
    #pragma unroll
    for (int o = 32; o; o >>= 1) tot += __shfl_xor(tot, o);
    if (lane == 0) btot[k] = tot;
}

// single block: exclusive scan of bucket totals -> bbase; seeds noff terminator
__global__ __launch_bounds__(1024) void bscanB_kernel(const unsigned* __restrict__ btot,
                                                      unsigned* __restrict__ bbase,
                                                      unsigned* __restrict__ noff) {
    __shared__ unsigned s[1024];
    const int t = threadIdx.x;
    unsigned v = (t < K_BKT) ? btot[t] : 0u;
    s[t] = v; __syncthreads();
    #pragma unroll
    for (int d = 1; d < 1024; d <<= 1) {
        unsigned x = (t >= d) ? s[t - d] : 0u; __syncthreads();
        s[t] += x; __syncthreads();
    }
    if (t < K_BKT) {
        bbase[t] = s[t] - v;
        if (t == K_BKT - 1) bbase[K_BKT] = s[t];
    }
    if (t == 0) noff[N_NODES] = N_EDGES;
}

// wave-per-bucket: rewrite hist2d rows to per-(block,bucket) running bases
__global__ __launch_bounds__(256) void bscanC_kernel(unsigned* __restrict__ hist2d,
                                                     const unsigned* __restrict__ bbase) {
    const int k = blockIdx.x * 4 + (threadIdx.x >> 6);
    const int lane = threadIdx.x & 63;
    if (k >= K_BKT) return;
    unsigned run = bbase[k];
    for (int c0 = 0; c0 < NBLK_PART; c0 += 64) {
        int blk = c0 + lane;
        unsigned v = (blk < NBLK_PART) ? hist2d[(size_t)blk * K_BKT + k] : 0u;
        unsigned incl = v;
        #pragma unroll
        for (int d = 1; d < 64; d <<= 1) {
            unsigned tq = __shfl_up(incl, d);
            if (lane >= d) incl += tq;
        }
        if (blk < NBLK_PART) hist2d[(size_t)blk * K_BKT + k] = run + incl - v;
        run += __shfl(incl, 63);
    }
}

// ---------------------------------------------------------------------------
// Partition edges into dst-range buckets using precomputed per-block bases.
// 2-edge vector loads of src and dst streams.
__global__ __launch_bounds__(512) void partition_kernel(const int* __restrict__ ei32,
                                                        const long long* __restrict__ ei64,
                                                        const int* __restrict__ flag,
                                                        const unsigned* __restrict__ hist2d,
                                                        unsigned* __restrict__ pairs) {
    __shared__ unsigned cur[K_BKT];
    const bool is64 = (*flag != 0);
    const int start = blockIdx.x * T_PART;
    const int end   = min(start + T_PART, N_EDGES);
    for (int k = threadIdx.x; k < K_BKT; k += 512)
        cur[k] = hist2d[(size_t)blockIdx.x * K_BKT + k];
    __syncthreads();
    if (is64) {
        const longlong2* s2 = (const longlong2*)&ei64[0];
        const longlong2* d2 = (const longlong2*)&ei64[N_EDGES];
        for (int i = (start >> 1) + threadIdx.x; i < (end >> 1); i += 512) {
            longlong2 s = s2[i];
            longlong2 d = d2[i];
            unsigned p0 = atomicAdd(&cur[(int)d.x >> BKT_SHIFT], 1u);
            pairs[p0] = (unsigned)s.x | ((unsigned)((int)d.x & (BKT_R - 1)) << 17);
            unsigned p1 = atomicAdd(&cur[(int)d.y >> BKT_SHIFT], 1u);
            pairs[p1] = (unsigned)s.y | ((unsigned)((int)d.y & (BKT_R - 1)) << 17);
        }
    } else {
        const int2* s2 = (const int2*)&ei32[0];
        const int2* d2 = (const int2*)&ei32[N_EDGES];
        for (int i = (start >> 1) + threadIdx.x; i < (end >> 1); i += 512) {
            int2 s = s2[i];
            int2 d = d2[i];
            unsigned p0 = atomicAdd(&cur[d.x >> BKT_SHIFT], 1u);
            pairs[p0] = (unsigned)s.x | ((unsigned)(d.x & (BKT_R - 1)) << 17);
            unsigned p1 = atomicAdd(&cur[d.y >> BKT_SHIFT], 1u);
            pairs[p1] = (unsigned)s.y | ((unsigned)(d.y & (BKT_R - 1)) << 17);
        }
    }
}

// ---------------------------------------------------------------------------
// Within-bucket counting sort to exact per-node CSR + noff + dinv.
__global__ __launch_bounds__(256) void sort2_kernel(const unsigned* __restrict__ pairs,
                                                    const unsigned* __restrict__ bbase,
                                                    int* __restrict__ ssrc,
                                                    unsigned* __restrict__ noff,
                                                    float* __restrict__ dinv) {
    __shared__ unsigned hist[BKT_R];
    __shared__ unsigned cur[BKT_R];
    const int k = blockIdx.x;
    const int t = threadIdx.x;
    const unsigned segS = bbase[k], segE = bbase[k + 1];

    if (t < BKT_R) hist[t] = 0u;
    __syncthreads();
    for (unsigned j = segS + t; j < segE; j += 256)
        atomicAdd(&hist[pairs[j] >> 17], 1u);
    __syncthreads();
    if (t < BKT_R) cur[t] = hist[t];
    __syncthreads();
    #pragma unroll
    for (int d = 1; d < BKT_R; d <<= 1) {
        unsigned x = (t < BKT_R && t >= d) ? cur[t - d] : 0u;
        __syncthreads();
        if (t < BKT_R) cur[t] += x;
        __syncthreads();
    }
    if (t < BKT_R) {
        unsigned mydeg = hist[t];
        unsigned start = segS + cur[t] - mydeg;   // exclusive
        int n = k * BKT_R + t;
        if (n < N_NODES) {
            noff[n] = start;
            dinv[n] = rsqrtf((float)(mydeg + 1u));
        }
        cur[t] = start;
    }
    __syncthreads();
    for (unsigned j = segS + t; j < segE; j += 256) {
        unsigned p = pairs[j];
        unsigned pos = atomicAdd(&cur[p >> 17], 1u);
        ssrc[pos] = (int)(p & 0x1FFFF);
    }
}

// ---------------------------------------------------------------------------
// hs = (x @ W) * dinv[row], bf16 store. MFMA 16x16x32 bf16.
__global__ __launch_bounds__(256) void gemm_kernel(const float* __restrict__ x,
                                                   const float* __restrict__ W,
                                                   const float* __restrict__ dinv,
                                                   unsigned short* __restrict__ hs) {
    __shared__ unsigned short Wf[8][4][64][8];   // 32 KB, fragment order
    const int tid = threadIdx.x;
    const int lane = tid & 63;
    const int wv = tid >> 6;

    for (int i = tid; i < 8 * 4 * 64 * 8; i += 256) {
        int kt = i >> 11;
        int rem = i & 2047;
        int ct = rem >> 9;
        int rem2 = rem & 511;
        int l = rem2 >> 3;
        int j = rem2 & 7;
        int kk = kt * 32 + (l >> 4) * 8 + j;
        int cc = ct * 16 + (l & 15);
        ((unsigned short*)Wf)[i] = f2bf(W[(size_t)kk * OUT_CH + cc]);
    }
    __syncthreads();

    const int r16 = lane & 15;   // A row within tile
    const int q = lane >> 4;     // k-quarter (A), row-quarter (C)

    for (int t = blockIdx.x * 4 + wv; t < N_NODES / 16; t += gridDim.x * 4) {
        const int row0 = t * 16;
        const float* xrow = &x[(size_t)(row0 + r16) * IN_CH + q * 8];
        f32x4 acc[4] = {{0.f,0.f,0.f,0.f},{0.f,0.f,0.f,0.f},
                        {0.f,0.f,0.f,0.f},{0.f,0.f,0.f,0.f}};
        #pragma unroll
        for (int kt = 0; kt < 8; ++kt) {
            float4 x0 = *(const float4*)&xrow[kt * 32];
            float4 x1 = *(const float4*)&xrow[kt * 32 + 4];
            unsigned p0, p1, p2, p3;
            asm("v_cvt_pk_bf16_f32 %0, %1, %2" : "=v"(p0) : "v"(x0.x), "v"(x0.y));
            asm("v_cvt_pk_bf16_f32 %0, %1, %2" : "=v"(p1) : "v"(x0.z), "v"(x0.w));
            asm("v_cvt_pk_bf16_f32 %0, %1, %2" : "=v"(p2) : "v"(x1.x), "v"(x1.y));
            asm("v_cvt_pk_bf16_f32 %0, %1, %2" : "=v"(p3) : "v"(x1.z), "v"(x1.w));
            u32x4 au = {p0, p1, p2, p3};
            bshort8 af = __builtin_bit_cast(bshort8, au);
            #pragma unroll
            for (int ct = 0; ct < 4; ++ct) {
                bshort8 bf = *(const bshort8*)&Wf[kt][ct][lane][0];
                acc[ct] = __builtin_amdgcn_mfma_f32_16x16x32_bf16(af, bf, acc[ct], 0, 0, 0);
            }
        }
        float dv[4];
        #pragma unroll
        for (int r = 0; r < 4; ++r) dv[r] = dinv[row0 + q * 4 + r];
        #pragma unroll
        for (int ct = 0; ct < 4; ++ct) {
            #pragma unroll
            for (int r = 0; r < 4; ++r) {
                int row = row0 + q * 4 + r;
                hs[(size_t)row * OUT_CH + ct * 16 + r16] = f2bf(acc[ct][r] * dv[r]);
            }
        }
    }
}

// ---------------------------------------------------------------------------
// Wave per node, quarter-wave per edge, 16-edge unroll => 4 gathers in flight.
__global__ __launch_bounds__(256) void reduce_kernel(const unsigned short* __restrict__ hs,
                                                     const float* __restrict__ dinv,
                                                     const unsigned* __restrict__ noff,
                                                     const int* __restrict__ ssrc,
                                                     const float* __restrict__ b,
                                                     float* __restrict__ out) {
    const int n = blockIdx.x * 4 + (threadIdx.x >> 6);
    const int lane = threadIdx.x & 63;
    const int q = lane >> 4;
    const int l16 = lane & 15;
    if (n >= N_NODES) return;
    const uint2* h8 = (const uint2*)hs;   // one row = 16 uint2
    float a0 = 0.f, a1 = 0.f, a2 = 0.f, a3 = 0.f;
    {   // self-loop (hs already carries dinv[n]); counted once (q==0)
        uint2 sv = h8[(size_t)n * 16 + l16];
        if (q == 0) { a0 = bflo(sv.x); a1 = bfhi(sv.x); a2 = bflo(sv.y); a3 = bfhi(sv.y); }
    }
    unsigned j = noff[n];
    const unsigned end = noff[n + 1];
    // 16 edges per iteration: 4 independent gathers in flight per wave
    for (; j + 16 <= end; j += 16) {
        int s0 = ssrc[j + q];
        int s1 = ssrc[j + 4 + q];
        int s2 = ssrc[j + 8 + q];
        int s3 = ssrc[j + 12 + q];
        uint2 v0 = h8[(size_t)s0 * 16 + l16];
        uint2 v1 = h8[(size_t)s1 * 16 + l16];
        uint2 v2 = h8[(size_t)s2 * 16 + l16];
        uint2 v3 = h8[(size_t)s3 * 16 + l16];
        a0 += bflo(v0.x); a1 += bfhi(v0.x); a2 += bflo(v0.y); a3 += bfhi(v0.y);
        a0 += bflo(v1.x); a1 += bfhi(v1.x); a2 += bflo(v1.y); a3 += bfhi(v1.y);
        a0 += bflo(v2.x); a1 += bfhi(v2.x); a2 += bflo(v2.y); a3 += bfhi(v2.y);
        a0 += bflo(v3.x); a1 += bfhi(v3.x); a2 += bflo(v3.y); a3 += bfhi(v3.y);
    }
    for (; j + 4 <= end; j += 4) {
        int s = ssrc[j + q];
        uint2 v = h8[(size_t)s * 16 + l16];
        a0 += bflo(v.x); a1 += bfhi(v.x); a2 += bflo(v.y); a3 += bfhi(v.y);
    }
    unsigned rem = end - j;
    if ((unsigned)q < rem) {
        int s = ssrc[j + q];
        uint2 v = h8[(size_t)s * 16 + l16];
        a0 += bflo(v.x); a1 += bfhi(v.x); a2 += bflo(v.y); a3 += bfhi(v.y);
    }
    a0 += __shfl_xor(a0, 16); a0 += __shfl_xor(a0, 32);
    a1 += __shfl_xor(a1, 16); a1 += __shfl_xor(a1, 32);
    a2 += __shfl_xor(a2, 16); a2 += __shfl_xor(a2, 32);
    a3 += __shfl_xor(a3, 16); a3 += __shfl_xor(a3, 32);
    const float dn = dinv[n];
    float4 bb = ((const float4*)b)[l16];
    float v0 = fmaxf(fmaf(a0, dn, bb.x), 0.f);
    float v1 = fmaxf(fmaf(a1, dn, bb.y), 0.f);
    float v2 = fmaxf(fmaf(a2, dn, bb.z), 0.f);
    float v3 = fmaxf(fmaf(a3, dn, bb.w), 0.f);
    float m = fmaxf(fmaxf(v0, v1), fmaxf(v2, v3));
    #pragma unroll
    for (int o = 8; o; o >>= 1) m = fmaxf(m, __shfl_xor(m, o));
    float sum = expf(v0 - m) + expf(v1 - m) + expf(v2 - m) + expf(v3 - m);
    #pragma unroll
    for (int o = 8; o; o >>= 1) sum += __shfl_xor(sum, o);
    float ls = logf(sum);
    if (q == 0) {
        float4 r;
        r.x = (v0 - m) - ls; r.y = (v1 - m) - ls;
        r.z = (v2 - m) - ls; r.w = (v3 - m) - ls;
        *(float4*)&out[(size_t)n * OUT_CH + l16 * 4] = r;
    }
}

// ---------------------------------------------------------------------------
// Fallback (atomic scatter) path, only if ws is too small for the CSR path.
__global__ __launch_bounds__(256) void deg_kernel(const int* __restrict__ ei32,
                                                  const long long* __restrict__ ei64,
                                                  const int* __restrict__ flag,
                                                  unsigned* __restrict__ deg) {
    const bool is64 = (*flag != 0);
    int i = blockIdx.x * blockDim.x + threadIdx.x;
    const int stride = gridDim.x * blockDim.x;
    for (; i < N_EDGES; i += stride) {
        int d = load_idx(ei32, ei64, is64, (long long)N_EDGES + i);
        atomicAdd(&deg[d], 1u);
    }
}

__global__ __launch_bounds__(256) void dinv_kernel(const unsigned* __restrict__ deg,
                                                   float* __restrict__ dinv) {
    int i = blockIdx.x * blockDim.x + threadIdx.x;
    if (i < N_NODES) dinv[i] = rsqrtf((float)(deg[i] + 1u));
}

__global__ __launch_bounds__(256) void scatter_kernel(const int* __restrict__ ei32,
                                                      const long long* __restrict__ ei64,
                                                      const int* __restrict__ flag,
                                                      const unsigned short* __restrict__ hs,
                                                      const float* __restrict__ dinv,
                                                      float* __restrict__ out) {
    const bool is64 = (*flag != 0);
    const int lane = threadIdx.x & 63;
    int w = blockIdx.x * (blockDim.x >> 6) + (threadIdx.x >> 6);
    const int nw = gridDim.x * (blockDim.x >> 6);
    for (int e = w; e < N_EDGES; e += nw) {
        int s = load_idx(ei32, ei64, is64, e);
        int d = load_idx(ei32, ei64, is64, (long long)N_EDGES + e);
        unsigned short us = hs[(size_t)s * OUT_CH + lane];
        float hv = __builtin_bit_cast(float, (unsigned)us << 16);
        atomicAdd(&out[(size_t)d * OUT_CH + lane], hv * dinv[d]);
    }
}

__global__ __launch_bounds__(256) void final_kernel(const unsigned short* __restrict__ hs,
                                                    const float* __restrict__ dinv,
                                                    const float* __restrict__ b,
                                                    float* __restrict__ out) {
    const int lane = threadIdx.x & 63;
    int w = blockIdx.x * (blockDim.x >> 6) + (threadIdx.x >> 6);
    const int nw = gridDim.x * (blockDim.x >> 6);
    const float bias = b[lane];
    for (int n = w; n < N_NODES; n += nw) {
        float di = dinv[n];
        unsigned short us = hs[(size_t)n * OUT_CH + lane];
        float hv = __builtin_bit_cast(float, (unsigned)us << 16);
        float v = out[(size_t)n * OUT_CH + lane] + hv * di + bias;
        v = fmaxf(v, 0.f);
        float m = v;
        #pragma unroll
        for (int o = 32; o; o >>= 1) m = fmaxf(m, __shfl_xor(m, o));
        float ex = expf(v - m);
        float sum = ex;
        #pragma unroll
        for (int o = 32; o; o >>= 1) sum += __shfl_xor(sum, o);
        out[(size_t)n * OUT_CH + lane] = (v - m) - logf(sum);
    }
}

// ---------------------------------------------------------------------------
extern "C" void kernel_launch(void* const* d_in, const int* in_sizes, int n_in,
                              void* d_out, int out_size, void* d_ws, size_t ws_size,
                              hipStream_t stream) {
    const float* x  = (const float*)d_in[0];
    const void*  ei = d_in[1];
    const float* W  = (const float*)d_in[2];
    const float* b  = (const float*)d_in[3];
    float* out = (float*)d_out;

    char* ws = (char*)d_ws;
    int* flag = (int*)(ws + WS_FLAG_OFF);

    const int* ei32       = (const int*)ei;
    const long long* ei64 = (const long long*)ei;

    probe_kernel<<<1, 64, 0, stream>>>((const unsigned*)ei, flag);

    if (ws_size >= (size_t)WS_NEED) {
        unsigned* bbase  = (unsigned*)(ws + WS_BBASE_OFF);
        unsigned* btot   = (unsigned*)(ws + WS_BTOT_OFF);
        float*    dinv   = (float*)(ws + WS_DINV_OFF);
        unsigned* noff   = (unsigned*)(ws + WS_NOFF_OFF);
        unsigned* pairs  = (unsigned*)(ws + WS_PAIRS_OFF);
        unsigned* hist2d = (unsigned*)(ws + WS_SSRC_OFF);   // aliased with ssrc
        int*      ssrc   = (int*)(ws + WS_SSRC_OFF);
        unsigned short* hs = (unsigned short*)(ws + WS_H_OFF);

        bcount_kernel<<<NBLK_PART, 256, 0, stream>>>(ei32, ei64, flag, hist2d);
        bscanA_kernel<<<(K_BKT + 3) / 4, 256, 0, stream>>>(hist2d, btot);
        bscanB_kernel<<<1, 1024, 0, stream>>>(btot, bbase, noff);
        bscanC_kernel<<<(K_BKT + 3) / 4, 256, 0, stream>>>(hist2d, bbase);
        partition_kernel<<<NBLK_PART, 512, 0, stream>>>(ei32, ei64, flag, hist2d, pairs);
        sort2_kernel<<<K_BKT, 256, 0, stream>>>(pairs, bbase, ssrc, noff, dinv);
        gemm_kernel<<<512, 256, 0, stream>>>(x, W, dinv, hs);
        reduce_kernel<<<(N_NODES + 3) / 4, 256, 0, stream>>>(hs, dinv, noff, ssrc, b, out);
    } else {
        unsigned* deg  = (unsigned*)(ws + WSF_DEG_OFF);
        float*    dinv = (float*)(ws + WSF_DINV_OFF);
        unsigned short* hs = (unsigned short*)(ws + WSF_H_OFF);
        hipMemsetAsync(deg, 0, (size_t)N_NODES * sizeof(unsigned), stream);
        hipMemsetAsync(d_out, 0, (size_t)out_size * sizeof(float), stream);
        deg_kernel<<<2048, 256, 0, stream>>>(ei32, ei64, flag, deg);
        dinv_kernel<<<(N_NODES + 255) / 256, 256, 0, stream>>>(deg, dinv);
        gemm_kernel<<<512, 256, 0, stream>>>(x, W, dinv, hs);
        scatter_kernel<<<2048, 256, 0, stream>>>(ei32, ei64, flag, hs, dinv, out);
        final_kernel<<<1024, 256, 0, stream>>>(hs, dinv, b, out);
    }
}

// Round 9
// 177.602 us; speedup vs baseline: 8.5590x; 1.0153x over previous
//
#include <hip/hip_runtime.h>
#include <cstddef>
#include <cstdint>

#define N_NODES 100000
#define IN_CH 256
#define OUT_CH 64
#define N_EDGES 3200000

// bucketing: 128 nodes per bucket
#define BKT_SHIFT 7
#define BKT_R     128
#define K_BKT     782                 // ceil(100000/128)
#define T_PART    8192                // edges per partition block
#define NBLK_PART ((N_EDGES + T_PART - 1) / T_PART)   // 391
#define NBLK_GEMM 512
#define N_TILES   (N_NODES / 16)      // 6250

// ---- ws layout (bytes) ----
#define WS_FLAG_OFF   0
#define WS_BBASE_OFF  3264            // 783 u32
#define WS_BTOT_OFF   6400            // 782 u32
#define WS_DINV_OFF   9600
#define WS_NOFF_OFF   409600
#define WS_PAIRS_OFF  809728
#define WS_SSRC_OFF   13609728        // aliased: hist2d (1.23MB) lives here until sort2
#define WS_H_OFF      26409728        // bf16 h: 100000*64*2 = 12.8MB (UNSCALED)
#define WS_NEED       39209728

// ---- fallback (atomic) layout ----
#define WSF_DEG_OFF   4096
#define WSF_DINV_OFF  404096
#define WSF_H_OFF     804096

typedef __attribute__((ext_vector_type(8))) short bshort8;
typedef __attribute__((ext_vector_type(4))) float f32x4;
typedef __attribute__((ext_vector_type(4))) unsigned u32x4;

// ---------------------------------------------------------------------------
static __device__ __forceinline__ unsigned short f2bf(float f) {
    unsigned u = __builtin_bit_cast(unsigned, f);
    u += 0x7FFFu + ((u >> 16) & 1u);     // RNE (finite inputs)
    return (unsigned short)(u >> 16);
}
static __device__ __forceinline__ float bflo(unsigned u) {
    return __builtin_bit_cast(float, u << 16);
}
static __device__ __forceinline__ float bfhi(unsigned u) {
    return __builtin_bit_cast(float, u & 0xFFFF0000u);
}

// ---------------------------------------------------------------------------
__global__ void probe_kernel(const unsigned* __restrict__ ei, int* __restrict__ flag) {
    if (blockIdx.x == 0 && threadIdx.x == 0) {
        int all0 = 1;
        for (int i = 0; i < 16; ++i) all0 &= (ei[2 * i + 1] == 0u);
        *flag = all0;  // 1 => int64 layout, 0 => int32 layout
    }
}

__device__ __forceinline__ int load_idx(const int* ei32, const long long* ei64,
                                        bool is64, long long pos) {
    return is64 ? (int)ei64[pos] : ei32[pos];
}

// ---------------------------------------------------------------------------
// Shared gemm body (256 threads, 4 waves): h = x @ W, bf16 store, UNSCALED.
// This is the round-7-proven gemm minus the dinv multiply.
static __device__ __forceinline__ void gemm_body(char* smem, int gbid, int nblk,
                                                 const float* __restrict__ x,
                                                 const float* __restrict__ W,
                                                 unsigned short* __restrict__ hs) {
    unsigned short (*Wf)[4][64][8] = (unsigned short (*)[4][64][8])smem;
    const int tid = threadIdx.x;
    const int lane = tid & 63;
    const int wv = tid >> 6;           // 4 waves

    for (int i = tid; i < 8 * 4 * 64 * 8; i += 256) {
        int kt = i >> 11;
        int rem = i & 2047;
        int ct = rem >> 9;
        int rem2 = rem & 511;
        int l = rem2 >> 3;
        int j = rem2 & 7;
        int kk = kt * 32 + (l >> 4) * 8 + j;
        int cc = ct * 16 + (l & 15);
        ((unsigned short*)Wf)[i] = f2bf(W[(size_t)kk * OUT_CH + cc]);
    }
    __syncthreads();

    const int r16 = lane & 15;   // A row within tile
    const int q = lane >> 4;     // k-quarter (A), row-quarter (C)

    for (int t = gbid * 4 + wv; t < N_TILES; t += nblk * 4) {
        const int row0 = t * 16;
        const float* xrow = &x[(size_t)(row0 + r16) * IN_CH + q * 8];
        f32x4 acc[4] = {{0.f,0.f,0.f,0.f},{0.f,0.f,0.f,0.f},
                        {0.f,0.f,0.f,0.f},{0.f,0.f,0.f,0.f}};
        #pragma unroll
        for (int kt = 0; kt < 8; ++kt) {
            float4 x0 = *(const float4*)&xrow[kt * 32];
            float4 x1 = *(const float4*)&xrow[kt * 32 + 4];
            unsigned p0, p1, p2, p3;
            asm("v_cvt_pk_bf16_f32 %0, %1, %2" : "=v"(p0) : "v"(x0.x), "v"(x0.y));
            asm("v_cvt_pk_bf16_f32 %0, %1, %2" : "=v"(p1) : "v"(x0.z), "v"(x0.w));
            asm("v_cvt_pk_bf16_f32 %0, %1, %2" : "=v"(p2) : "v"(x1.x), "v"(x1.y));
            asm("v_cvt_pk_bf16_f32 %0, %1, %2" : "=v"(p3) : "v"(x1.z), "v"(x1.w));
            u32x4 au = {p0, p1, p2, p3};
            bshort8 af = __builtin_bit_cast(bshort8, au);
            #pragma unroll
            for (int ct = 0; ct < 4; ++ct) {
                bshort8 bf = *(const bshort8*)&Wf[kt][ct][lane][0];
                acc[ct] = __builtin_amdgcn_mfma_f32_16x16x32_bf16(af, bf, acc[ct], 0, 0, 0);
            }
        }
        #pragma unroll
        for (int ct = 0; ct < 4; ++ct) {
            #pragma unroll
            for (int r = 0; r < 4; ++r) {
                int row = row0 + q * 4 + r;
                hs[(size_t)row * OUT_CH + ct * 16 + r16] = f2bf(acc[ct][r]);
            }
        }
    }
}

// ---------------------------------------------------------------------------
// FUSED: blocks [0, NBLK_PART) do per-(block,bucket) histograms (no global
// atomics); blocks [NBLK_PART, +NBLK_GEMM) do the independent gemm. The
// memory-bound histogram pass overlaps the MFMA gemm.
__global__ __launch_bounds__(256) void bcount_gemm_kernel(const int* __restrict__ ei32,
                                                          const long long* __restrict__ ei64,
                                                          const int* __restrict__ flag,
                                                          unsigned* __restrict__ hist2d,
                                                          const float* __restrict__ x,
                                                          const float* __restrict__ W,
                                                          unsigned short* __restrict__ hs) {
    __shared__ char smem[32768];
    const int bid = blockIdx.x;
    if (bid < NBLK_PART) {
        unsigned* hist = (unsigned*)smem;
        const bool is64 = (*flag != 0);
        const int start = bid * T_PART;
        const int end   = min(start + T_PART, N_EDGES);
        for (int k = threadIdx.x; k < K_BKT; k += 256) hist[k] = 0u;
        __syncthreads();
        if (is64) {
            const longlong2* d2 = (const longlong2*)&ei64[N_EDGES];
            for (int i = (start >> 1) + threadIdx.x; i < (end >> 1); i += 256) {
                longlong2 d = d2[i];
                atomicAdd(&hist[(int)d.x >> BKT_SHIFT], 1u);
                atomicAdd(&hist[(int)d.y >> BKT_SHIFT], 1u);
            }
        } else {
            const int2* d2 = (const int2*)&ei32[N_EDGES];
            for (int i = (start >> 1) + threadIdx.x; i < (end >> 1); i += 256) {
                int2 d = d2[i];
                atomicAdd(&hist[d.x >> BKT_SHIFT], 1u);
                atomicAdd(&hist[d.y >> BKT_SHIFT], 1u);
            }
        }
        __syncthreads();
        for (int k = threadIdx.x; k < K_BKT; k += 256)
            hist2d[(size_t)bid * K_BKT + k] = hist[k];
    } else {
        gemm_body(smem, bid - NBLK_PART, NBLK_GEMM, x, W, hs);
    }
}

// gemm-only wrapper (fallback path)
__global__ __launch_bounds__(256) void gemm_only_kernel(const float* __restrict__ x,
                                                        const float* __restrict__ W,
                                                        unsigned short* __restrict__ hs) {
    __shared__ char smem[32768];
    gemm_body(smem, blockIdx.x, gridDim.x, x, W, hs);
}

// ---------------------------------------------------------------------------
// wave-per-bucket totals
__global__ __launch_bounds__(256) void bscanA_kernel(const unsigned* __restrict__ hist2d,
                                                     unsigned* __restrict__ btot) {
    const int k = blockIdx.x * 4 + (threadIdx.x >> 6);
    const int lane = threadIdx.x & 63;
    if (k >= K_BKT) return;
    unsigned tot = 0u;
    for (int c = lane; c < NBLK_PART; c += 64)
        tot += hist2d[(size_t)c * K_BKT + k];
    #pragma unroll
    for (int o = 32; o; o >>= 1) tot += __shfl_xor(tot, o);
    if (lane == 0) btot[k] = tot;
}

// single block: exclusive scan of bucket totals -> bbase; seeds noff terminator
__global__ __launch_bounds__(1024) void bscanB_kernel(const unsigned* __restrict__ btot,
                                                      unsigned* __restrict__ bbase,
                                                      unsigned* __restrict__ noff) {
    __shared__ unsigned s[1024];
    const int t = threadIdx.x;
    unsigned v = (t < K_BKT) ? btot[t] : 0u;
    s[t] = v; __syncthreads();
    #pragma unroll
    for (int d = 1; d < 1024; d <<= 1) {
        unsigned x = (t >= d) ? s[t - d] : 0u; __syncthreads();
        s[t] += x; __syncthreads();
    }
    if (t < K_BKT) {
        bbase[t] = s[t] - v;
        if (t == K_BKT - 1) bbase[K_BKT] = s[t];
    }
    if (t == 0) noff[N_NODES] = N_EDGES;
}

// wave-per-bucket: rewrite hist2d rows to per-(block,bucket) running bases
__global__ __launch_bounds__(256) void bscanC_kernel(unsigned* __restrict__ hist2d,
                                                     const unsigned* __restrict__ bbase) {
    const int k = blockIdx.x * 4 + (threadIdx.x >> 6);
    const int lane = threadIdx.x & 63;
    if (k >= K_BKT) return;
    unsigned run = bbase[k];
    for (int c0 = 0; c0 < NBLK_PART; c0 += 64) {
        int blk = c0 + lane;
        unsigned v = (blk < NBLK_PART) ? hist2d[(size_t)blk * K_BKT + k] : 0u;
        unsigned incl = v;
        #pragma unroll
        for (int d = 1; d < 64; d <<= 1) {
            unsigned tq = __shfl_up(incl, d);
            if (lane >= d) incl += tq;
        }
        if (blk < NBLK_PART) hist2d[(size_t)blk * K_BKT + k] = run + incl - v;
        run += __shfl(incl, 63);
    }
}

// ---------------------------------------------------------------------------
// Partition edges into dst-range buckets using precomputed per-block bases.
__global__ __launch_bounds__(512) void partition_kernel(const int* __restrict__ ei32,
                                                        const long long* __restrict__ ei64,
                                                        const int* __restrict__ flag,
                                                        const unsigned* __restrict__ hist2d,
                                                        unsigned* __restrict__ pairs) {
    __shared__ unsigned cur[K_BKT];
    const bool is64 = (*flag != 0);
    const int start = blockIdx.x * T_PART;
    const int end   = min(start + T_PART, N_EDGES);
    for (int k = threadIdx.x; k < K_BKT; k += 512)
        cur[k] = hist2d[(size_t)blockIdx.x * K_BKT + k];
    __syncthreads();
    if (is64) {
        const longlong2* s2 = (const longlong2*)&ei64[0];
        const longlong2* d2 = (const longlong2*)&ei64[N_EDGES];
        for (int i = (start >> 1) + threadIdx.x; i < (end >> 1); i += 512) {
            longlong2 s = s2[i];
            longlong2 d = d2[i];
            unsigned p0 = atomicAdd(&cur[(int)d.x >> BKT_SHIFT], 1u);
            pairs[p0] = (unsigned)s.x | ((unsigned)((int)d.x & (BKT_R - 1)) << 17);
            unsigned p1 = atomicAdd(&cur[(int)d.y >> BKT_SHIFT], 1u);
            pairs[p1] = (unsigned)s.y | ((unsigned)((int)d.y & (BKT_R - 1)) << 17);
        }
    } else {
        const int2* s2 = (const int2*)&ei32[0];
        const int2* d2 = (const int2*)&ei32[N_EDGES];
        for (int i = (start >> 1) + threadIdx.x; i < (end >> 1); i += 512) {
            int2 s = s2[i];
            int2 d = d2[i];
            unsigned p0 = atomicAdd(&cur[d.x >> BKT_SHIFT], 1u);
            pairs[p0] = (unsigned)s.x | ((unsigned)(d.x & (BKT_R - 1)) << 17);
            unsigned p1 = atomicAdd(&cur[d.y >> BKT_SHIFT], 1u);
            pairs[p1] = (unsigned)s.y | ((unsigned)(d.y & (BKT_R - 1)) << 17);
        }
    }
}

// ---------------------------------------------------------------------------
// Within-bucket counting sort to exact per-node CSR + noff + dinv (round-7 exact).
__global__ __launch_bounds__(256) void sort2_kernel(const unsigned* __restrict__ pairs,
                                                    const unsigned* __restrict__ bbase,
                                                    int* __restrict__ ssrc,
                                                    unsigned* __restrict__ noff,
                                                    float* __restrict__ dinv) {
    __shared__ unsigned hist[BKT_R];
    __shared__ unsigned cur[BKT_R];
    const int k = blockIdx.x;
    const int t = threadIdx.x;
    const unsigned segS = bbase[k], segE = bbase[k + 1];

    if (t < BKT_R) hist[t] = 0u;
    __syncthreads();
    for (unsigned j = segS + t; j < segE; j += 256)
        atomicAdd(&hist[pairs[j] >> 17], 1u);
    __syncthreads();
    if (t < BKT_R) cur[t] = hist[t];
    __syncthreads();
    #pragma unroll
    for (int d = 1; d < BKT_R; d <<= 1) {
        unsigned x = (t < BKT_R && t >= d) ? cur[t - d] : 0u;
        __syncthreads();
        if (t < BKT_R) cur[t] += x;
        __syncthreads();
    }
    if (t < BKT_R) {
        unsigned mydeg = hist[t];
        unsigned start = segS + cur[t] - mydeg;   // exclusive
        int n = k * BKT_R + t;
        if (n < N_NODES) {
            noff[n] = start;
            dinv[n] = rsqrtf((float)(mydeg + 1u));
        }
        cur[t] = start;
    }
    __syncthreads();
    for (unsigned j = segS + t; j < segE; j += 256) {
        unsigned p = pairs[j];
        unsigned pos = atomicAdd(&cur[p >> 17], 1u);
        ssrc[pos] = (int)(p & 0x1FFFF);
    }
}

// ---------------------------------------------------------------------------
// Wave per node, quarter-wave per edge, 16-edge unroll (4 gathers in flight).
// hs is UNSCALED; dinv[src] applied here as fp32 fma (single-rounding error).
__global__ __launch_bounds__(256) void reduce_kernel(const unsigned short* __restrict__ hs,
                                                     const float* __restrict__ dinv,
                                                     const unsigned* __restrict__ noff,
                                                     const int* __restrict__ ssrc,
                                                     const float* __restrict__ b,
                                                     float* __restrict__ out) {
    const int n = blockIdx.x * 4 + (threadIdx.x >> 6);
    const int lane = threadIdx.x & 63;
    const int q = lane >> 4;
    const int l16 = lane & 15;
    if (n >= N_NODES) return;
    const uint2* h8 = (const uint2*)hs;   // one row = 16 uint2
    const float dn = dinv[n];
    float a0 = 0.f, a1 = 0.f, a2 = 0.f, a3 = 0.f;
    {   // self-loop: h[n]*dinv[n]; counted once (q==0)
        uint2 sv = h8[(size_t)n * 16 + l16];
        if (q == 0) {
            a0 = bflo(sv.x) * dn; a1 = bfhi(sv.x) * dn;
            a2 = bflo(sv.y) * dn; a3 = bfhi(sv.y) * dn;
        }
    }
    unsigned j = noff[n];
    const unsigned end = noff[n + 1];
    for (; j + 16 <= end; j += 16) {
        int s0 = ssrc[j + q];
        int s1 = ssrc[j + 4 + q];
        int s2 = ssrc[j + 8 + q];
        int s3 = ssrc[j + 12 + q];
        float f0 = dinv[s0], f1 = dinv[s1], f2 = dinv[s2], f3 = dinv[s3];
        uint2 v0 = h8[(size_t)s0 * 16 + l16];
        uint2 v1 = h8[(size_t)s1 * 16 + l16];
        uint2 v2 = h8[(size_t)s2 * 16 + l16];
        uint2 v3 = h8[(size_t)s3 * 16 + l16];
        a0 = fmaf(bflo(v0.x), f0, a0); a1 = fmaf(bfhi(v0.x), f0, a1);
        a2 = fmaf(bflo(v0.y), f0, a2); a3 = fmaf(bfhi(v0.y), f0, a3);
        a0 = fmaf(bflo(v1.x), f1, a0); a1 = fmaf(bfhi(v1.x), f1, a1);
        a2 = fmaf(bflo(v1.y), f1, a2); a3 = fmaf(bfhi(v1.y), f1, a3);
        a0 = fmaf(bflo(v2.x), f2, a0); a1 = fmaf(bfhi(v2.x), f2, a1);
        a2 = fmaf(bflo(v2.y), f2, a2); a3 = fmaf(bfhi(v2.y), f2, a3);
        a0 = fmaf(bflo(v3.x), f3, a0); a1 = fmaf(bfhi(v3.x), f3, a1);
        a2 = fmaf(bflo(v3.y), f3, a2); a3 = fmaf(bfhi(v3.y), f3, a3);
    }
    for (; j + 4 <= end; j += 4) {
        int s = ssrc[j + q];
        float f = dinv[s];
        uint2 v = h8[(size_t)s * 16 + l16];
        a0 = fmaf(bflo(v.x), f, a0); a1 = fmaf(bfhi(v.x), f, a1);
        a2 = fmaf(bflo(v.y), f, a2); a3 = fmaf(bfhi(v.y), f, a3);
    }
    unsigned rem = end - j;
    if ((unsigned)q < rem) {
        int s = ssrc[j + q];
        float f = dinv[s];
        uint2 v = h8[(size_t)s * 16 + l16];
        a0 = fmaf(bflo(v.x), f, a0); a1 = fmaf(bfhi(v.x), f, a1);
        a2 = fmaf(bflo(v.y), f, a2); a3 = fmaf(bfhi(v.y), f, a3);
    }
    a0 += __shfl_xor(a0, 16); a0 += __shfl_xor(a0, 32);
    a1 += __shfl_xor(a1, 16); a1 += __shfl_xor(a1, 32);
    a2 += __shfl_xor(a2, 16); a2 += __shfl_xor(a2, 32);
    a3 += __shfl_xor(a3, 16); a3 += __shfl_xor(a3, 32);
    float4 bb = ((const float4*)b)[l16];
    float v0 = fmaxf(fmaf(a0, dn, bb.x), 0.f);
    float v1 = fmaxf(fmaf(a1, dn, bb.y), 0.f);
    float v2 = fmaxf(fmaf(a2, dn, bb.z), 0.f);
    float v3 = fmaxf(fmaf(a3, dn, bb.w), 0.f);
    float m = fmaxf(fmaxf(v0, v1), fmaxf(v2, v3));
    #pragma unroll
    for (int o = 8; o; o >>= 1) m = fmaxf(m, __shfl_xor(m, o));
    float sum = expf(v0 - m) + expf(v1 - m) + expf(v2 - m) + expf(v3 - m);
    #pragma unroll
    for (int o = 8; o; o >>= 1) sum += __shfl_xor(sum, o);
    float ls = logf(sum);
    if (q == 0) {
        float4 r;
        r.x = (v0 - m) - ls; r.y = (v1 - m) - ls;
        r.z = (v2 - m) - ls; r.w = (v3 - m) - ls;
        *(float4*)&out[(size_t)n * OUT_CH + l16 * 4] = r;
    }
}

// ---------------------------------------------------------------------------
// Fallback (atomic scatter) path, only if ws is too small for the CSR path.
__global__ __launch_bounds__(256) void deg_kernel(const int* __restrict__ ei32,
                                                  const long long* __restrict__ ei64,
                                                  const int* __restrict__ flag,
                                                  unsigned* __restrict__ deg) {
    const bool is64 = (*flag != 0);
    int i = blockIdx.x * blockDim.x + threadIdx.x;
    const int stride = gridDim.x * blockDim.x;
    for (; i < N_EDGES; i += stride) {
        int d = load_idx(ei32, ei64, is64, (long long)N_EDGES + i);
        atomicAdd(&deg[d], 1u);
    }
}

__global__ __launch_bounds__(256) void dinv_kernel(const unsigned* __restrict__ deg,
                                                   float* __restrict__ dinv) {
    int i = blockIdx.x * blockDim.x + threadIdx.x;
    if (i < N_NODES) dinv[i] = rsqrtf((float)(deg[i] + 1u));
}

__global__ __launch_bounds__(256) void scatter_kernel(const int* __restrict__ ei32,
                                                      const long long* __restrict__ ei64,
                                                      const int* __restrict__ flag,
                                                      const unsigned short* __restrict__ hs,
                                                      const float* __restrict__ dinv,
                                                      float* __restrict__ out) {
    const bool is64 = (*flag != 0);
    const int lane = threadIdx.x & 63;
    int w = blockIdx.x * (blockDim.x >> 6) + (threadIdx.x >> 6);
    const int nw = gridDim.x * (blockDim.x >> 6);
    for (int e = w; e < N_EDGES; e += nw) {
        int s = load_idx(ei32, ei64, is64, e);
        int d = load_idx(ei32, ei64, is64, (long long)N_EDGES + e);
        unsigned short us = hs[(size_t)s * OUT_CH + lane];
        float hv = __builtin_bit_cast(float, (unsigned)us << 16);
        atomicAdd(&out[(size_t)d * OUT_CH + lane], hv * dinv[s] * dinv[d]);
    }
}

__global__ __launch_bounds__(256) void final_kernel(const unsigned short* __restrict__ hs,
                                                    const float* __restrict__ dinv,
                                                    const float* __restrict__ b,
                                                    float* __restrict__ out) {
    const int lane = threadIdx.x & 63;
    int w = blockIdx.x * (blockDim.x >> 6) + (threadIdx.x >> 6);
    const int nw = gridDim.x * (blockDim.x >> 6);
    const float bias = b[lane];
    for (int n = w; n < N_NODES; n += nw) {
        float di = dinv[n];
        unsigned short us = hs[(size_t)n * OUT_CH + lane];
        float hv = __builtin_bit_cast(float, (unsigned)us << 16);
        float v = out[(size_t)n * OUT_CH + lane] + hv * di * di + bias;
        v = fmaxf(v, 0.f);
        float m = v;
        #pragma unroll
        for (int o = 32; o; o >>= 1) m = fmaxf(m, __shfl_xor(m, o));
        float ex = expf(v - m);
        float sum = ex;
        #pragma unroll
        for (int o = 32; o; o >>= 1) sum += __shfl_xor(sum, o);
        out[(size_t)n * OUT_CH + lane] = (v - m) - logf(sum);
    }
}

// ---------------------------------------------------------------------------
extern "C" void kernel_launch(void* const* d_in, const int* in_sizes, int n_in,
                              void* d_out, int out_size, void* d_ws, size_t ws_size,
                              hipStream_t stream) {
    const float* x  = (const float*)d_in[0];
    const void*  ei = d_in[1];
    const float* W  = (const float*)d_in[2];
    const float* b  = (const float*)d_in[3];
    float* out = (float*)d_out;

    char* ws = (char*)d_ws;
    int* flag = (int*)(ws + WS_FLAG_OFF);

    const int* ei32       = (const int*)ei;
    const long long* ei64 = (const long long*)ei;

    probe_kernel<<<1, 64, 0, stream>>>((const unsigned*)ei, flag);

    if (ws_size >= (size_t)WS_NEED) {
        unsigned* bbase  = (unsigned*)(ws + WS_BBASE_OFF);
        unsigned* btot   = (unsigned*)(ws + WS_BTOT_OFF);
        float*    dinv   = (float*)(ws + WS_DINV_OFF);
        unsigned* noff   = (unsigned*)(ws + WS_NOFF_OFF);
        unsigned* pairs  = (unsigned*)(ws + WS_PAIRS_OFF);
        unsigned* hist2d = (unsigned*)(ws + WS_SSRC_OFF);   // aliased with ssrc
        int*      ssrc   = (int*)(ws + WS_SSRC_OFF);
        unsigned short* hs = (unsigned short*)(ws + WS_H_OFF);

        bcount_gemm_kernel<<<NBLK_PART + NBLK_GEMM, 256, 0, stream>>>(
            ei32, ei64, flag, hist2d, x, W, hs);
        bscanA_kernel<<<(K_BKT + 3) / 4, 256, 0, stream>>>(hist2d, btot);
        bscanB_kernel<<<1, 1024, 0, stream>>>(btot, bbase, noff);
        bscanC_kernel<<<(K_BKT + 3) / 4, 256, 0, stream>>>(hist2d, bbase);
        partition_kernel<<<NBLK_PART, 512, 0, stream>>>(ei32, ei64, flag, hist2d, pairs);
        sort2_kernel<<<K_BKT, 256, 0, stream>>>(pairs, bbase, ssrc, noff, dinv);
        reduce_kernel<<<(N_NODES + 3) / 4, 256, 0, stream>>>(hs, dinv, noff, ssrc, b, out);
    } else {
        unsigned* deg  = (unsigned*)(ws + WSF_DEG_OFF);
        float*    dinv = (float*)(ws + WSF_DINV_OFF);
        unsigned short* hs = (unsigned short*)(ws + WSF_H_OFF);
        hipMemsetAsync(deg, 0, (size_t)N_NODES * sizeof(unsigned), stream);
        hipMemsetAsync(d_out, 0, (size_t)out_size * sizeof(float), stream);
        deg_kernel<<<2048, 256, 0, stream>>>(ei32, ei64, flag, deg);
        dinv_kernel<<<(N_NODES + 255) / 256, 256, 0, stream>>>(deg, dinv);
        gemm_only_kernel<<<NBLK_GEMM, 256, 0, stream>>>(x, W, hs);
        scatter_kernel<<<2048, 256, 0, stream>>>(ei32, ei64, flag, hs, dinv, out);
        final_kernel<<<1024, 256, 0, stream>>>(hs, dinv, b, out);
    }
}

// Round 10
// 176.070 us; speedup vs baseline: 8.6335x; 1.0087x over previous
//
#include <hip/hip_runtime.h>
#include <cstddef>
#include <cstdint>

#define N_NODES 100000
#define IN_CH 256
#define OUT_CH 64
#define N_EDGES 3200000

// bucketing: 128 nodes per bucket, fixed-capacity slots
#define BKT_SHIFT 7
#define BKT_R     128
#define K_BKT     782                 // ceil(100000/128)
#define BKT_CAP   6144                // mean 4096 + 32 sigma; slots of 24KB
#define T_PART    8192                // edges per partition block
#define NBLK_PART ((N_EDGES + T_PART - 1) / T_PART)   // 391
#define NBLK_GEMM 512
#define N_TILES   (N_NODES / 16)      // 6250

// ---- ws layout (bytes) ----
#define WS_FLAG_OFF   0
#define WS_GCNT_OFF   64              // 782 u32 bucket fill counts
#define WS_DINV_OFF   4096            // 400000 B
#define WS_NSE_OFF    404096          // 100000 uint2 = 800000 B
#define WS_EDG_OFF    1204224         // 782*6144*4 = 19,218,432 B (pairs -> sorted src)
#define WS_H_OFF      20422656        // bf16 h: 100000*64*2 = 12.8MB (unscaled)
#define WS_NEED       33222656

// ---- fallback (atomic) layout ----
#define WSF_DEG_OFF   4096
#define WSF_DINV_OFF  404096
#define WSF_H_OFF     804096

typedef __attribute__((ext_vector_type(8))) short bshort8;
typedef __attribute__((ext_vector_type(4))) float f32x4;
typedef __attribute__((ext_vector_type(4))) unsigned u32x4;

// ---------------------------------------------------------------------------
static __device__ __forceinline__ unsigned short f2bf(float f) {
    unsigned u = __builtin_bit_cast(unsigned, f);
    u += 0x7FFFu + ((u >> 16) & 1u);     // RNE (finite inputs)
    return (unsigned short)(u >> 16);
}
static __device__ __forceinline__ float bflo(unsigned u) {
    return __builtin_bit_cast(float, u << 16);
}
static __device__ __forceinline__ float bfhi(unsigned u) {
    return __builtin_bit_cast(float, u & 0xFFFF0000u);
}

// ---------------------------------------------------------------------------
__global__ void probe_kernel(const unsigned* __restrict__ ei, int* __restrict__ flag) {
    if (blockIdx.x == 0 && threadIdx.x == 0) {
        int all0 = 1;
        for (int i = 0; i < 16; ++i) all0 &= (ei[2 * i + 1] == 0u);
        *flag = all0;  // 1 => int64 layout, 0 => int32 layout
    }
}

__device__ __forceinline__ int load_idx(const int* ei32, const long long* ei64,
                                        bool is64, long long pos) {
    return is64 ? (int)ei64[pos] : ei32[pos];
}

// ---------------------------------------------------------------------------
// Shared gemm body (256 threads, 4 waves): h = x @ W, bf16 store, UNSCALED.
// (round-9-proven code, unchanged)
static __device__ __forceinline__ void gemm_body(char* smem, int gbid, int nblk,
                                                 const float* __restrict__ x,
                                                 const float* __restrict__ W,
                                                 unsigned short* __restrict__ hs) {
    unsigned short (*Wf)[4][64][8] = (unsigned short (*)[4][64][8])smem;
    const int tid = threadIdx.x;
    const int lane = tid & 63;
    const int wv = tid >> 6;           // 4 waves

    for (int i = tid; i < 8 * 4 * 64 * 8; i += 256) {
        int kt = i >> 11;
        int rem = i & 2047;
        int ct = rem >> 9;
        int rem2 = rem & 511;
        int l = rem2 >> 3;
        int j = rem2 & 7;
        int kk = kt * 32 + (l >> 4) * 8 + j;
        int cc = ct * 16 + (l & 15);
        ((unsigned short*)Wf)[i] = f2bf(W[(size_t)kk * OUT_CH + cc]);
    }
    __syncthreads();

    const int r16 = lane & 15;   // A row within tile
    const int q = lane >> 4;     // k-quarter (A), row-quarter (C)

    for (int t = gbid * 4 + wv; t < N_TILES; t += nblk * 4) {
        const int row0 = t * 16;
        const float* xrow = &x[(size_t)(row0 + r16) * IN_CH + q * 8];
        f32x4 acc[4] = {{0.f,0.f,0.f,0.f},{0.f,0.f,0.f,0.f},
                        {0.f,0.f,0.f,0.f},{0.f,0.f,0.f,0.f}};
        #pragma unroll
        for (int kt = 0; kt < 8; ++kt) {
            float4 x0 = *(const float4*)&xrow[kt * 32];
            float4 x1 = *(const float4*)&xrow[kt * 32 + 4];
            unsigned p0, p1, p2, p3;
            asm("v_cvt_pk_bf16_f32 %0, %1, %2" : "=v"(p0) : "v"(x0.x), "v"(x0.y));
            asm("v_cvt_pk_bf16_f32 %0, %1, %2" : "=v"(p1) : "v"(x0.z), "v"(x0.w));
            asm("v_cvt_pk_bf16_f32 %0, %1, %2" : "=v"(p2) : "v"(x1.x), "v"(x1.y));
            asm("v_cvt_pk_bf16_f32 %0, %1, %2" : "=v"(p3) : "v"(x1.z), "v"(x1.w));
            u32x4 au = {p0, p1, p2, p3};
            bshort8 af = __builtin_bit_cast(bshort8, au);
            #pragma unroll
            for (int ct = 0; ct < 4; ++ct) {
                bshort8 bf = *(const bshort8*)&Wf[kt][ct][lane][0];
                acc[ct] = __builtin_amdgcn_mfma_f32_16x16x32_bf16(af, bf, acc[ct], 0, 0, 0);
            }
        }
        #pragma unroll
        for (int ct = 0; ct < 4; ++ct) {
            #pragma unroll
            for (int r = 0; r < 4; ++r) {
                int row = row0 + q * 4 + r;
                hs[(size_t)row * OUT_CH + ct * 16 + r16] = f2bf(acc[ct][r]);
            }
        }
    }
}

// ---------------------------------------------------------------------------
// FUSED: blocks [0, NBLK_PART) partition edges into fixed-capacity bucket
// slots (per-block LDS hist -> ONE global atomicAdd(gcnt[k]) reservation per
// (block,bucket) -> block-clustered writes); blocks [NBLK_PART, +NBLK_GEMM)
// run the independent gemm. pair = src | dLocal<<17.
__global__ __launch_bounds__(256) void part_gemm_kernel(const int* __restrict__ ei32,
                                                        const long long* __restrict__ ei64,
                                                        const int* __restrict__ flag,
                                                        unsigned* __restrict__ gcnt,
                                                        unsigned* __restrict__ edg,
                                                        const float* __restrict__ x,
                                                        const float* __restrict__ W,
                                                        unsigned short* __restrict__ hs) {
    __shared__ char smem[32768];
    const int bid = blockIdx.x;
    const int tid = threadIdx.x;

    if (bid < NBLK_PART) {
        unsigned* hist = (unsigned*)smem;          // 782 u32
        unsigned* cur  = ((unsigned*)smem) + 1024; // 782 u32
        const bool is64 = (*flag != 0);
        const int start = bid * T_PART;
        const int end   = min(start + T_PART, N_EDGES);
        for (int k = tid; k < K_BKT; k += 256) hist[k] = 0u;
        __syncthreads();
        // pass 1: histogram of dst buckets
        if (is64) {
            const longlong2* d2 = (const longlong2*)&ei64[N_EDGES];
            for (int i = (start >> 1) + tid; i < (end >> 1); i += 256) {
                longlong2 d = d2[i];
                atomicAdd(&hist[(int)d.x >> BKT_SHIFT], 1u);
                atomicAdd(&hist[(int)d.y >> BKT_SHIFT], 1u);
            }
        } else {
            const int2* d2 = (const int2*)&ei32[N_EDGES];
            for (int i = (start >> 1) + tid; i < (end >> 1); i += 256) {
                int2 d = d2[i];
                atomicAdd(&hist[d.x >> BKT_SHIFT], 1u);
                atomicAdd(&hist[d.y >> BKT_SHIFT], 1u);
            }
        }
        __syncthreads();
        // reserve a contiguous run per bucket in the padded slot region
        for (int k = tid; k < K_BKT; k += 256) {
            unsigned c = hist[k];
            unsigned base = c ? atomicAdd(&gcnt[k], c) : 0u;
            cur[k] = base + (unsigned)k * BKT_CAP;
        }
        __syncthreads();
        // pass 2: write pairs (block-clustered per bucket run; L2-merged)
        if (is64) {
            const longlong2* s2 = (const longlong2*)&ei64[0];
            const longlong2* d2 = (const longlong2*)&ei64[N_EDGES];
            for (int i = (start >> 1) + tid; i < (end >> 1); i += 256) {
                longlong2 s = s2[i];
                longlong2 d = d2[i];
                unsigned p0 = atomicAdd(&cur[(int)d.x >> BKT_SHIFT], 1u);
                edg[p0] = (unsigned)s.x | ((unsigned)((int)d.x & (BKT_R - 1)) << 17);
                unsigned p1 = atomicAdd(&cur[(int)d.y >> BKT_SHIFT], 1u);
                edg[p1] = (unsigned)s.y | ((unsigned)((int)d.y & (BKT_R - 1)) << 17);
            }
        } else {
            const int2* s2 = (const int2*)&ei32[0];
            const int2* d2 = (const int2*)&ei32[N_EDGES];
            for (int i = (start >> 1) + tid; i < (end >> 1); i += 256) {
                int2 s = s2[i];
                int2 d = d2[i];
                unsigned p0 = atomicAdd(&cur[d.x >> BKT_SHIFT], 1u);
                edg[p0] = (unsigned)s.x | ((unsigned)(d.x & (BKT_R - 1)) << 17);
                unsigned p1 = atomicAdd(&cur[d.y >> BKT_SHIFT], 1u);
                edg[p1] = (unsigned)s.y | ((unsigned)(d.y & (BKT_R - 1)) << 17);
            }
        }
    } else {
        gemm_body(smem, bid - NBLK_PART, NBLK_GEMM, x, W, hs);
    }
}

// gemm-only wrapper (fallback path)
__global__ __launch_bounds__(256) void gemm_only_kernel(const float* __restrict__ x,
                                                        const float* __restrict__ W,
                                                        unsigned short* __restrict__ hs) {
    __shared__ char smem[32768];
    gemm_body(smem, blockIdx.x, gridDim.x, x, W, hs);
}

// ---------------------------------------------------------------------------
// Within-bucket counting sort, LDS-staged and in place: loads the bucket's
// pairs into LDS, computes per-node CSR (nse = {start,end} in padded coords),
// dinv, and scatters sorted src ids back over the same slot region.
__global__ __launch_bounds__(256) void sort2_kernel(unsigned* __restrict__ edg,
                                                    const unsigned* __restrict__ gcnt,
                                                    uint2* __restrict__ nse,
                                                    float* __restrict__ dinv) {
    __shared__ unsigned ld[BKT_CAP];    // 24576 B
    __shared__ unsigned hist[BKT_R];
    __shared__ unsigned cur[BKT_R];
    const int k = blockIdx.x;
    const int t = threadIdx.x;
    const unsigned cnt = min(gcnt[k], (unsigned)BKT_CAP);
    const unsigned base = (unsigned)k * BKT_CAP;

    for (unsigned j = t; j < cnt; j += 256) ld[j] = edg[base + j];
    if (t < BKT_R) hist[t] = 0u;
    __syncthreads();
    for (unsigned j = t; j < cnt; j += 256)
        atomicAdd(&hist[ld[j] >> 17], 1u);
    __syncthreads();
    if (t < BKT_R) cur[t] = hist[t];
    __syncthreads();
    #pragma unroll
    for (int d = 1; d < BKT_R; d <<= 1) {
        unsigned x = (t < BKT_R && t >= d) ? cur[t - d] : 0u;
        __syncthreads();
        if (t < BKT_R) cur[t] += x;
        __syncthreads();
    }
    if (t < BKT_R) {
        unsigned mydeg = hist[t];
        unsigned start = base + cur[t] - mydeg;   // exclusive, padded coords
        int n = k * BKT_R + t;
        if (n < N_NODES) {
            nse[n] = make_uint2(start, start + mydeg);
            dinv[n] = rsqrtf((float)(mydeg + 1u));
        }
        cur[t] = start;
    }
    __syncthreads();
    for (unsigned j = t; j < cnt; j += 256) {
        unsigned p = ld[j];
        unsigned pos = atomicAdd(&cur[p >> 17], 1u);
        edg[pos] = p & 0x1FFFF;     // sorted src id
    }
}

// ---------------------------------------------------------------------------
// Wave per node, quarter-wave per edge, 16-edge unroll (4 gathers in flight).
// hs is UNSCALED; dinv[src] applied as fp32 fma. (round-9-proven; only the
// segment bounds now come from nse[n] = {start, end}.)
__global__ __launch_bounds__(256) void reduce_kernel(const unsigned short* __restrict__ hs,
                                                     const float* __restrict__ dinv,
                                                     const uint2* __restrict__ nse,
                                                     const int* __restrict__ ssrc,
                                                     const float* __restrict__ b,
                                                     float* __restrict__ out) {
    const int n = blockIdx.x * 4 + (threadIdx.x >> 6);
    const int lane = threadIdx.x & 63;
    const int q = lane >> 4;
    const int l16 = lane & 15;
    if (n >= N_NODES) return;
    const uint2* h8 = (const uint2*)hs;   // one row = 16 uint2
    const float dn = dinv[n];
    float a0 = 0.f, a1 = 0.f, a2 = 0.f, a3 = 0.f;
    {   // self-loop: h[n]*dinv[n]; counted once (q==0)
        uint2 sv = h8[(size_t)n * 16 + l16];
        if (q == 0) {
            a0 = bflo(sv.x) * dn; a1 = bfhi(sv.x) * dn;
            a2 = bflo(sv.y) * dn; a3 = bfhi(sv.y) * dn;
        }
    }
    uint2 se = nse[n];
    unsigned j = se.x;
    const unsigned end = se.y;
    for (; j + 16 <= end; j += 16) {
        int s0 = ssrc[j + q];
        int s1 = ssrc[j + 4 + q];
        int s2 = ssrc[j + 8 + q];
        int s3 = ssrc[j + 12 + q];
        float f0 = dinv[s0], f1 = dinv[s1], f2 = dinv[s2], f3 = dinv[s3];
        uint2 v0 = h8[(size_t)s0 * 16 + l16];
        uint2 v1 = h8[(size_t)s1 * 16 + l16];
        uint2 v2 = h8[(size_t)s2 * 16 + l16];
        uint2 v3 = h8[(size_t)s3 * 16 + l16];
        a0 = fmaf(bflo(v0.x), f0, a0); a1 = fmaf(bfhi(v0.x), f0, a1);
        a2 = fmaf(bflo(v0.y), f0, a2); a3 = fmaf(bfhi(v0.y), f0, a3);
        a0 = fmaf(bflo(v1.x), f1, a0); a1 = fmaf(bfhi(v1.x), f1, a1);
        a2 = fmaf(bflo(v1.y), f1, a2); a3 = fmaf(bfhi(v1.y), f1, a3);
        a0 = fmaf(bflo(v2.x), f2, a0); a1 = fmaf(bfhi(v2.x), f2, a1);
        a2 = fmaf(bflo(v2.y), f2, a2); a3 = fmaf(bfhi(v2.y), f2, a3);
        a0 = fmaf(bflo(v3.x), f3, a0); a1 = fmaf(bfhi(v3.x), f3, a1);
        a2 = fmaf(bflo(v3.y), f3, a2); a3 = fmaf(bfhi(v3.y), f3, a3);
    }
    for (; j + 4 <= end; j += 4) {
        int s = ssrc[j + q];
        float f = dinv[s];
        uint2 v = h8[(size_t)s * 16 + l16];
        a0 = fmaf(bflo(v.x), f, a0); a1 = fmaf(bfhi(v.x), f, a1);
        a2 = fmaf(bflo(v.y), f, a2); a3 = fmaf(bfhi(v.y), f, a3);
    }
    unsigned rem = end - j;
    if ((unsigned)q < rem) {
        int s = ssrc[j + q];
        float f = dinv[s];
        uint2 v = h8[(size_t)s * 16 + l16];
        a0 = fmaf(bflo(v.x), f, a0); a1 = fmaf(bfhi(v.x), f, a1);
        a2 = fmaf(bflo(v.y), f, a2); a3 = fmaf(bfhi(v.y), f, a3);
    }
    a0 += __shfl_xor(a0, 16); a0 += __shfl_xor(a0, 32);
    a1 += __shfl_xor(a1, 16); a1 += __shfl_xor(a1, 32);
    a2 += __shfl_xor(a2, 16); a2 += __shfl_xor(a2, 32);
    a3 += __shfl_xor(a3, 16); a3 += __shfl_xor(a3, 32);
    float4 bb = ((const float4*)b)[l16];
    float v0 = fmaxf(fmaf(a0, dn, bb.x), 0.f);
    float v1 = fmaxf(fmaf(a1, dn, bb.y), 0.f);
    float v2 = fmaxf(fmaf(a2, dn, bb.z), 0.f);
    float v3 = fmaxf(fmaf(a3, dn, bb.w), 0.f);
    float m = fmaxf(fmaxf(v0, v1), fmaxf(v2, v3));
    #pragma unroll
    for (int o = 8; o; o >>= 1) m = fmaxf(m, __shfl_xor(m, o));
    float sum = expf(v0 - m) + expf(v1 - m) + expf(v2 - m) + expf(v3 - m);
    #pragma unroll
    for (int o = 8; o; o >>= 1) sum += __shfl_xor(sum, o);
    float ls = logf(sum);
    if (q == 0) {
        float4 r;
        r.x = (v0 - m) - ls; r.y = (v1 - m) - ls;
        r.z = (v2 - m) - ls; r.w = (v3 - m) - ls;
        *(float4*)&out[(size_t)n * OUT_CH + l16 * 4] = r;
    }
}

// ---------------------------------------------------------------------------
// Fallback (atomic scatter) path, only if ws is too small for the CSR path.
__global__ __launch_bounds__(256) void deg_kernel(const int* __restrict__ ei32,
                                                  const long long* __restrict__ ei64,
                                                  const int* __restrict__ flag,
                                                  unsigned* __restrict__ deg) {
    const bool is64 = (*flag != 0);
    int i = blockIdx.x * blockDim.x + threadIdx.x;
    const int stride = gridDim.x * blockDim.x;
    for (; i < N_EDGES; i += stride) {
        int d = load_idx(ei32, ei64, is64, (long long)N_EDGES + i);
        atomicAdd(&deg[d], 1u);
    }
}

__global__ __launch_bounds__(256) void dinv_kernel(const unsigned* __restrict__ deg,
                                                   float* __restrict__ dinv) {
    int i = blockIdx.x * blockDim.x + threadIdx.x;
    if (i < N_NODES) dinv[i] = rsqrtf((float)(deg[i] + 1u));
}

__global__ __launch_bounds__(256) void scatter_kernel(const int* __restrict__ ei32,
                                                      const long long* __restrict__ ei64,
                                                      const int* __restrict__ flag,
                                                      const unsigned short* __restrict__ hs,
                                                      const float* __restrict__ dinv,
                                                      float* __restrict__ out) {
    const bool is64 = (*flag != 0);
    const int lane = threadIdx.x & 63;
    int w = blockIdx.x * (blockDim.x >> 6) + (threadIdx.x >> 6);
    const int nw = gridDim.x * (blockDim.x >> 6);
    for (int e = w; e < N_EDGES; e += nw) {
        int s = load_idx(ei32, ei64, is64, e);
        int d = load_idx(ei32, ei64, is64, (long long)N_EDGES + e);
        unsigned short us = hs[(size_t)s * OUT_CH + lane];
        float hv = __builtin_bit_cast(float, (unsigned)us << 16);
        atomicAdd(&out[(size_t)d * OUT_CH + lane], hv * dinv[s] * dinv[d]);
    }
}

__global__ __launch_bounds__(256) void final_kernel(const unsigned short* __restrict__ hs,
                                                    const float* __restrict__ dinv,
                                                    const float* __restrict__ b,
                                                    float* __restrict__ out) {
    const int lane = threadIdx.x & 63;
    int w = blockIdx.x * (blockDim.x >> 6) + (threadIdx.x >> 6);
    const int nw = gridDim.x * (blockDim.x >> 6);
    const float bias = b[lane];
    for (int n = w; n < N_NODES; n += nw) {
        float di = dinv[n];
        unsigned short us = hs[(size_t)n * OUT_CH + lane];
        float hv = __builtin_bit_cast(float, (unsigned)us << 16);
        float v = out[(size_t)n * OUT_CH + lane] + hv * di * di + bias;
        v = fmaxf(v, 0.f);
        float m = v;
        #pragma unroll
        for (int o = 32; o; o >>= 1) m = fmaxf(m, __shfl_xor(m, o));
        float ex = expf(v - m);
        float sum = ex;
        #pragma unroll
        for (int o = 32; o; o >>= 1) sum += __shfl_xor(sum, o);
        out[(size_t)n * OUT_CH + lane] = (v - m) - logf(sum);
    }
}

// ---------------------------------------------------------------------------
extern "C" void kernel_launch(void* const* d_in, const int* in_sizes, int n_in,
                              void* d_out, int out_size, void* d_ws, size_t ws_size,
                              hipStream_t stream) {
    const float* x  = (const float*)d_in[0];
    const void*  ei = d_in[1];
    const float* W  = (const float*)d_in[2];
    const float* b  = (const float*)d_in[3];
    float* out = (float*)d_out;

    char* ws = (char*)d_ws;
    int* flag = (int*)(ws + WS_FLAG_OFF);

    const int* ei32       = (const int*)ei;
    const long long* ei64 = (const long long*)ei;

    probe_kernel<<<1, 64, 0, stream>>>((const unsigned*)ei, flag);

    if (ws_size >= (size_t)WS_NEED) {
        unsigned* gcnt = (unsigned*)(ws + WS_GCNT_OFF);
        float*    dinv = (float*)(ws + WS_DINV_OFF);
        uint2*    nse  = (uint2*)(ws + WS_NSE_OFF);
        unsigned* edg  = (unsigned*)(ws + WS_EDG_OFF);
        unsigned short* hs = (unsigned short*)(ws + WS_H_OFF);

        hipMemsetAsync(gcnt, 0, K_BKT * sizeof(unsigned), stream);
        part_gemm_kernel<<<NBLK_PART + NBLK_GEMM, 256, 0, stream>>>(
            ei32, ei64, flag, gcnt, edg, x, W, hs);
        sort2_kernel<<<K_BKT, 256, 0, stream>>>(edg, gcnt, nse, dinv);
        reduce_kernel<<<(N_NODES + 3) / 4, 256, 0, stream>>>(
            hs, dinv, nse, (const int*)edg, b, out);
    } else {
        unsigned* deg  = (unsigned*)(ws + WSF_DEG_OFF);
        float*    dinv = (float*)(ws + WSF_DINV_OFF);
        unsigned short* hs = (unsigned short*)(ws + WSF_H_OFF);
        hipMemsetAsync(deg, 0, (size_t)N_NODES * sizeof(unsigned), stream);
        hipMemsetAsync(d_out, 0, (size_t)out_size * sizeof(float), stream);
        deg_kernel<<<2048, 256, 0, stream>>>(ei32, ei64, flag, deg);
        dinv_kernel<<<(N_NODES + 255) / 256, 256, 0, stream>>>(deg, dinv);
        gemm_only_kernel<<<NBLK_GEMM, 256, 0, stream>>>(x, W, hs);
        scatter_kernel<<<2048, 256, 0, stream>>>(ei32, ei64, flag, hs, dinv, out);
        final_kernel<<<1024, 256, 0, stream>>>(hs, dinv, b, out);
    }
}

// Round 11
// 165.834 us; speedup vs baseline: 9.1663x; 1.0617x over previous
//
#include <hip/hip_runtime.h>
#include <cstddef>
#include <cstdint>

#define N_NODES 100000
#define IN_CH 256
#define OUT_CH 64
#define N_EDGES 3200000

// bucketing: 128 nodes per bucket, fixed-capacity slots
#define BKT_SHIFT 7
#define BKT_R     128
#define K_BKT     782                 // ceil(100000/128)
#define BKT_CAP   6144                // mean 4096 + 32 sigma; slots of 24KB
#define T_PART    8192                // edges per partition block
#define NBLK_PART ((N_EDGES + T_PART - 1) / T_PART)   // 391
#define NBLK_GEMM 512
#define N_TILES   (N_NODES / 16)      // 6250

// ---- ws layout (bytes) ----
#define WS_FLAG_OFF   0
#define WS_GCNT_OFF   64              // 782 u32 bucket fill counts
#define WS_DINV_OFF   4096            // 400000 B
#define WS_NSE_OFF    404096          // 100000 uint2 = 800000 B
#define WS_EDG_OFF    1204224         // 782*6144*4 = 19,218,432 B (pairs -> sorted src)
#define WS_H_OFF      20422656        // bf16 h: 100000*64*2 = 12.8MB (unscaled)
#define WS_NEED       33222656

// ---- fallback (atomic) layout ----
#define WSF_DEG_OFF   4096
#define WSF_DINV_OFF  404096
#define WSF_H_OFF     804096

typedef __attribute__((ext_vector_type(8))) short bshort8;
typedef __attribute__((ext_vector_type(4))) float f32x4;
typedef __attribute__((ext_vector_type(4))) unsigned u32x4;

// ---------------------------------------------------------------------------
static __device__ __forceinline__ unsigned short f2bf(float f) {
    unsigned u = __builtin_bit_cast(unsigned, f);
    u += 0x7FFFu + ((u >> 16) & 1u);     // RNE (finite inputs)
    return (unsigned short)(u >> 16);
}
static __device__ __forceinline__ float bflo(unsigned u) {
    return __builtin_bit_cast(float, u << 16);
}
static __device__ __forceinline__ float bfhi(unsigned u) {
    return __builtin_bit_cast(float, u & 0xFFFF0000u);
}

// ---------------------------------------------------------------------------
__global__ void probe_kernel(const unsigned* __restrict__ ei, int* __restrict__ flag) {
    if (blockIdx.x == 0 && threadIdx.x == 0) {
        int all0 = 1;
        for (int i = 0; i < 16; ++i) all0 &= (ei[2 * i + 1] == 0u);
        *flag = all0;  // 1 => int64 layout, 0 => int32 layout
    }
}

__device__ __forceinline__ int load_idx(const int* ei32, const long long* ei64,
                                        bool is64, long long pos) {
    return is64 ? (int)ei64[pos] : ei32[pos];
}

// ---------------------------------------------------------------------------
// Shared gemm body (256 threads, 4 waves): h = x @ W, bf16 store, UNSCALED.
// (round-9/10-proven code, unchanged)
static __device__ __forceinline__ void gemm_body(char* smem, int gbid, int nblk,
                                                 const float* __restrict__ x,
                                                 const float* __restrict__ W,
                                                 unsigned short* __restrict__ hs) {
    unsigned short (*Wf)[4][64][8] = (unsigned short (*)[4][64][8])smem;
    const int tid = threadIdx.x;
    const int lane = tid & 63;
    const int wv = tid >> 6;           // 4 waves

    for (int i = tid; i < 8 * 4 * 64 * 8; i += 256) {
        int kt = i >> 11;
        int rem = i & 2047;
        int ct = rem >> 9;
        int rem2 = rem & 511;
        int l = rem2 >> 3;
        int j = rem2 & 7;
        int kk = kt * 32 + (l >> 4) * 8 + j;
        int cc = ct * 16 + (l & 15);
        ((unsigned short*)Wf)[i] = f2bf(W[(size_t)kk * OUT_CH + cc]);
    }
    __syncthreads();

    const int r16 = lane & 15;   // A row within tile
    const int q = lane >> 4;     // k-quarter (A), row-quarter (C)

    for (int t = gbid * 4 + wv; t < N_TILES; t += nblk * 4) {
        const int row0 = t * 16;
        const float* xrow = &x[(size_t)(row0 + r16) * IN_CH + q * 8];
        f32x4 acc[4] = {{0.f,0.f,0.f,0.f},{0.f,0.f,0.f,0.f},
                        {0.f,0.f,0.f,0.f},{0.f,0.f,0.f,0.f}};
        #pragma unroll
        for (int kt = 0; kt < 8; ++kt) {
            float4 x0 = *(const float4*)&xrow[kt * 32];
            float4 x1 = *(const float4*)&xrow[kt * 32 + 4];
            unsigned p0, p1, p2, p3;
            asm("v_cvt_pk_bf16_f32 %0, %1, %2" : "=v"(p0) : "v"(x0.x), "v"(x0.y));
            asm("v_cvt_pk_bf16_f32 %0, %1, %2" : "=v"(p1) : "v"(x0.z), "v"(x0.w));
            asm("v_cvt_pk_bf16_f32 %0, %1, %2" : "=v"(p2) : "v"(x1.x), "v"(x1.y));
            asm("v_cvt_pk_bf16_f32 %0, %1, %2" : "=v"(p3) : "v"(x1.z), "v"(x1.w));
            u32x4 au = {p0, p1, p2, p3};
            bshort8 af = __builtin_bit_cast(bshort8, au);
            #pragma unroll
            for (int ct = 0; ct < 4; ++ct) {
                bshort8 bf = *(const bshort8*)&Wf[kt][ct][lane][0];
                acc[ct] = __builtin_amdgcn_mfma_f32_16x16x32_bf16(af, bf, acc[ct], 0, 0, 0);
            }
        }
        #pragma unroll
        for (int ct = 0; ct < 4; ++ct) {
            #pragma unroll
            for (int r = 0; r < 4; ++r) {
                int row = row0 + q * 4 + r;
                hs[(size_t)row * OUT_CH + ct * 16 + r16] = f2bf(acc[ct][r]);
            }
        }
    }
}

// ---------------------------------------------------------------------------
// Standalone partition: 512 threads, small LDS (hist+cur = 6.4KB) => occupancy
// is threads-bound, not LDS-bound. Per-block LDS hist -> ONE global
// atomicAdd(gcnt[k]) reservation per (block,bucket) -> block-clustered writes
// into fixed-capacity slots. pair = src | dLocal<<17.
__global__ __launch_bounds__(512) void partition_kernel(const int* __restrict__ ei32,
                                                        const long long* __restrict__ ei64,
                                                        const int* __restrict__ flag,
                                                        unsigned* __restrict__ gcnt,
                                                        unsigned* __restrict__ edg) {
    __shared__ unsigned hist[K_BKT];
    __shared__ unsigned cur[K_BKT];
    const bool is64 = (*flag != 0);
    const int tid = threadIdx.x;
    const int start = blockIdx.x * T_PART;
    const int end   = min(start + T_PART, N_EDGES);
    for (int k = tid; k < K_BKT; k += 512) hist[k] = 0u;
    __syncthreads();
    // pass 1: histogram of dst buckets (2-edge vector loads)
    if (is64) {
        const longlong2* d2 = (const longlong2*)&ei64[N_EDGES];
        for (int i = (start >> 1) + tid; i < (end >> 1); i += 512) {
            longlong2 d = d2[i];
            atomicAdd(&hist[(int)d.x >> BKT_SHIFT], 1u);
            atomicAdd(&hist[(int)d.y >> BKT_SHIFT], 1u);
        }
    } else {
        const int2* d2 = (const int2*)&ei32[N_EDGES];
        for (int i = (start >> 1) + tid; i < (end >> 1); i += 512) {
            int2 d = d2[i];
            atomicAdd(&hist[d.x >> BKT_SHIFT], 1u);
            atomicAdd(&hist[d.y >> BKT_SHIFT], 1u);
        }
    }
    __syncthreads();
    // reserve a contiguous run per bucket in the padded slot region
    for (int k = tid; k < K_BKT; k += 512) {
        unsigned c = hist[k];
        unsigned base = c ? atomicAdd(&gcnt[k], c) : 0u;
        cur[k] = base + (unsigned)k * BKT_CAP;
    }
    __syncthreads();
    // pass 2: write pairs (block-clustered per bucket run; L2-merged)
    if (is64) {
        const longlong2* s2 = (const longlong2*)&ei64[0];
        const longlong2* d2 = (const longlong2*)&ei64[N_EDGES];
        for (int i = (start >> 1) + tid; i < (end >> 1); i += 512) {
            longlong2 s = s2[i];
            longlong2 d = d2[i];
            unsigned p0 = atomicAdd(&cur[(int)d.x >> BKT_SHIFT], 1u);
            edg[p0] = (unsigned)s.x | ((unsigned)((int)d.x & (BKT_R - 1)) << 17);
            unsigned p1 = atomicAdd(&cur[(int)d.y >> BKT_SHIFT], 1u);
            edg[p1] = (unsigned)s.y | ((unsigned)((int)d.y & (BKT_R - 1)) << 17);
        }
    } else {
        const int2* s2 = (const int2*)&ei32[0];
        const int2* d2 = (const int2*)&ei32[N_EDGES];
        for (int i = (start >> 1) + tid; i < (end >> 1); i += 512) {
            int2 s = s2[i];
            int2 d = d2[i];
            unsigned p0 = atomicAdd(&cur[d.x >> BKT_SHIFT], 1u);
            edg[p0] = (unsigned)s.x | ((unsigned)(d.x & (BKT_R - 1)) << 17);
            unsigned p1 = atomicAdd(&cur[d.y >> BKT_SHIFT], 1u);
            edg[p1] = (unsigned)s.y | ((unsigned)(d.y & (BKT_R - 1)) << 17);
        }
    }
}

// ---------------------------------------------------------------------------
// FUSED sort2 + gemm: blocks [0, K_BKT) do the within-bucket counting sort
// (LDS-staged, in place -> nse/dinv); blocks [K_BKT, +NBLK_GEMM) run the
// independent gemm. Both want ~25-32KB LDS, so the union wastes nothing.
__global__ __launch_bounds__(256) void sortgemm_kernel(unsigned* __restrict__ edg,
                                                       const unsigned* __restrict__ gcnt,
                                                       uint2* __restrict__ nse,
                                                       float* __restrict__ dinv,
                                                       const float* __restrict__ x,
                                                       const float* __restrict__ W,
                                                       unsigned short* __restrict__ hs) {
    __shared__ char smem[32768];
    const int bid = blockIdx.x;
    if (bid < K_BKT) {
        unsigned* ld   = (unsigned*)smem;            // 24576 B
        unsigned* hist = (unsigned*)(smem + 24576);  // 512 B
        unsigned* cur  = (unsigned*)(smem + 25088);  // 512 B
        const int k = bid;
        const int t = threadIdx.x;
        const unsigned cnt = min(gcnt[k], (unsigned)BKT_CAP);
        const unsigned base = (unsigned)k * BKT_CAP;

        for (unsigned j = t; j < cnt; j += 256) ld[j] = edg[base + j];
        if (t < BKT_R) hist[t] = 0u;
        __syncthreads();
        for (unsigned j = t; j < cnt; j += 256)
            atomicAdd(&hist[ld[j] >> 17], 1u);
        __syncthreads();
        if (t < BKT_R) cur[t] = hist[t];
        __syncthreads();
        #pragma unroll
        for (int d = 1; d < BKT_R; d <<= 1) {
            unsigned v = (t < BKT_R && t >= d) ? cur[t - d] : 0u;
            __syncthreads();
            if (t < BKT_R) cur[t] += v;
            __syncthreads();
        }
        if (t < BKT_R) {
            unsigned mydeg = hist[t];
            unsigned start = base + cur[t] - mydeg;   // exclusive, padded coords
            int n = k * BKT_R + t;
            if (n < N_NODES) {
                nse[n] = make_uint2(start, start + mydeg);
                dinv[n] = rsqrtf((float)(mydeg + 1u));
            }
            cur[t] = start;
        }
        __syncthreads();
        for (unsigned j = t; j < cnt; j += 256) {
            unsigned p = ld[j];
            unsigned pos = atomicAdd(&cur[p >> 17], 1u);
            edg[pos] = p & 0x1FFFF;     // sorted src id
        }
    } else {
        gemm_body(smem, bid - K_BKT, NBLK_GEMM, x, W, hs);
    }
}

// gemm-only wrapper (fallback path)
__global__ __launch_bounds__(256) void gemm_only_kernel(const float* __restrict__ x,
                                                        const float* __restrict__ W,
                                                        unsigned short* __restrict__ hs) {
    __shared__ char smem[32768];
    gemm_body(smem, blockIdx.x, gridDim.x, x, W, hs);
}

// ---------------------------------------------------------------------------
// Wave per node, quarter-wave per edge, 16-edge unroll (4 gathers in flight).
// hs is UNSCALED; dinv[src] applied as fp32 fma. (round-10-proven, unchanged)
__global__ __launch_bounds__(256) void reduce_kernel(const unsigned short* __restrict__ hs,
                                                     const float* __restrict__ dinv,
                                                     const uint2* __restrict__ nse,
                                                     const int* __restrict__ ssrc,
                                                     const float* __restrict__ b,
                                                     float* __restrict__ out) {
    const int n = blockIdx.x * 4 + (threadIdx.x >> 6);
    const int lane = threadIdx.x & 63;
    const int q = lane >> 4;
    const int l16 = lane & 15;
    if (n >= N_NODES) return;
    const uint2* h8 = (const uint2*)hs;   // one row = 16 uint2
    const float dn = dinv[n];
    float a0 = 0.f, a1 = 0.f, a2 = 0.f, a3 = 0.f;
    {   // self-loop: h[n]*dinv[n]; counted once (q==0)
        uint2 sv = h8[(size_t)n * 16 + l16];
        if (q == 0) {
            a0 = bflo(sv.x) * dn; a1 = bfhi(sv.x) * dn;
            a2 = bflo(sv.y) * dn; a3 = bfhi(sv.y) * dn;
        }
    }
    uint2 se = nse[n];
    unsigned j = se.x;
    const unsigned end = se.y;
    for (; j + 16 <= end; j += 16) {
        int s0 = ssrc[j + q];
        int s1 = ssrc[j + 4 + q];
        int s2 = ssrc[j + 8 + q];
        int s3 = ssrc[j + 12 + q];
        float f0 = dinv[s0], f1 = dinv[s1], f2 = dinv[s2], f3 = dinv[s3];
        uint2 v0 = h8[(size_t)s0 * 16 + l16];
        uint2 v1 = h8[(size_t)s1 * 16 + l16];
        uint2 v2 = h8[(size_t)s2 * 16 + l16];
        uint2 v3 = h8[(size_t)s3 * 16 + l16];
        a0 = fmaf(bflo(v0.x), f0, a0); a1 = fmaf(bfhi(v0.x), f0, a1);
        a2 = fmaf(bflo(v0.y), f0, a2); a3 = fmaf(bfhi(v0.y), f0, a3);
        a0 = fmaf(bflo(v1.x), f1, a0); a1 = fmaf(bfhi(v1.x), f1, a1);
        a2 = fmaf(bflo(v1.y), f1, a2); a3 = fmaf(bfhi(v1.y), f1, a3);
        a0 = fmaf(bflo(v2.x), f2, a0); a1 = fmaf(bfhi(v2.x), f2, a1);
        a2 = fmaf(bflo(v2.y), f2, a2); a3 = fmaf(bfhi(v2.y), f2, a3);
        a0 = fmaf(bflo(v3.x), f3, a0); a1 = fmaf(bfhi(v3.x), f3, a1);
        a2 = fmaf(bflo(v3.y), f3, a2); a3 = fmaf(bfhi(v3.y), f3, a3);
    }
    for (; j + 4 <= end; j += 4) {
        int s = ssrc[j + q];
        float f = dinv[s];
        uint2 v = h8[(size_t)s * 16 + l16];
        a0 = fmaf(bflo(v.x), f, a0); a1 = fmaf(bfhi(v.x), f, a1);
        a2 = fmaf(bflo(v.y), f, a2); a3 = fmaf(bfhi(v.y), f, a3);
    }
    unsigned rem = end - j;
    if ((unsigned)q < rem) {
        int s = ssrc[j + q];
        float f = dinv[s];
        uint2 v = h8[(size_t)s * 16 + l16];
        a0 = fmaf(bflo(v.x), f, a0); a1 = fmaf(bfhi(v.x), f, a1);
        a2 = fmaf(bflo(v.y), f, a2); a3 = fmaf(bfhi(v.y), f, a3);
    }
    a0 += __shfl_xor(a0, 16); a0 += __shfl_xor(a0, 32);
    a1 += __shfl_xor(a1, 16); a1 += __shfl_xor(a1, 32);
    a2 += __shfl_xor(a2, 16); a2 += __shfl_xor(a2, 32);
    a3 += __shfl_xor(a3, 16); a3 += __shfl_xor(a3, 32);
    float4 bb = ((const float4*)b)[l16];
    float v0 = fmaxf(fmaf(a0, dn, bb.x), 0.f);
    float v1 = fmaxf(fmaf(a1, dn, bb.y), 0.f);
    float v2 = fmaxf(fmaf(a2, dn, bb.z), 0.f);
    float v3 = fmaxf(fmaf(a3, dn, bb.w), 0.f);
    float m = fmaxf(fmaxf(v0, v1), fmaxf(v2, v3));
    #pragma unroll
    for (int o = 8; o; o >>= 1) m = fmaxf(m, __shfl_xor(m, o));
    float sum = expf(v0 - m) + expf(v1 - m) + expf(v2 - m) + expf(v3 - m);
    #pragma unroll
    for (int o = 8; o; o >>= 1) sum += __shfl_xor(sum, o);
    float ls = logf(sum);
    if (q == 0) {
        float4 r;
        r.x = (v0 - m) - ls; r.y = (v1 - m) - ls;
        r.z = (v2 - m) - ls; r.w = (v3 - m) - ls;
        *(float4*)&out[(size_t)n * OUT_CH + l16 * 4] = r;
    }
}

// ---------------------------------------------------------------------------
// Fallback (atomic scatter) path, only if ws is too small for the CSR path.
__global__ __launch_bounds__(256) void deg_kernel(const int* __restrict__ ei32,
                                                  const long long* __restrict__ ei64,
                                                  const int* __restrict__ flag,
                                                  unsigned* __restrict__ deg) {
    const bool is64 = (*flag != 0);
    int i = blockIdx.x * blockDim.x + threadIdx.x;
    const int stride = gridDim.x * blockDim.x;
    for (; i < N_EDGES; i += stride) {
        int d = load_idx(ei32, ei64, is64, (long long)N_EDGES + i);
        atomicAdd(&deg[d], 1u);
    }
}

__global__ __launch_bounds__(256) void dinv_kernel(const unsigned* __restrict__ deg,
                                                   float* __restrict__ dinv) {
    int i = blockIdx.x * blockDim.x + threadIdx.x;
    if (i < N_NODES) dinv[i] = rsqrtf((float)(deg[i] + 1u));
}

__global__ __launch_bounds__(256) void scatter_kernel(const int* __restrict__ ei32,
                                                      const long long* __restrict__ ei64,
                                                      const int* __restrict__ flag,
                                                      const unsigned short* __restrict__ hs,
                                                      const float* __restrict__ dinv,
                                                      float* __restrict__ out) {
    const bool is64 = (*flag != 0);
    const int lane = threadIdx.x & 63;
    int w = blockIdx.x * (blockDim.x >> 6) + (threadIdx.x >> 6);
    const int nw = gridDim.x * (blockDim.x >> 6);
    for (int e = w; e < N_EDGES; e += nw) {
        int s = load_idx(ei32, ei64, is64, e);
        int d = load_idx(ei32, ei64, is64, (long long)N_EDGES + e);
        unsigned short us = hs[(size_t)s * OUT_CH + lane];
        float hv = __builtin_bit_cast(float, (unsigned)us << 16);
        atomicAdd(&out[(size_t)d * OUT_CH + lane], hv * dinv[s] * dinv[d]);
    }
}

__global__ __launch_bounds__(256) void final_kernel(const unsigned short* __restrict__ hs,
                                                    const float* __restrict__ dinv,
                                                    const float* __restrict__ b,
                                                    float* __restrict__ out) {
    const int lane = threadIdx.x & 63;
    int w = blockIdx.x * (blockDim.x >> 6) + (threadIdx.x >> 6);
    const int nw = gridDim.x * (blockDim.x >> 6);
    const float bias = b[lane];
    for (int n = w; n < N_NODES; n += nw) {
        float di = dinv[n];
        unsigned short us = hs[(size_t)n * OUT_CH + lane];
        float hv = __builtin_bit_cast(float, (unsigned)us << 16);
        float v = out[(size_t)n * OUT_CH + lane] + hv * di * di + bias;
        v = fmaxf(v, 0.f);
        float m = v;
        #pragma unroll
        for (int o = 32; o; o >>= 1) m = fmaxf(m, __shfl_xor(m, o));
        float ex = expf(v - m);
        float sum = ex;
        #pragma unroll
        for (int o = 32; o; o >>= 1) sum += __shfl_xor(sum, o);
        out[(size_t)n * OUT_CH + lane] = (v - m) - logf(sum);
    }
}

// ---------------------------------------------------------------------------
extern "C" void kernel_launch(void* const* d_in, const int* in_sizes, int n_in,
                              void* d_out, int out_size, void* d_ws, size_t ws_size,
                              hipStream_t stream) {
    const float* x  = (const float*)d_in[0];
    const void*  ei = d_in[1];
    const float* W  = (const float*)d_in[2];
    const float* b  = (const float*)d_in[3];
    float* out = (float*)d_out;

    char* ws = (char*)d_ws;
    int* flag = (int*)(ws + WS_FLAG_OFF);

    const int* ei32       = (const int*)ei;
    const long long* ei64 = (const long long*)ei;

    probe_kernel<<<1, 64, 0, stream>>>((const unsigned*)ei, flag);

    if (ws_size >= (size_t)WS_NEED) {
        unsigned* gcnt = (unsigned*)(ws + WS_GCNT_OFF);
        float*    dinv = (float*)(ws + WS_DINV_OFF);
        uint2*    nse  = (uint2*)(ws + WS_NSE_OFF);
        unsigned* edg  = (unsigned*)(ws + WS_EDG_OFF);
        unsigned short* hs = (unsigned short*)(ws + WS_H_OFF);

        hipMemsetAsync(gcnt, 0, K_BKT * sizeof(unsigned), stream);
        partition_kernel<<<NBLK_PART, 512, 0, stream>>>(ei32, ei64, flag, gcnt, edg);
        sortgemm_kernel<<<K_BKT + NBLK_GEMM, 256, 0, stream>>>(
            edg, gcnt, nse, dinv, x, W, hs);
        reduce_kernel<<<(N_NODES + 3) / 4, 256, 0, stream>>>(
            hs, dinv, nse, (const int*)edg, b, out);
    } else {
        unsigned* deg  = (unsigned*)(ws + WSF_DEG_OFF);
        float*    dinv = (float*)(ws + WSF_DINV_OFF);
        unsigned short* hs = (unsigned short*)(ws + WSF_H_OFF);
        hipMemsetAsync(deg, 0, (size_t)N_NODES * sizeof(unsigned), stream);
        hipMemsetAsync(d_out, 0, (size_t)out_size * sizeof(float), stream);
        deg_kernel<<<2048, 256, 0, stream>>>(ei32, ei64, flag, deg);
        dinv_kernel<<<(N_NODES + 255) / 256, 256, 0, stream>>>(deg, dinv);
        gemm_only_kernel<<<NBLK_GEMM, 256, 0, stream>>>(x, W, hs);
        scatter_kernel<<<2048, 256, 0, stream>>>(ei32, ei64, flag, hs, dinv, out);
        final_kernel<<<1024, 256, 0, stream>>>(hs, dinv, b, out);
    }
}

// Round 12
// 161.887 us; speedup vs baseline: 9.3898x; 1.0244x over previous
//
#include <hip/hip_runtime.h>
#include <cstddef>
#include <cstdint>

#define N_NODES 100000
#define IN_CH 256
#define OUT_CH 64
#define N_EDGES 3200000

// bucketing: 128 nodes per bucket, fixed-capacity slots
#define BKT_SHIFT 7
#define BKT_R     128
#define K_BKT     782                 // ceil(100000/128)
#define BKT_CAP   6144                // mean 4096 + 32 sigma; slots of 24KB
#define T_PART    8192                // edges per partition block
#define NBLK_PART ((N_EDGES + T_PART - 1) / T_PART)   // 391
#define NBLK_GEMM 512
#define N_TILES   (N_NODES / 16)      // 6250

// ---- ws layout (bytes) ----
#define WS_FLAG_OFF   0
#define WS_GCNT_OFF   64              // 782 u32 bucket fill counts
#define WS_DINV_OFF   4096            // 400000 B
#define WS_NSE_OFF    404096          // 100000 uint2 = 800000 B
#define WS_EDG_OFF    1204224         // 782*6144*4 = 19,218,432 B (pairs -> sorted src)
#define WS_H_OFF      20422656        // bf16 h: 100000*64*2 = 12.8MB (unscaled)
#define WS_NEED       33222656

// ---- fallback (atomic) layout ----
#define WSF_DEG_OFF   4096
#define WSF_DINV_OFF  404096
#define WSF_H_OFF     804096

typedef __attribute__((ext_vector_type(8))) short bshort8;
typedef __attribute__((ext_vector_type(4))) float f32x4;
typedef __attribute__((ext_vector_type(2))) float f32x2;
typedef __attribute__((ext_vector_type(4))) unsigned u32x4;

// ---------------------------------------------------------------------------
static __device__ __forceinline__ unsigned short f2bf(float f) {
    unsigned u = __builtin_bit_cast(unsigned, f);
    u += 0x7FFFu + ((u >> 16) & 1u);     // RNE (finite inputs)
    return (unsigned short)(u >> 16);
}
static __device__ __forceinline__ float bflo(unsigned u) {
    return __builtin_bit_cast(float, u << 16);
}
static __device__ __forceinline__ float bfhi(unsigned u) {
    return __builtin_bit_cast(float, u & 0xFFFF0000u);
}
// unpack u32 of 2 bf16 -> f32x2 {lo, hi}; vector form so the compiler can use
// v_pk_fma_f32 on the subsequent multiply-accumulate.
static __device__ __forceinline__ f32x2 up2(unsigned u) {
    f32x2 r;
    r.x = __builtin_bit_cast(float, u << 16);
    r.y = __builtin_bit_cast(float, u & 0xFFFF0000u);
    return r;
}

// ---------------------------------------------------------------------------
// probe: detect int64 vs int32 edge layout AND zero the gcnt counters.
__global__ void probe_kernel(const unsigned* __restrict__ ei, int* __restrict__ flag,
                             unsigned* __restrict__ gcnt) {
    if (blockIdx.x == 0) {
        for (int k = threadIdx.x; k < K_BKT; k += 64) gcnt[k] = 0u;
        if (threadIdx.x == 0) {
            int all0 = 1;
            for (int i = 0; i < 16; ++i) all0 &= (ei[2 * i + 1] == 0u);
            *flag = all0;  // 1 => int64 layout, 0 => int32 layout
        }
    }
}

__device__ __forceinline__ int load_idx(const int* ei32, const long long* ei64,
                                        bool is64, long long pos) {
    return is64 ? (int)ei64[pos] : ei32[pos];
}

// ---------------------------------------------------------------------------
// Shared gemm body (256 threads, 4 waves): h = x @ W, bf16 store, UNSCALED.
// (round-9/10/11-proven code, unchanged)
static __device__ __forceinline__ void gemm_body(char* smem, int gbid, int nblk,
                                                 const float* __restrict__ x,
                                                 const float* __restrict__ W,
                                                 unsigned short* __restrict__ hs) {
    unsigned short (*Wf)[4][64][8] = (unsigned short (*)[4][64][8])smem;
    const int tid = threadIdx.x;
    const int lane = tid & 63;
    const int wv = tid >> 6;           // 4 waves

    for (int i = tid; i < 8 * 4 * 64 * 8; i += 256) {
        int kt = i >> 11;
        int rem = i & 2047;
        int ct = rem >> 9;
        int rem2 = rem & 511;
        int l = rem2 >> 3;
        int j = rem2 & 7;
        int kk = kt * 32 + (l >> 4) * 8 + j;
        int cc = ct * 16 + (l & 15);
        ((unsigned short*)Wf)[i] = f2bf(W[(size_t)kk * OUT_CH + cc]);
    }
    __syncthreads();

    const int r16 = lane & 15;   // A row within tile
    const int q = lane >> 4;     // k-quarter (A), row-quarter (C)

    for (int t = gbid * 4 + wv; t < N_TILES; t += nblk * 4) {
        const int row0 = t * 16;
        const float* xrow = &x[(size_t)(row0 + r16) * IN_CH + q * 8];
        f32x4 acc[4] = {{0.f,0.f,0.f,0.f},{0.f,0.f,0.f,0.f},
                        {0.f,0.f,0.f,0.f},{0.f,0.f,0.f,0.f}};
        #pragma unroll
        for (int kt = 0; kt < 8; ++kt) {
            float4 x0 = *(const float4*)&xrow[kt * 32];
            float4 x1 = *(const float4*)&xrow[kt * 32 + 4];
            unsigned p0, p1, p2, p3;
            asm("v_cvt_pk_bf16_f32 %0, %1, %2" : "=v"(p0) : "v"(x0.x), "v"(x0.y));
            asm("v_cvt_pk_bf16_f32 %0, %1, %2" : "=v"(p1) : "v"(x0.z), "v"(x0.w));
            asm("v_cvt_pk_bf16_f32 %0, %1, %2" : "=v"(p2) : "v"(x1.x), "v"(x1.y));
            asm("v_cvt_pk_bf16_f32 %0, %1, %2" : "=v"(p3) : "v"(x1.z), "v"(x1.w));
            u32x4 au = {p0, p1, p2, p3};
            bshort8 af = __builtin_bit_cast(bshort8, au);
            #pragma unroll
            for (int ct = 0; ct < 4; ++ct) {
                bshort8 bf = *(const bshort8*)&Wf[kt][ct][lane][0];
                acc[ct] = __builtin_amdgcn_mfma_f32_16x16x32_bf16(af, bf, acc[ct], 0, 0, 0);
            }
        }
        #pragma unroll
        for (int ct = 0; ct < 4; ++ct) {
            #pragma unroll
            for (int r = 0; r < 4; ++r) {
                int row = row0 + q * 4 + r;
                hs[(size_t)row * OUT_CH + ct * 16 + r16] = f2bf(acc[ct][r]);
            }
        }
    }
}

// ---------------------------------------------------------------------------
// Standalone partition, 512 threads, 6.4KB LDS. Pass 1 histograms dst buckets
// AND register-caches the dst ids (16 VGPR/thread, statically indexed), so
// pass 2 reads ONLY the src stream (saves 25.6MB of dst re-read).
__global__ __launch_bounds__(512) void partition_kernel(const int* __restrict__ ei32,
                                                        const long long* __restrict__ ei64,
                                                        const int* __restrict__ flag,
                                                        unsigned* __restrict__ gcnt,
                                                        unsigned* __restrict__ edg) {
    __shared__ unsigned hist[K_BKT];
    __shared__ unsigned cur[K_BKT];
    const bool is64 = (*flag != 0);
    const int tid = threadIdx.x;
    const int start = blockIdx.x * T_PART;
    const int end   = min(start + T_PART, N_EDGES);
    const int pbase = start >> 1;
    const int pend  = end >> 1;
    unsigned dcx[8], dcy[8];

    for (int k = tid; k < K_BKT; k += 512) hist[k] = 0u;
    __syncthreads();
    // pass 1: histogram + register-cache dst ids
    if (is64) {
        const longlong2* d2 = (const longlong2*)&ei64[N_EDGES];
        #pragma unroll
        for (int it = 0; it < 8; ++it) {
            int i = pbase + it * 512 + tid;
            if (i < pend) {
                longlong2 d = d2[i];
                dcx[it] = (unsigned)(int)d.x;
                dcy[it] = (unsigned)(int)d.y;
                atomicAdd(&hist[dcx[it] >> BKT_SHIFT], 1u);
                atomicAdd(&hist[dcy[it] >> BKT_SHIFT], 1u);
            }
        }
    } else {
        const int2* d2 = (const int2*)&ei32[N_EDGES];
        #pragma unroll
        for (int it = 0; it < 8; ++it) {
            int i = pbase + it * 512 + tid;
            if (i < pend) {
                int2 d = d2[i];
                dcx[it] = (unsigned)d.x;
                dcy[it] = (unsigned)d.y;
                atomicAdd(&hist[dcx[it] >> BKT_SHIFT], 1u);
                atomicAdd(&hist[dcy[it] >> BKT_SHIFT], 1u);
            }
        }
    }
    __syncthreads();
    // reserve a contiguous run per bucket in the padded slot region
    for (int k = tid; k < K_BKT; k += 512) {
        unsigned c = hist[k];
        unsigned base = c ? atomicAdd(&gcnt[k], c) : 0u;
        cur[k] = base + (unsigned)k * BKT_CAP;
    }
    __syncthreads();
    // pass 2: read ONLY src stream; dst from registers
    if (is64) {
        const longlong2* s2 = (const longlong2*)&ei64[0];
        #pragma unroll
        for (int it = 0; it < 8; ++it) {
            int i = pbase + it * 512 + tid;
            if (i < pend) {
                longlong2 s = s2[i];
                unsigned dx = dcx[it], dy = dcy[it];
                unsigned p0 = atomicAdd(&cur[dx >> BKT_SHIFT], 1u);
                edg[p0] = (unsigned)s.x | ((dx & (BKT_R - 1)) << 17);
                unsigned p1 = atomicAdd(&cur[dy >> BKT_SHIFT], 1u);
                edg[p1] = (unsigned)s.y | ((dy & (BKT_R - 1)) << 17);
            }
        }
    } else {
        const int2* s2 = (const int2*)&ei32[0];
        #pragma unroll
        for (int it = 0; it < 8; ++it) {
            int i = pbase + it * 512 + tid;
            if (i < pend) {
                int2 s = s2[i];
                unsigned dx = dcx[it], dy = dcy[it];
                unsigned p0 = atomicAdd(&cur[dx >> BKT_SHIFT], 1u);
                edg[p0] = (unsigned)s.x | ((dx & (BKT_R - 1)) << 17);
                unsigned p1 = atomicAdd(&cur[dy >> BKT_SHIFT], 1u);
                edg[p1] = (unsigned)s.y | ((dy & (BKT_R - 1)) << 17);
            }
        }
    }
}

// ---------------------------------------------------------------------------
// FUSED sort2 + gemm (round-11-proven): blocks [0, K_BKT) counting-sort their
// bucket (LDS-staged, in place -> nse/dinv); blocks [K_BKT, +NBLK_GEMM) gemm.
__global__ __launch_bounds__(256) void sortgemm_kernel(unsigned* __restrict__ edg,
                                                       const unsigned* __restrict__ gcnt,
                                                       uint2* __restrict__ nse,
                                                       float* __restrict__ dinv,
                                                       const float* __restrict__ x,
                                                       const float* __restrict__ W,
                                                       unsigned short* __restrict__ hs) {
    __shared__ char smem[32768];
    const int bid = blockIdx.x;
    if (bid < K_BKT) {
        unsigned* ld   = (unsigned*)smem;            // 24576 B
        unsigned* hist = (unsigned*)(smem + 24576);  // 512 B
        unsigned* cur  = (unsigned*)(smem + 25088);  // 512 B
        const int k = bid;
        const int t = threadIdx.x;
        const unsigned cnt = min(gcnt[k], (unsigned)BKT_CAP);
        const unsigned base = (unsigned)k * BKT_CAP;

        for (unsigned j = t; j < cnt; j += 256) ld[j] = edg[base + j];
        if (t < BKT_R) hist[t] = 0u;
        __syncthreads();
        for (unsigned j = t; j < cnt; j += 256)
            atomicAdd(&hist[ld[j] >> 17], 1u);
        __syncthreads();
        if (t < BKT_R) cur[t] = hist[t];
        __syncthreads();
        #pragma unroll
        for (int d = 1; d < BKT_R; d <<= 1) {
            unsigned v = (t < BKT_R && t >= d) ? cur[t - d] : 0u;
            __syncthreads();
            if (t < BKT_R) cur[t] += v;
            __syncthreads();
        }
        if (t < BKT_R) {
            unsigned mydeg = hist[t];
            unsigned start = base + cur[t] - mydeg;   // exclusive, padded coords
            int n = k * BKT_R + t;
            if (n < N_NODES) {
                nse[n] = make_uint2(start, start + mydeg);
                dinv[n] = rsqrtf((float)(mydeg + 1u));
            }
            cur[t] = start;
        }
        __syncthreads();
        for (unsigned j = t; j < cnt; j += 256) {
            unsigned p = ld[j];
            unsigned pos = atomicAdd(&cur[p >> 17], 1u);
            edg[pos] = p & 0x1FFFF;     // sorted src id
        }
    } else {
        gemm_body(smem, bid - K_BKT, NBLK_GEMM, x, W, hs);
    }
}

// gemm-only wrapper (fallback path)
__global__ __launch_bounds__(256) void gemm_only_kernel(const float* __restrict__ x,
                                                        const float* __restrict__ W,
                                                        unsigned short* __restrict__ hs) {
    __shared__ char smem[32768];
    gemm_body(smem, blockIdx.x, gridDim.x, x, W, hs);
}

// ---------------------------------------------------------------------------
// Wave per node, quarter-wave per edge, 16-edge unroll (4 gathers in flight).
// Accumulators/ops are f32x2 so the compiler can emit v_pk_fma_f32 (packed
// fp32 FMA = 2 fma/instr). Numerics identical to the scalar round-11 version.
__global__ __launch_bounds__(256) void reduce_kernel(const unsigned short* __restrict__ hs,
                                                     const float* __restrict__ dinv,
                                                     const uint2* __restrict__ nse,
                                                     const int* __restrict__ ssrc,
                                                     const float* __restrict__ b,
                                                     float* __restrict__ out) {
    const int n = blockIdx.x * 4 + (threadIdx.x >> 6);
    const int lane = threadIdx.x & 63;
    const int q = lane >> 4;
    const int l16 = lane & 15;
    if (n >= N_NODES) return;
    const uint2* h8 = (const uint2*)hs;   // one row = 16 uint2
    const float dn = dinv[n];
    f32x2 A01 = {0.f, 0.f}, A23 = {0.f, 0.f};
    {   // self-loop: h[n]*dinv[n]; counted once (q==0)
        uint2 sv = h8[(size_t)n * 16 + l16];
        if (q == 0) {
            f32x2 dnv = {dn, dn};
            A01 = up2(sv.x) * dnv;
            A23 = up2(sv.y) * dnv;
        }
    }
    uint2 se = nse[n];
    unsigned j = se.x;
    const unsigned end = se.y;
    for (; j + 16 <= end; j += 16) {
        int s0 = ssrc[j + q];
        int s1 = ssrc[j + 4 + q];
        int s2 = ssrc[j + 8 + q];
        int s3 = ssrc[j + 12 + q];
        float f0 = dinv[s0], f1 = dinv[s1], f2 = dinv[s2], f3 = dinv[s3];
        uint2 v0 = h8[(size_t)s0 * 16 + l16];
        uint2 v1 = h8[(size_t)s1 * 16 + l16];
        uint2 v2 = h8[(size_t)s2 * 16 + l16];
        uint2 v3 = h8[(size_t)s3 * 16 + l16];
        f32x2 F0 = {f0, f0}, F1 = {f1, f1}, F2 = {f2, f2}, F3 = {f3, f3};
        A01 += up2(v0.x) * F0; A23 += up2(v0.y) * F0;
        A01 += up2(v1.x) * F1; A23 += up2(v1.y) * F1;
        A01 += up2(v2.x) * F2; A23 += up2(v2.y) * F2;
        A01 += up2(v3.x) * F3; A23 += up2(v3.y) * F3;
    }
    for (; j + 4 <= end; j += 4) {
        int s = ssrc[j + q];
        float f = dinv[s];
        uint2 v = h8[(size_t)s * 16 + l16];
        f32x2 F = {f, f};
        A01 += up2(v.x) * F; A23 += up2(v.y) * F;
    }
    unsigned rem = end - j;
    if ((unsigned)q < rem) {
        int s = ssrc[j + q];
        float f = dinv[s];
        uint2 v = h8[(size_t)s * 16 + l16];
        f32x2 F = {f, f};
        A01 += up2(v.x) * F; A23 += up2(v.y) * F;
    }
    float a0 = A01.x, a1 = A01.y, a2 = A23.x, a3 = A23.y;
    a0 += __shfl_xor(a0, 16); a0 += __shfl_xor(a0, 32);
    a1 += __shfl_xor(a1, 16); a1 += __shfl_xor(a1, 32);
    a2 += __shfl_xor(a2, 16); a2 += __shfl_xor(a2, 32);
    a3 += __shfl_xor(a3, 16); a3 += __shfl_xor(a3, 32);
    float4 bb = ((const float4*)b)[l16];
    float v0 = fmaxf(fmaf(a0, dn, bb.x), 0.f);
    float v1 = fmaxf(fmaf(a1, dn, bb.y), 0.f);
    float v2 = fmaxf(fmaf(a2, dn, bb.z), 0.f);
    float v3 = fmaxf(fmaf(a3, dn, bb.w), 0.f);
    float m = fmaxf(fmaxf(v0, v1), fmaxf(v2, v3));
    #pragma unroll
    for (int o = 8; o; o >>= 1) m = fmaxf(m, __shfl_xor(m, o));
    float sum = expf(v0 - m) + expf(v1 - m) + expf(v2 - m) + expf(v3 - m);
    #pragma unroll
    for (int o = 8; o; o >>= 1) sum += __shfl_xor(sum, o);
    float ls = logf(sum);
    if (q == 0) {
        float4 r;
        r.x = (v0 - m) - ls; r.y = (v1 - m) - ls;
        r.z = (v2 - m) - ls; r.w = (v3 - m) - ls;
        *(float4*)&out[(size_t)n * OUT_CH + l16 * 4] = r;
    }
}

// ---------------------------------------------------------------------------
// Fallback (atomic scatter) path, only if ws is too small for the CSR path.
__global__ __launch_bounds__(256) void deg_kernel(const int* __restrict__ ei32,
                                                  const long long* __restrict__ ei64,
                                                  const int* __restrict__ flag,
                                                  unsigned* __restrict__ deg) {
    const bool is64 = (*flag != 0);
    int i = blockIdx.x * blockDim.x + threadIdx.x;
    const int stride = gridDim.x * blockDim.x;
    for (; i < N_EDGES; i += stride) {
        int d = load_idx(ei32, ei64, is64, (long long)N_EDGES + i);
        atomicAdd(&deg[d], 1u);
    }
}

__global__ __launch_bounds__(256) void dinv_kernel(const unsigned* __restrict__ deg,
                                                   float* __restrict__ dinv) {
    int i = blockIdx.x * blockDim.x + threadIdx.x;
    if (i < N_NODES) dinv[i] = rsqrtf((float)(deg[i] + 1u));
}

__global__ __launch_bounds__(256) void scatter_kernel(const int* __restrict__ ei32,
                                                      const long long* __restrict__ ei64,
                                                      const int* __restrict__ flag,
                                                      const unsigned short* __restrict__ hs,
                                                      const float* __restrict__ dinv,
                                                      float* __restrict__ out) {
    const bool is64 = (*flag != 0);
    const int lane = threadIdx.x & 63;
    int w = blockIdx.x * (blockDim.x >> 6) + (threadIdx.x >> 6);
    const int nw = gridDim.x * (blockDim.x >> 6);
    for (int e = w; e < N_EDGES; e += nw) {
        int s = load_idx(ei32, ei64, is64, e);
        int d = load_idx(ei32, ei64, is64, (long long)N_EDGES + e);
        unsigned short us = hs[(size_t)s * OUT_CH + lane];
        float hv = __builtin_bit_cast(float, (unsigned)us << 16);
        atomicAdd(&out[(size_t)d * OUT_CH + lane], hv * dinv[s] * dinv[d]);
    }
}

__global__ __launch_bounds__(256) void final_kernel(const unsigned short* __restrict__ hs,
                                                    const float* __restrict__ dinv,
                                                    const float* __restrict__ b,
                                                    float* __restrict__ out) {
    const int lane = threadIdx.x & 63;
    int w = blockIdx.x * (blockDim.x >> 6) + (threadIdx.x >> 6);
    const int nw = gridDim.x * (blockDim.x >> 6);
    const float bias = b[lane];
    for (int n = w; n < N_NODES; n += nw) {
        float di = dinv[n];
        unsigned short us = hs[(size_t)n * OUT_CH + lane];
        float hv = __builtin_bit_cast(float, (unsigned)us << 16);
        float v = out[(size_t)n * OUT_CH + lane] + hv * di * di + bias;
        v = fmaxf(v, 0.f);
        float m = v;
        #pragma unroll
        for (int o = 32; o; o >>= 1) m = fmaxf(m, __shfl_xor(m, o));
        float ex = expf(v - m);
        float sum = ex;
        #pragma unroll
        for (int o = 32; o; o >>= 1) sum += __shfl_xor(sum, o);
        out[(size_t)n * OUT_CH + lane] = (v - m) - logf(sum);
    }
}

// ---------------------------------------------------------------------------
extern "C" void kernel_launch(void* const* d_in, const int* in_sizes, int n_in,
                              void* d_out, int out_size, void* d_ws, size_t ws_size,
                              hipStream_t stream) {
    const float* x  = (const float*)d_in[0];
    const void*  ei = d_in[1];
    const float* W  = (const float*)d_in[2];
    const float* b  = (const float*)d_in[3];
    float* out = (float*)d_out;

    char* ws = (char*)d_ws;
    int* flag = (int*)(ws + WS_FLAG_OFF);
    unsigned* gcnt = (unsigned*)(ws + WS_GCNT_OFF);

    const int* ei32       = (const int*)ei;
    const long long* ei64 = (const long long*)ei;

    probe_kernel<<<1, 64, 0, stream>>>((const unsigned*)ei, flag, gcnt);

    if (ws_size >= (size_t)WS_NEED) {
        float*    dinv = (float*)(ws + WS_DINV_OFF);
        uint2*    nse  = (uint2*)(ws + WS_NSE_OFF);
        unsigned* edg  = (unsigned*)(ws + WS_EDG_OFF);
        unsigned short* hs = (unsigned short*)(ws + WS_H_OFF);

        partition_kernel<<<NBLK_PART, 512, 0, stream>>>(ei32, ei64, flag, gcnt, edg);
        sortgemm_kernel<<<K_BKT + NBLK_GEMM, 256, 0, stream>>>(
            edg, gcnt, nse, dinv, x, W, hs);
        reduce_kernel<<<(N_NODES + 3) / 4, 256, 0, stream>>>(
            hs, dinv, nse, (const int*)edg, b, out);
    } else {
        unsigned* deg  = (unsigned*)(ws + WSF_DEG_OFF);
        float*    dinv = (float*)(ws + WSF_DINV_OFF);
        unsigned short* hs = (unsigned short*)(ws + WSF_H_OFF);
        hipMemsetAsync(deg, 0, (size_t)N_NODES * sizeof(unsigned), stream);
        hipMemsetAsync(d_out, 0, (size_t)out_size * sizeof(float), stream);
        deg_kernel<<<2048, 256, 0, stream>>>(ei32, ei64, flag, deg);
        dinv_kernel<<<(N_NODES + 255) / 256, 256, 0, stream>>>(deg, dinv);
        gemm_only_kernel<<<NBLK_GEMM, 256, 0, stream>>>(x, W, hs);
        scatter_kernel<<<2048, 256, 0, stream>>>(ei32, ei64, flag, hs, dinv, out);
        final_kernel<<<1024, 256, 0, stream>>>(hs, dinv, b, out);
    }
}

// Round 13
// 161.053 us; speedup vs baseline: 9.4385x; 1.0052x over previous
//
#include <hip/hip_runtime.h>
#include <cstddef>
#include <cstdint>

#define N_NODES 100000
#define IN_CH 256
#define OUT_CH 64
#define N_EDGES 3200000

// bucketing: 128 nodes per bucket, fixed-capacity slots
#define BKT_SHIFT 7
#define BKT_R     128
#define K_BKT     782                 // ceil(100000/128)
#define BKT_CAP   6144                // mean 4096 + 32 sigma; slots of 24KB
#define T_PART    8192                // edges per partition block
#define NBLK_PART ((N_EDGES + T_PART - 1) / T_PART)   // 391
#define NBLK_GEMM 512
#define N_TILES   (N_NODES / 16)      // 6250

// ---- ws layout (bytes) ----
#define WS_FLAG_OFF   0
#define WS_GCNT_OFF   64              // 782 u32 bucket fill counts
#define WS_DINV_OFF   4096            // 400000 B
#define WS_NSE_OFF    404096          // 100000 uint2 = 800000 B
#define WS_EDG_OFF    1204224         // 782*6144*4 = 19,218,432 B (pairs -> sorted src)
#define WS_H_OFF      20422656        // bf16 h: 100000*64*2 = 12.8MB (unscaled)
#define WS_NEED       33222656

// ---- fallback (atomic) layout ----
#define WSF_DEG_OFF   4096
#define WSF_DINV_OFF  404096
#define WSF_H_OFF     804096

typedef __attribute__((ext_vector_type(8))) short bshort8;
typedef __attribute__((ext_vector_type(4))) float f32x4;
typedef __attribute__((ext_vector_type(2))) float f32x2;
typedef __attribute__((ext_vector_type(4))) unsigned u32x4;

// ---------------------------------------------------------------------------
static __device__ __forceinline__ unsigned short f2bf(float f) {
    unsigned u = __builtin_bit_cast(unsigned, f);
    u += 0x7FFFu + ((u >> 16) & 1u);     // RNE (finite inputs)
    return (unsigned short)(u >> 16);
}
static __device__ __forceinline__ float bflo(unsigned u) {
    return __builtin_bit_cast(float, u << 16);
}
static __device__ __forceinline__ float bfhi(unsigned u) {
    return __builtin_bit_cast(float, u & 0xFFFF0000u);
}
static __device__ __forceinline__ f32x2 up2(unsigned u) {
    f32x2 r;
    r.x = __builtin_bit_cast(float, u << 16);
    r.y = __builtin_bit_cast(float, u & 0xFFFF0000u);
    return r;
}

// ---------------------------------------------------------------------------
// probe: detect int64 vs int32 edge layout AND zero the gcnt counters.
__global__ void probe_kernel(const unsigned* __restrict__ ei, int* __restrict__ flag,
                             unsigned* __restrict__ gcnt) {
    if (blockIdx.x == 0) {
        for (int k = threadIdx.x; k < K_BKT; k += 64) gcnt[k] = 0u;
        if (threadIdx.x == 0) {
            int all0 = 1;
            for (int i = 0; i < 16; ++i) all0 &= (ei[2 * i + 1] == 0u);
            *flag = all0;  // 1 => int64 layout, 0 => int32 layout
        }
    }
}

__device__ __forceinline__ int load_idx(const int* ei32, const long long* ei64,
                                        bool is64, long long pos) {
    return is64 ? (int)ei64[pos] : ei32[pos];
}

// ---------------------------------------------------------------------------
// Shared gemm body (256 threads, 4 waves): h = x @ W, bf16 store, UNSCALED.
// (round-9..12-proven code, unchanged)
static __device__ __forceinline__ void gemm_body(char* smem, int gbid, int nblk,
                                                 const float* __restrict__ x,
                                                 const float* __restrict__ W,
                                                 unsigned short* __restrict__ hs) {
    unsigned short (*Wf)[4][64][8] = (unsigned short (*)[4][64][8])smem;
    const int tid = threadIdx.x;
    const int lane = tid & 63;
    const int wv = tid >> 6;           // 4 waves

    for (int i = tid; i < 8 * 4 * 64 * 8; i += 256) {
        int kt = i >> 11;
        int rem = i & 2047;
        int ct = rem >> 9;
        int rem2 = rem & 511;
        int l = rem2 >> 3;
        int j = rem2 & 7;
        int kk = kt * 32 + (l >> 4) * 8 + j;
        int cc = ct * 16 + (l & 15);
        ((unsigned short*)Wf)[i] = f2bf(W[(size_t)kk * OUT_CH + cc]);
    }
    __syncthreads();

    const int r16 = lane & 15;   // A row within tile
    const int q = lane >> 4;     // k-quarter (A), row-quarter (C)

    for (int t = gbid * 4 + wv; t < N_TILES; t += nblk * 4) {
        const int row0 = t * 16;
        const float* xrow = &x[(size_t)(row0 + r16) * IN_CH + q * 8];
        f32x4 acc[4] = {{0.f,0.f,0.f,0.f},{0.f,0.f,0.f,0.f},
                        {0.f,0.f,0.f,0.f},{0.f,0.f,0.f,0.f}};
        #pragma unroll
        for (int kt = 0; kt < 8; ++kt) {
            float4 x0 = *(const float4*)&xrow[kt * 32];
            float4 x1 = *(const float4*)&xrow[kt * 32 + 4];
            unsigned p0, p1, p2, p3;
            asm("v_cvt_pk_bf16_f32 %0, %1, %2" : "=v"(p0) : "v"(x0.x), "v"(x0.y));
            asm("v_cvt_pk_bf16_f32 %0, %1, %2" : "=v"(p1) : "v"(x0.z), "v"(x0.w));
            asm("v_cvt_pk_bf16_f32 %0, %1, %2" : "=v"(p2) : "v"(x1.x), "v"(x1.y));
            asm("v_cvt_pk_bf16_f32 %0, %1, %2" : "=v"(p3) : "v"(x1.z), "v"(x1.w));
            u32x4 au = {p0, p1, p2, p3};
            bshort8 af = __builtin_bit_cast(bshort8, au);
            #pragma unroll
            for (int ct = 0; ct < 4; ++ct) {
                bshort8 bf = *(const bshort8*)&Wf[kt][ct][lane][0];
                acc[ct] = __builtin_amdgcn_mfma_f32_16x16x32_bf16(af, bf, acc[ct], 0, 0, 0);
            }
        }
        #pragma unroll
        for (int ct = 0; ct < 4; ++ct) {
            #pragma unroll
            for (int r = 0; r < 4; ++r) {
                int row = row0 + q * 4 + r;
                hs[(size_t)row * OUT_CH + ct * 16 + r16] = f2bf(acc[ct][r]);
            }
        }
    }
}

// ---------------------------------------------------------------------------
// Standalone partition (round-12-proven): 512 threads, 6.4KB LDS; pass 1
// histograms + register-caches dst; pass 2 reads only src.
__global__ __launch_bounds__(512) void partition_kernel(const int* __restrict__ ei32,
                                                        const long long* __restrict__ ei64,
                                                        const int* __restrict__ flag,
                                                        unsigned* __restrict__ gcnt,
                                                        unsigned* __restrict__ edg) {
    __shared__ unsigned hist[K_BKT];
    __shared__ unsigned cur[K_BKT];
    const bool is64 = (*flag != 0);
    const int tid = threadIdx.x;
    const int start = blockIdx.x * T_PART;
    const int end   = min(start + T_PART, N_EDGES);
    const int pbase = start >> 1;
    const int pend  = end >> 1;
    unsigned dcx[8], dcy[8];

    for (int k = tid; k < K_BKT; k += 512) hist[k] = 0u;
    __syncthreads();
    if (is64) {
        const longlong2* d2 = (const longlong2*)&ei64[N_EDGES];
        #pragma unroll
        for (int it = 0; it < 8; ++it) {
            int i = pbase + it * 512 + tid;
            if (i < pend) {
                longlong2 d = d2[i];
                dcx[it] = (unsigned)(int)d.x;
                dcy[it] = (unsigned)(int)d.y;
                atomicAdd(&hist[dcx[it] >> BKT_SHIFT], 1u);
                atomicAdd(&hist[dcy[it] >> BKT_SHIFT], 1u);
            }
        }
    } else {
        const int2* d2 = (const int2*)&ei32[N_EDGES];
        #pragma unroll
        for (int it = 0; it < 8; ++it) {
            int i = pbase + it * 512 + tid;
            if (i < pend) {
                int2 d = d2[i];
                dcx[it] = (unsigned)d.x;
                dcy[it] = (unsigned)d.y;
                atomicAdd(&hist[dcx[it] >> BKT_SHIFT], 1u);
                atomicAdd(&hist[dcy[it] >> BKT_SHIFT], 1u);
            }
        }
    }
    __syncthreads();
    for (int k = tid; k < K_BKT; k += 512) {
        unsigned c = hist[k];
        unsigned base = c ? atomicAdd(&gcnt[k], c) : 0u;
        cur[k] = base + (unsigned)k * BKT_CAP;
    }
    __syncthreads();
    if (is64) {
        const longlong2* s2 = (const longlong2*)&ei64[0];
        #pragma unroll
        for (int it = 0; it < 8; ++it) {
            int i = pbase + it * 512 + tid;
            if (i < pend) {
                longlong2 s = s2[i];
                unsigned dx = dcx[it], dy = dcy[it];
                unsigned p0 = atomicAdd(&cur[dx >> BKT_SHIFT], 1u);
                edg[p0] = (unsigned)s.x | ((dx & (BKT_R - 1)) << 17);
                unsigned p1 = atomicAdd(&cur[dy >> BKT_SHIFT], 1u);
                edg[p1] = (unsigned)s.y | ((dy & (BKT_R - 1)) << 17);
            }
        }
    } else {
        const int2* s2 = (const int2*)&ei32[0];
        #pragma unroll
        for (int it = 0; it < 8; ++it) {
            int i = pbase + it * 512 + tid;
            if (i < pend) {
                int2 s = s2[i];
                unsigned dx = dcx[it], dy = dcy[it];
                unsigned p0 = atomicAdd(&cur[dx >> BKT_SHIFT], 1u);
                edg[p0] = (unsigned)s.x | ((dx & (BKT_R - 1)) << 17);
                unsigned p1 = atomicAdd(&cur[dy >> BKT_SHIFT], 1u);
                edg[p1] = (unsigned)s.y | ((dy & (BKT_R - 1)) << 17);
            }
        }
    }
}

// ---------------------------------------------------------------------------
// FUSED sort2 + gemm (round-11-proven): blocks [0, K_BKT) counting-sort their
// bucket (LDS-staged, in place -> nse/dinv); blocks [K_BKT, +NBLK_GEMM) gemm.
__global__ __launch_bounds__(256) void sortgemm_kernel(unsigned* __restrict__ edg,
                                                       const unsigned* __restrict__ gcnt,
                                                       uint2* __restrict__ nse,
                                                       float* __restrict__ dinv,
                                                       const float* __restrict__ x,
                                                       const float* __restrict__ W,
                                                       unsigned short* __restrict__ hs) {
    __shared__ char smem[32768];
    const int bid = blockIdx.x;
    if (bid < K_BKT) {
        unsigned* ld   = (unsigned*)smem;            // 24576 B
        unsigned* hist = (unsigned*)(smem + 24576);  // 512 B
        unsigned* cur  = (unsigned*)(smem + 25088);  // 512 B
        const int k = bid;
        const int t = threadIdx.x;
        const unsigned cnt = min(gcnt[k], (unsigned)BKT_CAP);
        const unsigned base = (unsigned)k * BKT_CAP;

        for (unsigned j = t; j < cnt; j += 256) ld[j] = edg[base + j];
        if (t < BKT_R) hist[t] = 0u;
        __syncthreads();
        for (unsigned j = t; j < cnt; j += 256)
            atomicAdd(&hist[ld[j] >> 17], 1u);
        __syncthreads();
        if (t < BKT_R) cur[t] = hist[t];
        __syncthreads();
        #pragma unroll
        for (int d = 1; d < BKT_R; d <<= 1) {
            unsigned v = (t < BKT_R && t >= d) ? cur[t - d] : 0u;
            __syncthreads();
            if (t < BKT_R) cur[t] += v;
            __syncthreads();
        }
        if (t < BKT_R) {
            unsigned mydeg = hist[t];
            unsigned start = base + cur[t] - mydeg;   // exclusive, padded coords
            int n = k * BKT_R + t;
            if (n < N_NODES) {
                nse[n] = make_uint2(start, start + mydeg);
                dinv[n] = rsqrtf((float)(mydeg + 1u));
            }
            cur[t] = start;
        }
        __syncthreads();
        for (unsigned j = t; j < cnt; j += 256) {
            unsigned p = ld[j];
            unsigned pos = atomicAdd(&cur[p >> 17], 1u);
            edg[pos] = p & 0x1FFFF;     // sorted src id
        }
    } else {
        gemm_body(smem, bid - K_BKT, NBLK_GEMM, x, W, hs);
    }
}

// gemm-only wrapper (fallback path)
__global__ __launch_bounds__(256) void gemm_only_kernel(const float* __restrict__ x,
                                                        const float* __restrict__ W,
                                                        unsigned short* __restrict__ hs) {
    __shared__ char smem[32768];
    gemm_body(smem, blockIdx.x, gridDim.x, x, W, hs);
}

// ---------------------------------------------------------------------------
// Wave per node, quarter-wave per edge. Main loop = 32 edges/iteration with
// 8 INDEPENDENT h-gathers in flight (MLP x2 vs round 12); 16/4/1 tails.
__global__ __launch_bounds__(256) void reduce_kernel(const unsigned short* __restrict__ hs,
                                                     const float* __restrict__ dinv,
                                                     const uint2* __restrict__ nse,
                                                     const int* __restrict__ ssrc,
                                                     const float* __restrict__ b,
                                                     float* __restrict__ out) {
    const int n = blockIdx.x * 4 + (threadIdx.x >> 6);
    const int lane = threadIdx.x & 63;
    const int q = lane >> 4;
    const int l16 = lane & 15;
    if (n >= N_NODES) return;
    const uint2* h8 = (const uint2*)hs;   // one row = 16 uint2
    const float dn = dinv[n];
    f32x2 A01 = {0.f, 0.f}, A23 = {0.f, 0.f};
    {   // self-loop: h[n]*dinv[n]; counted once (q==0)
        uint2 sv = h8[(size_t)n * 16 + l16];
        if (q == 0) {
            f32x2 dnv = {dn, dn};
            A01 = up2(sv.x) * dnv;
            A23 = up2(sv.y) * dnv;
        }
    }
    uint2 se = nse[n];
    unsigned j = se.x;
    const unsigned end = se.y;
    // 32 edges per iteration: 8 independent gathers in flight per wave
    for (; j + 32 <= end; j += 32) {
        int s0 = ssrc[j + q];
        int s1 = ssrc[j + 4 + q];
        int s2 = ssrc[j + 8 + q];
        int s3 = ssrc[j + 12 + q];
        int s4 = ssrc[j + 16 + q];
        int s5 = ssrc[j + 20 + q];
        int s6 = ssrc[j + 24 + q];
        int s7 = ssrc[j + 28 + q];
        float f0 = dinv[s0], f1 = dinv[s1], f2 = dinv[s2], f3 = dinv[s3];
        float f4 = dinv[s4], f5 = dinv[s5], f6 = dinv[s6], f7 = dinv[s7];
        uint2 v0 = h8[(size_t)s0 * 16 + l16];
        uint2 v1 = h8[(size_t)s1 * 16 + l16];
        uint2 v2 = h8[(size_t)s2 * 16 + l16];
        uint2 v3 = h8[(size_t)s3 * 16 + l16];
        uint2 v4 = h8[(size_t)s4 * 16 + l16];
        uint2 v5 = h8[(size_t)s5 * 16 + l16];
        uint2 v6 = h8[(size_t)s6 * 16 + l16];
        uint2 v7 = h8[(size_t)s7 * 16 + l16];
        f32x2 F0 = {f0, f0}, F1 = {f1, f1}, F2 = {f2, f2}, F3 = {f3, f3};
        f32x2 F4 = {f4, f4}, F5 = {f5, f5}, F6 = {f6, f6}, F7 = {f7, f7};
        A01 += up2(v0.x) * F0; A23 += up2(v0.y) * F0;
        A01 += up2(v1.x) * F1; A23 += up2(v1.y) * F1;
        A01 += up2(v2.x) * F2; A23 += up2(v2.y) * F2;
        A01 += up2(v3.x) * F3; A23 += up2(v3.y) * F3;
        A01 += up2(v4.x) * F4; A23 += up2(v4.y) * F4;
        A01 += up2(v5.x) * F5; A23 += up2(v5.y) * F5;
        A01 += up2(v6.x) * F6; A23 += up2(v6.y) * F6;
        A01 += up2(v7.x) * F7; A23 += up2(v7.y) * F7;
    }
    for (; j + 16 <= end; j += 16) {
        int s0 = ssrc[j + q];
        int s1 = ssrc[j + 4 + q];
        int s2 = ssrc[j + 8 + q];
        int s3 = ssrc[j + 12 + q];
        float f0 = dinv[s0], f1 = dinv[s1], f2 = dinv[s2], f3 = dinv[s3];
        uint2 v0 = h8[(size_t)s0 * 16 + l16];
        uint2 v1 = h8[(size_t)s1 * 16 + l16];
        uint2 v2 = h8[(size_t)s2 * 16 + l16];
        uint2 v3 = h8[(size_t)s3 * 16 + l16];
        f32x2 F0 = {f0, f0}, F1 = {f1, f1}, F2 = {f2, f2}, F3 = {f3, f3};
        A01 += up2(v0.x) * F0; A23 += up2(v0.y) * F0;
        A01 += up2(v1.x) * F1; A23 += up2(v1.y) * F1;
        A01 += up2(v2.x) * F2; A23 += up2(v2.y) * F2;
        A01 += up2(v3.x) * F3; A23 += up2(v3.y) * F3;
    }
    for (; j + 4 <= end; j += 4) {
        int s = ssrc[j + q];
        float f = dinv[s];
        uint2 v = h8[(size_t)s * 16 + l16];
        f32x2 F = {f, f};
        A01 += up2(v.x) * F; A23 += up2(v.y) * F;
    }
    unsigned rem = end - j;
    if ((unsigned)q < rem) {
        int s = ssrc[j + q];
        float f = dinv[s];
        uint2 v = h8[(size_t)s * 16 + l16];
        f32x2 F = {f, f};
        A01 += up2(v.x) * F; A23 += up2(v.y) * F;
    }
    float a0 = A01.x, a1 = A01.y, a2 = A23.x, a3 = A23.y;
    a0 += __shfl_xor(a0, 16); a0 += __shfl_xor(a0, 32);
    a1 += __shfl_xor(a1, 16); a1 += __shfl_xor(a1, 32);
    a2 += __shfl_xor(a2, 16); a2 += __shfl_xor(a2, 32);
    a3 += __shfl_xor(a3, 16); a3 += __shfl_xor(a3, 32);
    float4 bb = ((const float4*)b)[l16];
    float v0 = fmaxf(fmaf(a0, dn, bb.x), 0.f);
    float v1 = fmaxf(fmaf(a1, dn, bb.y), 0.f);
    float v2 = fmaxf(fmaf(a2, dn, bb.z), 0.f);
    float v3 = fmaxf(fmaf(a3, dn, bb.w), 0.f);
    float m = fmaxf(fmaxf(v0, v1), fmaxf(v2, v3));
    #pragma unroll
    for (int o = 8; o; o >>= 1) m = fmaxf(m, __shfl_xor(m, o));
    float sum = expf(v0 - m) + expf(v1 - m) + expf(v2 - m) + expf(v3 - m);
    #pragma unroll
    for (int o = 8; o; o >>= 1) sum += __shfl_xor(sum, o);
    float ls = logf(sum);
    if (q == 0) {
        float4 r;
        r.x = (v0 - m) - ls; r.y = (v1 - m) - ls;
        r.z = (v2 - m) - ls; r.w = (v3 - m) - ls;
        *(float4*)&out[(size_t)n * OUT_CH + l16 * 4] = r;
    }
}

// ---------------------------------------------------------------------------
// Fallback (atomic scatter) path, only if ws is too small for the CSR path.
__global__ __launch_bounds__(256) void deg_kernel(const int* __restrict__ ei32,
                                                  const long long* __restrict__ ei64,
                                                  const int* __restrict__ flag,
                                                  unsigned* __restrict__ deg) {
    const bool is64 = (*flag != 0);
    int i = blockIdx.x * blockDim.x + threadIdx.x;
    const int stride = gridDim.x * blockDim.x;
    for (; i < N_EDGES; i += stride) {
        int d = load_idx(ei32, ei64, is64, (long long)N_EDGES + i);
        atomicAdd(&deg[d], 1u);
    }
}

__global__ __launch_bounds__(256) void dinv_kernel(const unsigned* __restrict__ deg,
                                                   float* __restrict__ dinv) {
    int i = blockIdx.x * blockDim.x + threadIdx.x;
    if (i < N_NODES) dinv[i] = rsqrtf((float)(deg[i] + 1u));
}

__global__ __launch_bounds__(256) void scatter_kernel(const int* __restrict__ ei32,
                                                      const long long* __restrict__ ei64,
                                                      const int* __restrict__ flag,
                                                      const unsigned short* __restrict__ hs,
                                                      const float* __restrict__ dinv,
                                                      float* __restrict__ out) {
    const bool is64 = (*flag != 0);
    const int lane = threadIdx.x & 63;
    int w = blockIdx.x * (blockDim.x >> 6) + (threadIdx.x >> 6);
    const int nw = gridDim.x * (blockDim.x >> 6);
    for (int e = w; e < N_EDGES; e += nw) {
        int s = load_idx(ei32, ei64, is64, e);
        int d = load_idx(ei32, ei64, is64, (long long)N_EDGES + e);
        unsigned short us = hs[(size_t)s * OUT_CH + lane];
        float hv = __builtin_bit_cast(float, (unsigned)us << 16);
        atomicAdd(&out[(size_t)d * OUT_CH + lane], hv * dinv[s] * dinv[d]);
    }
}

__global__ __launch_bounds__(256) void final_kernel(const unsigned short* __restrict__ hs,
                                                    const float* __restrict__ dinv,
                                                    const float* __restrict__ b,
                                                    float* __restrict__ out) {
    const int lane = threadIdx.x & 63;
    int w = blockIdx.x * (blockDim.x >> 6) + (threadIdx.x >> 6);
    const int nw = gridDim.x * (blockDim.x >> 6);
    const float bias = b[lane];
    for (int n = w; n < N_NODES; n += nw) {
        float di = dinv[n];
        unsigned short us = hs[(size_t)n * OUT_CH + lane];
        float hv = __builtin_bit_cast(float, (unsigned)us << 16);
        float v = out[(size_t)n * OUT_CH + lane] + hv * di * di + bias;
        v = fmaxf(v, 0.f);
        float m = v;
        #pragma unroll
        for (int o = 32; o; o >>= 1) m = fmaxf(m, __shfl_xor(m, o));
        float ex = expf(v - m);
        float sum = ex;
        #pragma unroll
        for (int o = 32; o; o >>= 1) sum += __shfl_xor(sum, o);
        out[(size_t)n * OUT_CH + lane] = (v - m) - logf(sum);
    }
}

// ---------------------------------------------------------------------------
extern "C" void kernel_launch(void* const* d_in, const int* in_sizes, int n_in,
                              void* d_out, int out_size, void* d_ws, size_t ws_size,
                              hipStream_t stream) {
    const float* x  = (const float*)d_in[0];
    const void*  ei = d_in[1];
    const float* W  = (const float*)d_in[2];
    const float* b  = (const float*)d_in[3];
    float* out = (float*)d_out;

    char* ws = (char*)d_ws;
    int* flag = (int*)(ws + WS_FLAG_OFF);
    unsigned* gcnt = (unsigned*)(ws + WS_GCNT_OFF);

    const int* ei32       = (const int*)ei;
    const long long* ei64 = (const long long*)ei;

    probe_kernel<<<1, 64, 0, stream>>>((const unsigned*)ei, flag, gcnt);

    if (ws_size >= (size_t)WS_NEED) {
        float*    dinv = (float*)(ws + WS_DINV_OFF);
        uint2*    nse  = (uint2*)(ws + WS_NSE_OFF);
        unsigned* edg  = (unsigned*)(ws + WS_EDG_OFF);
        unsigned short* hs = (unsigned short*)(ws + WS_H_OFF);

        partition_kernel<<<NBLK_PART, 512, 0, stream>>>(ei32, ei64, flag, gcnt, edg);
        sortgemm_kernel<<<K_BKT + NBLK_GEMM, 256, 0, stream>>>(
            edg, gcnt, nse, dinv, x, W, hs);
        reduce_kernel<<<(N_NODES + 3) / 4, 256, 0, stream>>>(
            hs, dinv, nse, (const int*)edg, b, out);
    } else {
        unsigned* deg  = (unsigned*)(ws + WSF_DEG_OFF);
        float*    dinv = (float*)(ws + WSF_DINV_OFF);
        unsigned short* hs = (unsigned short*)(ws + WSF_H_OFF);
        hipMemsetAsync(deg, 0, (size_t)N_NODES * sizeof(unsigned), stream);
        hipMemsetAsync(d_out, 0, (size_t)out_size * sizeof(float), stream);
        deg_kernel<<<2048, 256, 0, stream>>>(ei32, ei64, flag, deg);
        dinv_kernel<<<(N_NODES + 255) / 256, 256, 0, stream>>>(deg, dinv);
        gemm_only_kernel<<<NBLK_GEMM, 256, 0, stream>>>(x, W, hs);
        scatter_kernel<<<2048, 256, 0, stream>>>(ei32, ei64, flag, hs, dinv, out);
        final_kernel<<<1024, 256, 0, stream>>>(hs, dinv, b, out);
    }
}